// Round 17
// baseline (702.106 us; speedup 1.0000x reference)
//
#include <hip/hip_runtime.h>
#include <stdint.h>

#define TPB 256

typedef _Float16 half_t;
typedef __attribute__((ext_vector_type(8))) _Float16 f16x8;
typedef __attribute__((ext_vector_type(4))) float f32x4;

static inline int nblk(long n) { return (int)((n + TPB - 1) / TPB); }
static inline int gmin(long a, long b) { return (int)(a < b ? a : b); }

// ---------- scan-based compaction ----------
__global__ void cmpA0_k(const float* __restrict__ x, int n, int* __restrict__ bcnt) {
  int i = blockIdx.x * TPB + threadIdx.x;
  bool a = false;
  if (i < n) {
    float2 v = *(const float2*)(x + 2L * i);
    a = (v.x != 0.f) || (v.y != 0.f);
  }
  unsigned long long bal = __ballot(a);
  __shared__ int wc[4];
  if ((threadIdx.x & 63) == 0) wc[threadIdx.x >> 6] = __popcll(bal);
  __syncthreads();
  if (threadIdx.x == 0) bcnt[blockIdx.x] = wc[0] + wc[1] + wc[2] + wc[3];
}

// also converts x -> f16
__global__ void cmpB0_k(const float* __restrict__ x, int n, const int* __restrict__ bbase,
                        int* __restrict__ list, int* __restrict__ inv, int cap,
                        half_t* __restrict__ xh) {
  int i = blockIdx.x * TPB + threadIdx.x;
  float2 v = {0.f, 0.f};
  bool a = false;
  if (i < n) {
    v = *(const float2*)(x + 2L * i);
    a = (v.x != 0.f) || (v.y != 0.f);
  }
  unsigned long long bal = __ballot(a);
  __shared__ int wc[4];
  int wid = threadIdx.x >> 6, lane = threadIdx.x & 63;
  if (lane == 0) wc[wid] = __popcll(bal);
  __syncthreads();
  int base = bbase[blockIdx.x];
  for (int w = 0; w < wid; ++w) base += wc[w];
  if (i < n) {
    xh[2L * i] = (half_t)v.x;
    xh[2L * i + 1] = (half_t)v.y;
    int pos = base + __popcll(bal & ((1ull << lane) - 1));
    if (a && pos < cap) { list[pos] = i; inv[i] = pos; }
    else inv[i] = -1;
  }
}

__device__ __forceinline__ bool actp(const int* invp, int Hp, int Wp, int Ho, int Wo, int i) {
  int wo = i % Wo; int t = i / Wo; int ho = t % Ho; int bb = t / Ho;
  long rb = ((long)bb * Hp + 2 * ho) * Wp + 2 * wo;
  bool a = false;
  #pragma unroll
  for (int kh = 0; kh < 3; ++kh)
    #pragma unroll
    for (int kw = 0; kw < 3; ++kw)
      a |= (invp[rb + kh * Wp + kw] >= 0);
  return a;
}

__global__ void poolA_k(const int* __restrict__ invp, int Hp, int Wp, int Ho, int Wo,
                        int n, int* __restrict__ bcnt) {
  int i = blockIdx.x * TPB + threadIdx.x;
  bool a = (i < n) && actp(invp, Hp, Wp, Ho, Wo, i);
  unsigned long long bal = __ballot(a);
  __shared__ int wc[4];
  if ((threadIdx.x & 63) == 0) wc[threadIdx.x >> 6] = __popcll(bal);
  __syncthreads();
  if (threadIdx.x == 0) bcnt[blockIdx.x] = wc[0] + wc[1] + wc[2] + wc[3];
}

__global__ void poolB_k(const int* __restrict__ invp, int Hp, int Wp, int Ho, int Wo, int n,
                        const int* __restrict__ bbase, int* __restrict__ list,
                        int* __restrict__ inv, int cap) {
  int i = blockIdx.x * TPB + threadIdx.x;
  bool a = (i < n) && actp(invp, Hp, Wp, Ho, Wo, i);
  unsigned long long bal = __ballot(a);
  __shared__ int wc[4];
  int wid = threadIdx.x >> 6, lane = threadIdx.x & 63;
  if (lane == 0) wc[wid] = __popcll(bal);
  __syncthreads();
  int base = bbase[blockIdx.x];
  for (int w = 0; w < wid; ++w) base += wc[w];
  if (i < n) {
    int pos = base + __popcll(bal & ((1ull << lane) - 1));
    if (a && pos < cap) { list[pos] = i; inv[i] = pos; }
    else inv[i] = -1;
  }
}

// exclusive scan; total -> *total; zeroes stats
__global__ void scan_k(int* __restrict__ b, int n, int* __restrict__ total,
                       float* __restrict__ stats) {
  __shared__ int sh[1024];
  __shared__ int sc;
  if (threadIdx.x < 512) stats[threadIdx.x] = 0.f;
  if (threadIdx.x == 0) sc = 0;
  __syncthreads();
  for (int base = 0; base < n; base += 1024) {
    int i = base + threadIdx.x;
    int v = (i < n) ? b[i] : 0;
    sh[threadIdx.x] = v;
    __syncthreads();
    for (int o = 1; o < 1024; o <<= 1) {
      int t = (threadIdx.x >= o) ? sh[threadIdx.x - o] : 0;
      __syncthreads();
      sh[threadIdx.x] += t;
      __syncthreads();
    }
    if (i < n) b[i] = sh[threadIdx.x] - v + sc;
    __syncthreads();
    if (threadIdx.x == 0) sc += sh[1023];
    __syncthreads();
  }
  if (threadIdx.x == 0) *total = sc;
}

// ---------- pooled values (f16 in/out) ----------
template <int C>
__global__ void pool_val_f16_k(const half_t* __restrict__ xin, const int* __restrict__ invp,
                               const int* __restrict__ list, const int* __restrict__ cnt,
                               int Hp, int Wp, int Ho, int Wo, half_t* __restrict__ y) {
  long total = (long)cnt[0] * C;
  for (long i = (long)blockIdx.x * TPB + threadIdx.x; i < total; i += (long)gridDim.x * TPB) {
    int c = (int)(i & (C - 1));
    int r = (int)(i / C);
    int site = list[r];
    int wo = site % Wo; int t = site / Wo; int ho = t % Ho; int bb = t / Ho;
    long rb = ((long)bb * Hp + 2 * ho) * Wp + 2 * wo;
    float best = -1e30f;
    #pragma unroll
    for (int kh = 0; kh < 3; ++kh)
      #pragma unroll
      for (int kw = 0; kw < 3; ++kw) {
        int j = invp[rb + kh * Wp + kw];
        if (j >= 0) best = fmaxf(best, (float)xin[(long)j * C + c]);
      }
    y[i] = (half_t)best;
  }
}

// ---------- mega weight pack ----------
struct PackArgs {
  const float* src[14];
  half_t* dst[14];
};

__global__ void packall_k(PackArgs pa) {
  const int seg = blockIdx.y;
  const int tci[14]  = {2, 16, 16, 32, 32, 64, 64, 128, 128, 256, 256, 256, 256, 256};
  const int tco[14]  = {16, 16, 32, 32, 64, 64, 128, 128, 256, 256, 256, 256, 256, 256};
  const int tkp[14]  = {32, 160, 160, 288, 0, 0, 0, 0, 0, 0, 0, 0, 0, 0};
  const int twci[14] = {2, 16, 16, 32, 32, 64, 64, 128, 128, 256, 512, 512, 512, 512};
  const int twco[14] = {16, 16, 32, 32, 64, 64, 128, 128, 256, 256, 512, 256, 512, 256};
  const int CI = tci[seg], CO = tco[seg], KP = tkp[seg];
  const int wci = twci[seg], wco = twco[seg];
  const float* __restrict__ src = pa.src[seg];
  half_t* __restrict__ dst = pa.dst[seg];
  if (KP > 0) {
    long total = (long)CO * KP;
    for (long i = (long)blockIdx.x * TPB + threadIdx.x; i < total; i += (long)gridDim.x * TPB) {
      int k = (int)(i % KP), co = (int)(i / KP);
      int tap = k / CI, ci = k - tap * CI;
      float v = (tap < 9) ? src[((long)tap * wci + ci) * wco + co] : 0.f;
      dst[i] = (half_t)v;
    }
  } else {
    long total = 9L * CO * CI;
    for (long i = (long)blockIdx.x * TPB + threadIdx.x; i < total; i += (long)gridDim.x * TPB) {
      int ci = (int)(i % CI);
      long t = i / CI;
      int co = (int)(t % CO);
      int tap = (int)(t / CO);
      dst[i] = (half_t)src[((long)tap * wci + ci) * wco + co];
    }
  }
}

__global__ void w1tr_k(const float* __restrict__ W1, half_t* __restrict__ w1t) {
  __shared__ float tile[64][65];
  int k0 = blockIdx.x * 64, j0 = blockIdx.y * 64;
  for (int i = threadIdx.x; i < 4096; i += TPB) {
    int r = i >> 6, c = i & 63;
    tile[r][c] = W1[(long)(k0 + r) * 1024 + j0 + c];
  }
  __syncthreads();
  for (int i = threadIdx.x; i < 4096; i += TPB) {
    int r = i >> 6, c = i & 63;
    w1t[(long)(j0 + r) * 8960 + k0 + c] = (half_t)tile[c][r];
  }
}

// ---------- zero-fill dense GRU outputs + dflat ----------
__global__ void zfill_k(float* __restrict__ h1, float* __restrict__ h2,
                        half_t* __restrict__ df) {
  for (long i = (long)blockIdx.x * TPB + threadIdx.x; i < 286720; i += (long)gridDim.x * TPB) {
    h1[i] = 0.f;
    h2[i] = 0.f;
    df[i] = (half_t)0.f;
  }
}

// ---------- K-packed MFMA conv (CO<=32); 64 sites/block; f16 out; optional BN stats ----------
template <int CI, int CO, bool DENSE>
__global__ __launch_bounds__(256) void mconvp_k(const half_t* __restrict__ X,
                                                const half_t* __restrict__ Wt,
                                                half_t* __restrict__ y,
                                                const int* __restrict__ inv,
                                                const int* __restrict__ list,
                                                const int* __restrict__ cnt,
                                                int H, int W,
                                                float* __restrict__ stats) {
  constexpr int KP = ((9 * CI + 31) / 32) * 32;
  constexpr int NCO = CO / 16;
  const int nact = cnt[0];
  const int base = blockIdx.x * 64;
  if (base >= nact) return;
  __shared__ int nbr[64 * 9];
  __shared__ float sstat[2][CO];
  for (int i = threadIdx.x; i < 64 * 9; i += TPB) {
    int s = i / 9, nb = i - s * 9;
    int j = -1;
    if (base + s < nact) {
      int site = list[base + s];
      int w = site % W; int t = site / W; int h = t % H; int bb = t / H;
      int hh = h + nb / 3 - 1, ww = w + nb % 3 - 1;
      if ((unsigned)hh < (unsigned)H && (unsigned)ww < (unsigned)W) {
        int ss = (bb * H + hh) * W + ww;
        j = DENSE ? ss : inv[ss];
      }
    }
    nbr[i] = j;
  }
  if (stats) {
    for (int i = threadIdx.x; i < 2 * CO; i += TPB) ((float*)sstat)[i] = 0.f;
  }
  __syncthreads();
  const int lane = threadIdx.x & 63, wv = threadIdx.x >> 6;
  const int srow = lane & 15, kseg = lane >> 4;
  const int sloc = wv * 16 + srow;
  f32x4 acc[NCO];
  #pragma unroll
  for (int c = 0; c < NCO; ++c) acc[c] = (f32x4){0.f, 0.f, 0.f, 0.f};
  #pragma unroll
  for (int k0 = 0; k0 < KP; k0 += 32) {
    const int k = k0 + kseg * 8;
    f16x8 av;
    #pragma unroll
    for (int z = 0; z < 8; ++z) av[z] = (_Float16)0.f;
    if (CI >= 8) {
      int tap = k / CI;
      int ci = k - tap * CI;
      if (tap < 9) {
        int j = nbr[sloc * 9 + tap];
        if (j >= 0) av = *(const f16x8*)(X + (long)j * CI + ci);
      }
    } else {  // CI == 2
      #pragma unroll
      for (int q = 0; q < 4; ++q) {
        int kk = k + 2 * q;
        int tap = kk >> 1;
        if (tap < 9) {
          int j = nbr[sloc * 9 + tap];
          if (j >= 0) {
            const half_t* xp = X + (long)j * 2;
            av[2 * q] = xp[0];
            av[2 * q + 1] = xp[1];
          }
        }
      }
    }
    #pragma unroll
    for (int c = 0; c < NCO; ++c) {
      f16x8 bv = *(const f16x8*)(Wt + (long)(c * 16 + srow) * KP + k);
      acc[c] = __builtin_amdgcn_mfma_f32_16x16x32_f16(av, bv, acc[c], 0, 0, 0);
    }
  }
  #pragma unroll
  for (int c = 0; c < NCO; ++c)
    #pragma unroll
    for (int r = 0; r < 4; ++r) {
      int ss = base + wv * 16 + kseg * 4 + r;
      if (ss < nact) y[(long)ss * CO + c * 16 + srow] = (half_t)acc[c][r];
    }
  if (stats) {
    #pragma unroll
    for (int c = 0; c < NCO; ++c) {
      float ps = 0.f, pq = 0.f;
      #pragma unroll
      for (int r = 0; r < 4; ++r) {
        float v = acc[c][r];  // zero for invalid sites (all taps masked)
        int ss = base + wv * 16 + kseg * 4 + r;
        if (ss < nact) { ps += v; pq += v * v; }
      }
      atomicAdd(&sstat[0][c * 16 + srow], ps);
      atomicAdd(&sstat[1][c * 16 + srow], pq);
    }
    __syncthreads();
    for (int i = threadIdx.x; i < CO; i += TPB) {
      atomicAdd(&stats[i], sstat[0][i]);
      atomicAdd(&stats[CO + i], sstat[1][i]);
    }
  }
}

// ---------- LDS-staged-weight conv: 64 sites x 64 co; optional BN stats ----------
template <int CI>
__global__ __launch_bounds__(256) void mconv_lds_k(const half_t* __restrict__ X,
                                                   const half_t* __restrict__ Wt,
                                                   half_t* __restrict__ y,
                                                   const int* __restrict__ inv,
                                                   const int* __restrict__ list,
                                                   const int* __restrict__ cnt,
                                                   int H, int W, int COfull,
                                                   float* __restrict__ stats) {
  constexpr int NK = CI / 32;
  constexpr int LDW = CI + 8;
  __shared__ half_t wlds[64 * LDW];
  __shared__ float sstat[2][64];
  const int nact = cnt[0];
  const int base = blockIdx.x * 64;
  if (base >= nact) return;
  const int lane = threadIdx.x & 63, wv = threadIdx.x >> 6;
  const int srow = lane & 15, kseg = lane >> 4;
  const int co0 = blockIdx.y * 64;
  int jj[9];
  {
    int s = base + wv * 16 + srow;
    bool sv = (s < nact);
    int h = 0, w = 0, bb = 0;
    if (sv) {
      int site = list[s];
      w = site % W;
      int t = site / W;
      h = t % H;
      bb = t / H;
    }
    #pragma unroll
    for (int tap = 0; tap < 9; ++tap) {
      int j = -1;
      if (sv) {
        int hh = h + tap / 3 - 1, ww = w + tap % 3 - 1;
        if ((unsigned)hh < (unsigned)H && (unsigned)ww < (unsigned)W)
          j = inv[(bb * H + hh) * W + ww];
      }
      jj[tap] = j;
    }
  }
  if (stats) {
    for (int i = threadIdx.x; i < 128; i += TPB) ((float*)sstat)[i] = 0.f;
  }
  f32x4 acc[4];
  #pragma unroll
  for (int b = 0; b < 4; ++b) acc[b] = (f32x4){0.f, 0.f, 0.f, 0.f};
  for (int tap = 0; tap < 9; ++tap) {
    __syncthreads();
    constexpr int GR = 64 * (CI / 8);
    const half_t* wsrc = Wt + ((long)tap * COfull + co0) * CI;
    for (int idx = threadIdx.x; idx < GR; idx += TPB) {
      int row = idx / (CI / 8), cb = idx % (CI / 8);
      *(f16x8*)(&wlds[row * LDW + cb * 8]) = *(const f16x8*)(wsrc + (long)row * CI + cb * 8);
    }
    __syncthreads();
    const int j = jj[tap];
    f16x8 av[NK];
    #pragma unroll
    for (int s = 0; s < NK; ++s) {
      #pragma unroll
      for (int z = 0; z < 8; ++z) av[s][z] = (_Float16)0.f;
      if (j >= 0) av[s] = *(const f16x8*)(X + (long)j * CI + kseg * 8 + s * 32);
    }
    #pragma unroll
    for (int s = 0; s < NK; ++s) {
      #pragma unroll
      for (int b = 0; b < 4; ++b) {
        f16x8 bv = *(const f16x8*)(&wlds[(b * 16 + srow) * LDW + kseg * 8 + s * 32]);
        acc[b] = __builtin_amdgcn_mfma_f32_16x16x32_f16(av[s], bv, acc[b], 0, 0, 0);
      }
    }
  }
  #pragma unroll
  for (int b = 0; b < 4; ++b)
    #pragma unroll
    for (int r = 0; r < 4; ++r) {
      int ss = base + wv * 16 + kseg * 4 + r;
      if (ss < nact) y[(long)ss * COfull + co0 + b * 16 + srow] = (half_t)acc[b][r];
    }
  if (stats) {
    #pragma unroll
    for (int b = 0; b < 4; ++b) {
      float ps = 0.f, pq = 0.f;
      #pragma unroll
      for (int r = 0; r < 4; ++r) {
        int ss = base + wv * 16 + kseg * 4 + r;
        if (ss < nact) { float v = acc[b][r]; ps += v; pq += v * v; }
      }
      atomicAdd(&sstat[0][b * 16 + srow], ps);
      atomicAdd(&sstat[1][b * 16 + srow], pq);
    }
    __syncthreads();
    for (int i = threadIdx.x; i < 64; i += TPB) {
      atomicAdd(&stats[co0 + i], sstat[0][i]);
      atomicAdd(&stats[COfull + co0 + i], sstat[1][i]);
    }
  }
}

// ---------- fused GRU conv: 16 sites x 16 co per block (grid 70x16) ----------
template <int CI>
__global__ __launch_bounds__(256) void gruconv16_k(const half_t* __restrict__ X,
                                                   const half_t* __restrict__ Wg,
                                                   const half_t* __restrict__ Wc,
                                                   float* __restrict__ hdense,
                                                   half_t* __restrict__ hcomp,
                                                   half_t* __restrict__ dflat,
                                                   const int* __restrict__ inv,
                                                   const int* __restrict__ list,
                                                   const int* __restrict__ cnt,
                                                   int H, int W) {
  constexpr int CO = 256;
  constexpr int NK = CI / 32;
  const int nact = cnt[0];
  const int base = blockIdx.x * 16;
  if (base >= nact) return;
  __shared__ int nbr[16 * 9];
  __shared__ float red[4][16][34];
  for (int i = threadIdx.x; i < 16 * 9; i += TPB) {
    int s = i / 9, nb = i - s * 9;
    int j = -1;
    if (base + s < nact) {
      int site = list[base + s];
      int w = site % W; int t = site / W; int h = t % H; int bb = t / H;
      int hh = h + nb / 3 - 1, ww = w + nb % 3 - 1;
      if ((unsigned)hh < (unsigned)H && (unsigned)ww < (unsigned)W)
        j = inv[(bb * H + hh) * W + ww];
    }
    nbr[i] = j;
  }
  __syncthreads();
  const int lane = threadIdx.x & 63, wv = threadIdx.x >> 6;
  const int srow = lane & 15, kseg = lane >> 4;
  const int co0 = blockIdx.y * 16;
  const int t0 = (wv * 9) / 4, t1 = ((wv + 1) * 9) / 4;
  f32x4 g = {0.f, 0.f, 0.f, 0.f};
  f32x4 c = g;
  for (int tap = t0; tap < t1; ++tap) {
    int j = nbr[srow * 9 + tap];
    const half_t* xp = X + (long)j * CI + kseg * 8;
    const half_t* wgp = Wg + ((long)tap * CO + co0 + srow) * CI + kseg * 8;
    const half_t* wcp = Wc + ((long)tap * CO + co0 + srow) * CI + kseg * 8;
    f16x8 av[NK];
    #pragma unroll
    for (int s = 0; s < NK; ++s) {
      #pragma unroll
      for (int z = 0; z < 8; ++z) av[s][z] = (_Float16)0.f;
      if (j >= 0) av[s] = *(const f16x8*)(xp + s * 32);
    }
    #pragma unroll
    for (int s = 0; s < NK; ++s) {
      f16x8 bg = *(const f16x8*)(wgp + s * 32);
      f16x8 bc = *(const f16x8*)(wcp + s * 32);
      g = __builtin_amdgcn_mfma_f32_16x16x32_f16(av[s], bg, g, 0, 0, 0);
      c = __builtin_amdgcn_mfma_f32_16x16x32_f16(av[s], bc, c, 0, 0, 0);
    }
  }
  #pragma unroll
  for (int r = 0; r < 4; ++r) {
    int s = kseg * 4 + r;
    red[wv][s][srow] = g[r];
    red[wv][s][16 + srow] = c[r];
  }
  __syncthreads();
  {
    int i = threadIdx.x;
    int s = i >> 4, co = i & 15;
    float gs = red[0][s][co] + red[1][s][co] + red[2][s][co] + red[3][s][co];
    float cs = red[0][s][16 + co] + red[1][s][16 + co] + red[2][s][16 + co] + red[3][s][16 + co];
    int ss = base + s;
    if (ss < nact) {
      float u = 1.f / (1.f + expf(-gs));
      float v = u * tanhf(cs);
      if (hcomp) hcomp[(long)ss * CO + co0 + co] = (half_t)v;
      int site = list[ss];
      hdense[(long)site * CO + co0 + co] = v;
      if (dflat) {
        int b = site / 35, s2 = site - b * 35;
        dflat[(long)b * 8960 + (co0 + co) * 35 + s2] = (half_t)v;
      }
    }
  }
}

// ---------- BN apply (scale/shift computed in-kernel from raw stats) ----------
template <int C>
__global__ void bnapply_f16_k(const half_t* __restrict__ y, const int* __restrict__ cnt,
                              const float* __restrict__ stats, const float* __restrict__ gamma,
                              const float* __restrict__ beta, half_t* __restrict__ out) {
  __shared__ float sc[C], sh2[C];
  for (int c = threadIdx.x; c < C; c += TPB) {
    float n = fmaxf((float)cnt[0], 1.f);
    float mean = stats[c] / n;
    float var = fmaxf(stats[C + c] / n - mean * mean, 0.f);
    float s = gamma[c] * rsqrtf(var + 1e-4f);
    sc[c] = s;
    sh2[c] = beta[c] - mean * s;
  }
  __syncthreads();
  long total = (long)cnt[0] * C;
  for (long i = (long)blockIdx.x * TPB + threadIdx.x; i < total; i += (long)gridDim.x * TPB) {
    int c = (int)(i & (C - 1));
    out[i] = (half_t)fmaxf(fmaf((float)y[i], sc[c], sh2[c]), 0.f);
  }
}

// ---------- head: MFMA lin1 ----------
#define KS1 35
__global__ __launch_bounds__(256) void lin1m_k(const half_t* __restrict__ D,
                                               const half_t* __restrict__ W1T,
                                               float* __restrict__ part) {
  __shared__ float red[4][32][65];
  const int lane = threadIdx.x & 63, wv = threadIdx.x >> 6;
  const int srow = lane & 15, kseg = lane >> 4;
  const int kc = blockIdx.x, j0 = blockIdx.y * 64;
  const int kbase = kc * 256 + wv * 64;
  f32x4 acc[2][4];
  #pragma unroll
  for (int m = 0; m < 2; ++m)
    #pragma unroll
    for (int b = 0; b < 4; ++b) acc[m][b] = (f32x4){0.f, 0.f, 0.f, 0.f};
  #pragma unroll
  for (int step = 0; step < 2; ++step) {
    int k = kbase + step * 32 + kseg * 8;
    f16x8 a0 = *(const f16x8*)(D + (long)srow * 8960 + k);
    f16x8 a1 = *(const f16x8*)(D + (long)(16 + srow) * 8960 + k);
    #pragma unroll
    for (int b = 0; b < 4; ++b) {
      f16x8 bv = *(const f16x8*)(W1T + (long)(j0 + b * 16 + srow) * 8960 + k);
      acc[0][b] = __builtin_amdgcn_mfma_f32_16x16x32_f16(a0, bv, acc[0][b], 0, 0, 0);
      acc[1][b] = __builtin_amdgcn_mfma_f32_16x16x32_f16(a1, bv, acc[1][b], 0, 0, 0);
    }
  }
  #pragma unroll
  for (int m = 0; m < 2; ++m)
    #pragma unroll
    for (int b = 0; b < 4; ++b)
      #pragma unroll
      for (int r = 0; r < 4; ++r)
        red[wv][m * 16 + kseg * 4 + r][b * 16 + srow] = acc[m][b][r];
  __syncthreads();
  for (int i = threadIdx.x; i < 32 * 64; i += TPB) {
    int row = i >> 6, col = i & 63;
    float v = red[0][row][col] + red[1][row][col] + red[2][row][col] + red[3][row][col];
    part[(long)kc * 32768 + row * 1024 + j0 + col] = v;
  }
}

__global__ void lin1_reduce_k(const float* __restrict__ part, const float* __restrict__ b1,
                              float* __restrict__ y1) {
  int i = blockIdx.x * TPB + threadIdx.x;
  if (i >= 32 * 1024) return;
  int b = i >> 10, j = i & 1023;
  float a = b1[j];
  #pragma unroll
  for (int kc = 0; kc < KS1; ++kc) a += part[(long)kc * 32768 + b * 1024 + j];
  y1[i] = fmaxf(a, 0.f);
}

#define JS2 8
__global__ void lin2_part_k(const float* __restrict__ y1, const float* __restrict__ W2,
                            float* __restrict__ part2) {
  int i = blockIdx.x * TPB + threadIdx.x;
  if (i >= 32 * 420) return;
  int b = i / 420, o = i - b * 420;
  int j0 = blockIdx.y * 128;
  float a = 0.f;
  const float* yp = y1 + b * 1024 + j0;
  const float* wp = W2 + (long)j0 * 420 + o;
  #pragma unroll 8
  for (int j = 0; j < 128; ++j) a = fmaf(yp[j], wp[(long)j * 420], a);
  part2[(long)blockIdx.y * 13440 + i] = a;
}

__global__ void lin2_fin_k(const float* __restrict__ part2, const float* __restrict__ b2,
                           float* __restrict__ out) {
  int i = blockIdx.x * TPB + threadIdx.x;
  if (i >= 32 * 420) return;
  int o = i % 420;
  float a = b2[o];
  #pragma unroll
  for (int js = 0; js < JS2; ++js) a += part2[(long)js * 13440 + i];
  out[i] = a;
}

extern "C" void kernel_launch(void* const* d_in, const int* in_sizes, int n_in,
                              void* d_out, int out_size, void* d_ws, size_t ws_size,
                              hipStream_t stream) {
  const float* x = (const float*)d_in[0];
  const float* ca[5] = {(const float*)d_in[2], (const float*)d_in[6], (const float*)d_in[10],
                        (const float*)d_in[14], (const float*)d_in[18]};
  const float* bg[5] = {(const float*)d_in[3], (const float*)d_in[7], (const float*)d_in[11],
                        (const float*)d_in[15], (const float*)d_in[19]};
  const float* bb[5] = {(const float*)d_in[4], (const float*)d_in[8], (const float*)d_in[12],
                        (const float*)d_in[16], (const float*)d_in[20]};
  const float* cb[5] = {(const float*)d_in[5], (const float*)d_in[9], (const float*)d_in[13],
                        (const float*)d_in[17], (const float*)d_in[21]};
  const float* g1Wg = (const float*)d_in[22];
  const float* g1Wc = (const float*)d_in[23];
  const float* g2Wg = (const float*)d_in[24];
  const float* g2Wc = (const float*)d_in[25];
  const float* W1 = (const float*)d_in[26];
  const float* b1 = (const float*)d_in[27];
  const float* W2 = (const float*)d_in[28];
  const float* b2 = (const float*)d_in[29];

  const int Hs[6] = {191, 95, 47, 23, 11, 5};
  const int Wd[6] = {255, 127, 63, 31, 15, 7};
  const long NS[6] = {1558560, 386080, 94752, 22816, 5280, 1120};
  const int cap[6] = {200000, 386080, 94752, 22816, 5280, 1120};

  float* ws = (float*)d_ws;
  long off = 0;
  float* part = ws + off;  off += 1200000;
  float* part2 = ws + off; off += 120000;
  float* stats = ws + off; off += 512;
  float* y1 = ws + off;    off += 32L * 1024;

  half_t* hbase = (half_t*)(ws + off);
  long hoff = 0;
  half_t* hbufA = hbase + hoff; hoff += 6500000;
  half_t* hbufB = hbase + hoff; hoff += 6500000;
  half_t* hbufC = hbase + hoff; hoff += 6500000;
  half_t* xh = hbase + hoff;    hoff += 3117120;
  half_t* w1t = hbase + hoff;   hoff += 9175040;
  half_t* df16 = hbase + hoff;  hoff += 286720;
  half_t* wp_ca0 = hbase + hoff; hoff += 16L * 32;
  half_t* wp_cb0 = hbase + hoff; hoff += 16L * 160;
  half_t* wp_ca1 = hbase + hoff; hoff += 32L * 160;
  half_t* wp_cb1 = hbase + hoff; hoff += 32L * 288;
  half_t* wt_ca2 = hbase + hoff; hoff += 9L * 64 * 32;
  half_t* wt_cb2 = hbase + hoff; hoff += 9L * 64 * 64;
  half_t* wt_ca3 = hbase + hoff; hoff += 9L * 128 * 64;
  half_t* wt_cb3 = hbase + hoff; hoff += 9L * 128 * 128;
  half_t* wt_ca4 = hbase + hoff; hoff += 9L * 256 * 128;
  half_t* wt_cb4 = hbase + hoff; hoff += 9L * 256 * 256;
  half_t* wt_g1g = hbase + hoff; hoff += 9L * 256 * 256;
  half_t* wt_g1c = hbase + hoff; hoff += 9L * 256 * 256;
  half_t* wt_g2g = hbase + hoff; hoff += 9L * 256 * 256;
  half_t* wt_g2c = hbase + hoff; hoff += 9L * 256 * 256;

  int* ip = (int*)(hbase + hoff);
  long ioff = 0;
  int* cnt = ip + ioff; ioff += 16;
  int* bcnt = ip + ioff; ioff += 8192;
  int* list[6]; int* inv[6];
  for (int l = 0; l < 6; ++l) { list[l] = ip + ioff; ioff += cap[l]; }
  for (int l = 0; l < 6; ++l) { inv[l] = ip + ioff; ioff += NS[l]; }
  size_t needed = (size_t)off * 4 + (size_t)hoff * 2 + (size_t)ioff * 4;
  if (ws_size < needed) return;

  float* h1d = (float*)d_out + 13440;
  float* h2d = h1d + 286720;

  // ---- one-shot weight packing + W1 transpose ----
  PackArgs pa;
  pa.src[0] = ca[0]; pa.dst[0] = wp_ca0;
  pa.src[1] = cb[0]; pa.dst[1] = wp_cb0;
  pa.src[2] = ca[1]; pa.dst[2] = wp_ca1;
  pa.src[3] = cb[1]; pa.dst[3] = wp_cb1;
  pa.src[4] = ca[2]; pa.dst[4] = wt_ca2;
  pa.src[5] = cb[2]; pa.dst[5] = wt_cb2;
  pa.src[6] = ca[3]; pa.dst[6] = wt_ca3;
  pa.src[7] = cb[3]; pa.dst[7] = wt_cb3;
  pa.src[8] = ca[4]; pa.dst[8] = wt_ca4;
  pa.src[9] = cb[4]; pa.dst[9] = wt_cb4;
  pa.src[10] = g1Wg; pa.dst[10] = wt_g1g;
  pa.src[11] = g1Wc; pa.dst[11] = wt_g1c;
  pa.src[12] = g2Wg; pa.dst[12] = wt_g2g;
  pa.src[13] = g2Wc; pa.dst[13] = wt_g2c;
  packall_k<<<dim3(288, 14), TPB, 0, stream>>>(pa);
  w1tr_k<<<dim3(140, 16), TPB, 0, stream>>>(W1, w1t);
  zfill_k<<<512, TPB, 0, stream>>>(h1d, h2d, df16);

  // ---- level-0 compaction (also x->f16) ----
  {
    int nb = nblk(NS[0]);
    cmpA0_k<<<nb, TPB, 0, stream>>>(x, (int)NS[0], bcnt);
    scan_k<<<1, 1024, 0, stream>>>(bcnt, nb, cnt + 0, stats);
    cmpB0_k<<<nb, TPB, 0, stream>>>(x, (int)NS[0], bcnt, list[0], inv[0], cap[0], xh);
  }

  // ---------- level 1 ----------
  mconvp_k<2, 16, true><<<(cap[0] + 63) / 64, TPB, 0, stream>>>(
      xh, wp_ca0, hbufC, nullptr, list[0], cnt + 0, Hs[0], Wd[0], stats);
  bnapply_f16_k<16><<<2048, TPB, 0, stream>>>(hbufC, cnt + 0, stats, bg[0], bb[0], hbufA);
  mconvp_k<16, 16, false><<<(cap[0] + 63) / 64, TPB, 0, stream>>>(
      hbufA, wp_cb0, hbufC, inv[0], list[0], cnt + 0, Hs[0], Wd[0], nullptr);
  {
    int nb = nblk(NS[1]);
    poolA_k<<<nb, TPB, 0, stream>>>(inv[0], Hs[0], Wd[0], Hs[1], Wd[1], (int)NS[1], bcnt);
    scan_k<<<1, 1024, 0, stream>>>(bcnt, nb, cnt + 1, stats);
    poolB_k<<<nb, TPB, 0, stream>>>(inv[0], Hs[0], Wd[0], Hs[1], Wd[1], (int)NS[1], bcnt,
                                    list[1], inv[1], cap[1]);
  }
  pool_val_f16_k<16><<<2048, TPB, 0, stream>>>(hbufC, inv[0], list[1], cnt + 1, Hs[0], Wd[0], Hs[1], Wd[1], hbufB);

  // ---------- level 2 ----------
  mconvp_k<16, 32, false><<<(cap[1] + 63) / 64, TPB, 0, stream>>>(
      hbufB, wp_ca1, hbufC, inv[1], list[1], cnt + 1, Hs[1], Wd[1], stats);
  bnapply_f16_k<32><<<2048, TPB, 0, stream>>>(hbufC, cnt + 1, stats, bg[1], bb[1], hbufA);
  mconvp_k<32, 32, false><<<(cap[1] + 63) / 64, TPB, 0, stream>>>(
      hbufA, wp_cb1, hbufC, inv[1], list[1], cnt + 1, Hs[1], Wd[1], nullptr);
  {
    int nb = nblk(NS[2]);
    poolA_k<<<nb, TPB, 0, stream>>>(inv[1], Hs[1], Wd[1], Hs[2], Wd[2], (int)NS[2], bcnt);
    scan_k<<<1, 1024, 0, stream>>>(bcnt, nb, cnt + 2, stats);
    poolB_k<<<nb, TPB, 0, stream>>>(inv[1], Hs[1], Wd[1], Hs[2], Wd[2], (int)NS[2], bcnt,
                                    list[2], inv[2], cap[2]);
  }
  pool_val_f16_k<32><<<2048, TPB, 0, stream>>>(hbufC, inv[1], list[2], cnt + 2, Hs[1], Wd[1], Hs[2], Wd[2], hbufB);

  // ---------- level 3 (LDS-staged weights, fused stats) ----------
  mconv_lds_k<32><<<dim3((cap[2] + 63) / 64, 1), TPB, 0, stream>>>(
      hbufB, wt_ca2, hbufC, inv[2], list[2], cnt + 2, Hs[2], Wd[2], 64, stats);
  bnapply_f16_k<64><<<2048, TPB, 0, stream>>>(hbufC, cnt + 2, stats, bg[2], bb[2], hbufA);
  mconv_lds_k<64><<<dim3((cap[2] + 63) / 64, 1), TPB, 0, stream>>>(
      hbufA, wt_cb2, hbufC, inv[2], list[2], cnt + 2, Hs[2], Wd[2], 64, nullptr);
  {
    int nb = nblk(NS[3]);
    poolA_k<<<nb, TPB, 0, stream>>>(inv[2], Hs[2], Wd[2], Hs[3], Wd[3], (int)NS[3], bcnt);
    scan_k<<<1, 1024, 0, stream>>>(bcnt, nb, cnt + 3, stats);
    poolB_k<<<nb, TPB, 0, stream>>>(inv[2], Hs[2], Wd[2], Hs[3], Wd[3], (int)NS[3], bcnt,
                                    list[3], inv[3], cap[3]);
  }
  pool_val_f16_k<64><<<2048, TPB, 0, stream>>>(hbufC, inv[2], list[3], cnt + 3, Hs[2], Wd[2], Hs[3], Wd[3], hbufB);

  // ---------- level 4 (LDS-staged weights, fused stats) ----------
  mconv_lds_k<64><<<dim3((cap[3] + 63) / 64, 2), TPB, 0, stream>>>(
      hbufB, wt_ca3, hbufC, inv[3], list[3], cnt + 3, Hs[3], Wd[3], 128, stats);
  bnapply_f16_k<128><<<2048, TPB, 0, stream>>>(hbufC, cnt + 3, stats, bg[3], bb[3], hbufA);
  mconv_lds_k<128><<<dim3((cap[3] + 63) / 64, 2), TPB, 0, stream>>>(
      hbufA, wt_cb3, hbufC, inv[3], list[3], cnt + 3, Hs[3], Wd[3], 128, nullptr);
  {
    int nb = nblk(NS[4]);
    poolA_k<<<nb, TPB, 0, stream>>>(inv[3], Hs[3], Wd[3], Hs[4], Wd[4], (int)NS[4], bcnt);
    scan_k<<<1, 1024, 0, stream>>>(bcnt, nb, cnt + 4, stats);
    poolB_k<<<nb, TPB, 0, stream>>>(inv[3], Hs[3], Wd[3], Hs[4], Wd[4], (int)NS[4], bcnt,
                                    list[4], inv[4], cap[4]);
  }
  pool_val_f16_k<128><<<2048, TPB, 0, stream>>>(hbufC, inv[3], list[4], cnt + 4, Hs[3], Wd[3], Hs[4], Wd[4], hbufB);

  // ---------- level 5 (LDS-staged weights, fused stats) ----------
  mconv_lds_k<128><<<dim3((cap[4] + 63) / 64, 4), TPB, 0, stream>>>(
      hbufB, wt_ca4, hbufC, inv[4], list[4], cnt + 4, Hs[4], Wd[4], 256, stats);
  bnapply_f16_k<256><<<2048, TPB, 0, stream>>>(hbufC, cnt + 4, stats, bg[4], bb[4], hbufA);
  mconv_lds_k<256><<<dim3((cap[4] + 63) / 64, 4), TPB, 0, stream>>>(
      hbufA, wt_cb4, hbufC, inv[4], list[4], cnt + 4, Hs[4], Wd[4], 256, nullptr);
  {
    int nb = nblk(NS[5]);
    poolA_k<<<nb, TPB, 0, stream>>>(inv[4], Hs[4], Wd[4], Hs[5], Wd[5], (int)NS[5], bcnt);
    scan_k<<<1, 1024, 0, stream>>>(bcnt, nb, cnt + 5, stats);
    poolB_k<<<nb, TPB, 0, stream>>>(inv[4], Hs[4], Wd[4], Hs[5], Wd[5], (int)NS[5], bcnt,
                                    list[5], inv[5], cap[5]);
  }
  pool_val_f16_k<256><<<1024, TPB, 0, stream>>>(hbufC, inv[4], list[5], cnt + 5, Hs[4], Wd[4], Hs[5], Wd[5], hbufB);

  // ---------- GRUs (16-co tiles) ----------
  gruconv16_k<256><<<dim3((cap[5] + 15) / 16, 16), TPB, 0, stream>>>(
      hbufB, wt_g1g, wt_g1c, h1d, hbufA, nullptr, inv[5], list[5], cnt + 5, Hs[5], Wd[5]);
  gruconv16_k<256><<<dim3((cap[5] + 15) / 16, 16), TPB, 0, stream>>>(
      hbufA, wt_g2g, wt_g2c, h2d, nullptr, df16, inv[5], list[5], cnt + 5, Hs[5], Wd[5]);

  // ---------- head ----------
  lin1m_k<<<dim3(KS1, 16), TPB, 0, stream>>>(df16, w1t, part);
  lin1_reduce_k<<<nblk(32L * 1024), TPB, 0, stream>>>(part, b1, y1);
  lin2_part_k<<<dim3(nblk(32L * 420), JS2), TPB, 0, stream>>>(y1, W2, part2);
  lin2_fin_k<<<nblk(32L * 420), TPB, 0, stream>>>(part2, b2, (float*)d_out);
}

// Round 19
// 584.224 us; speedup vs baseline: 1.2018x; 1.2018x over previous
//
#include <hip/hip_runtime.h>
#include <stdint.h>

#define TPB 256

typedef _Float16 half_t;
typedef __attribute__((ext_vector_type(8))) _Float16 f16x8;
typedef __attribute__((ext_vector_type(4))) float f32x4;

static inline int nblk(long n) { return (int)((n + TPB - 1) / TPB); }
static inline int gmin(long a, long b) { return (int)(a < b ? a : b); }

// ---------- scan-based compaction ----------
__global__ void cmpA0_k(const float* __restrict__ x, int n, int* __restrict__ bcnt) {
  int i = blockIdx.x * TPB + threadIdx.x;
  bool a = false;
  if (i < n) {
    float2 v = *(const float2*)(x + 2L * i);
    a = (v.x != 0.f) || (v.y != 0.f);
  }
  unsigned long long bal = __ballot(a);
  __shared__ int wc[4];
  if ((threadIdx.x & 63) == 0) wc[threadIdx.x >> 6] = __popcll(bal);
  __syncthreads();
  if (threadIdx.x == 0) bcnt[blockIdx.x] = wc[0] + wc[1] + wc[2] + wc[3];
}

// also converts x -> f16
__global__ void cmpB0_k(const float* __restrict__ x, int n, const int* __restrict__ bbase,
                        int* __restrict__ list, int* __restrict__ inv, int cap,
                        half_t* __restrict__ xh) {
  int i = blockIdx.x * TPB + threadIdx.x;
  float2 v = {0.f, 0.f};
  bool a = false;
  if (i < n) {
    v = *(const float2*)(x + 2L * i);
    a = (v.x != 0.f) || (v.y != 0.f);
  }
  unsigned long long bal = __ballot(a);
  __shared__ int wc[4];
  int wid = threadIdx.x >> 6, lane = threadIdx.x & 63;
  if (lane == 0) wc[wid] = __popcll(bal);
  __syncthreads();
  int base = bbase[blockIdx.x];
  for (int w = 0; w < wid; ++w) base += wc[w];
  if (i < n) {
    xh[2L * i] = (half_t)v.x;
    xh[2L * i + 1] = (half_t)v.y;
    int pos = base + __popcll(bal & ((1ull << lane) - 1));
    if (a && pos < cap) { list[pos] = i; inv[i] = pos; }
    else inv[i] = -1;
  }
}

__device__ __forceinline__ bool actp(const int* invp, int Hp, int Wp, int Ho, int Wo, int i) {
  int wo = i % Wo; int t = i / Wo; int ho = t % Ho; int bb = t / Ho;
  long rb = ((long)bb * Hp + 2 * ho) * Wp + 2 * wo;
  bool a = false;
  #pragma unroll
  for (int kh = 0; kh < 3; ++kh)
    #pragma unroll
    for (int kw = 0; kw < 3; ++kw)
      a |= (invp[rb + kh * Wp + kw] >= 0);
  return a;
}

__global__ void poolA_k(const int* __restrict__ invp, int Hp, int Wp, int Ho, int Wo,
                        int n, int* __restrict__ bcnt) {
  int i = blockIdx.x * TPB + threadIdx.x;
  bool a = (i < n) && actp(invp, Hp, Wp, Ho, Wo, i);
  unsigned long long bal = __ballot(a);
  __shared__ int wc[4];
  if ((threadIdx.x & 63) == 0) wc[threadIdx.x >> 6] = __popcll(bal);
  __syncthreads();
  if (threadIdx.x == 0) bcnt[blockIdx.x] = wc[0] + wc[1] + wc[2] + wc[3];
}

__global__ void poolB_k(const int* __restrict__ invp, int Hp, int Wp, int Ho, int Wo, int n,
                        const int* __restrict__ bbase, int* __restrict__ list,
                        int* __restrict__ inv, int cap) {
  int i = blockIdx.x * TPB + threadIdx.x;
  bool a = (i < n) && actp(invp, Hp, Wp, Ho, Wo, i);
  unsigned long long bal = __ballot(a);
  __shared__ int wc[4];
  int wid = threadIdx.x >> 6, lane = threadIdx.x & 63;
  if (lane == 0) wc[wid] = __popcll(bal);
  __syncthreads();
  int base = bbase[blockIdx.x];
  for (int w = 0; w < wid; ++w) base += wc[w];
  if (i < n) {
    int pos = base + __popcll(bal & ((1ull << lane) - 1));
    if (a && pos < cap) { list[pos] = i; inv[i] = pos; }
    else inv[i] = -1;
  }
}

// exclusive scan; total -> *total; zeroes stats
__global__ void scan_k(int* __restrict__ b, int n, int* __restrict__ total,
                       float* __restrict__ stats) {
  __shared__ int sh[1024];
  __shared__ int sc;
  if (threadIdx.x < 512) stats[threadIdx.x] = 0.f;
  if (threadIdx.x == 0) sc = 0;
  __syncthreads();
  for (int base = 0; base < n; base += 1024) {
    int i = base + threadIdx.x;
    int v = (i < n) ? b[i] : 0;
    sh[threadIdx.x] = v;
    __syncthreads();
    for (int o = 1; o < 1024; o <<= 1) {
      int t = (threadIdx.x >= o) ? sh[threadIdx.x - o] : 0;
      __syncthreads();
      sh[threadIdx.x] += t;
      __syncthreads();
    }
    if (i < n) b[i] = sh[threadIdx.x] - v + sc;
    __syncthreads();
    if (threadIdx.x == 0) sc += sh[1023];
    __syncthreads();
  }
  if (threadIdx.x == 0) *total = sc;
}

// ---------- pooled values (f16 in/out, vectorized f16x8) ----------
template <int C>
__global__ void pool_val_f16_k(const half_t* __restrict__ xin, const int* __restrict__ invp,
                               const int* __restrict__ list, const int* __restrict__ cnt,
                               int Hp, int Wp, int Ho, int Wo, half_t* __restrict__ y) {
  constexpr int CV = C / 8;
  long total = (long)cnt[0] * CV;
  for (long i = (long)blockIdx.x * TPB + threadIdx.x; i < total; i += (long)gridDim.x * TPB) {
    int cb = (int)(i & (CV - 1));
    int r = (int)(i / CV);
    int site = list[r];
    int wo = site % Wo; int t = site / Wo; int ho = t % Ho; int bb = t / Ho;
    long rb = ((long)bb * Hp + 2 * ho) * Wp + 2 * wo;
    float best[8];
    #pragma unroll
    for (int z = 0; z < 8; ++z) best[z] = -1e30f;
    #pragma unroll
    for (int kh = 0; kh < 3; ++kh)
      #pragma unroll
      for (int kw = 0; kw < 3; ++kw) {
        int j = invp[rb + kh * Wp + kw];
        if (j >= 0) {
          f16x8 v = *(const f16x8*)(xin + (long)j * C + cb * 8);
          #pragma unroll
          for (int z = 0; z < 8; ++z) best[z] = fmaxf(best[z], (float)v[z]);
        }
      }
    f16x8 o;
    #pragma unroll
    for (int z = 0; z < 8; ++z) o[z] = (half_t)best[z];
    *(f16x8*)(y + (long)r * C + cb * 8) = o;
  }
}

// ---------- mega weight pack ----------
struct PackArgs {
  const float* src[14];
  half_t* dst[14];
};

__global__ void packall_k(PackArgs pa) {
  const int seg = blockIdx.y;
  const int tci[14]  = {2, 16, 16, 32, 32, 64, 64, 128, 128, 256, 256, 256, 256, 256};
  const int tco[14]  = {16, 16, 32, 32, 64, 64, 128, 128, 256, 256, 256, 256, 256, 256};
  const int tkp[14]  = {32, 160, 160, 288, 0, 0, 0, 0, 0, 0, 0, 0, 0, 0};
  const int twci[14] = {2, 16, 16, 32, 32, 64, 64, 128, 128, 256, 512, 512, 512, 512};
  const int twco[14] = {16, 16, 32, 32, 64, 64, 128, 128, 256, 256, 512, 256, 512, 256};
  const int CI = tci[seg], CO = tco[seg], KP = tkp[seg];
  const int wci = twci[seg], wco = twco[seg];
  const float* __restrict__ src = pa.src[seg];
  half_t* __restrict__ dst = pa.dst[seg];
  if (KP > 0) {
    long total = (long)CO * KP;
    for (long i = (long)blockIdx.x * TPB + threadIdx.x; i < total; i += (long)gridDim.x * TPB) {
      int k = (int)(i % KP), co = (int)(i / KP);
      int tap = k / CI, ci = k - tap * CI;
      float v = (tap < 9) ? src[((long)tap * wci + ci) * wco + co] : 0.f;
      dst[i] = (half_t)v;
    }
  } else {
    long total = 9L * CO * CI;
    for (long i = (long)blockIdx.x * TPB + threadIdx.x; i < total; i += (long)gridDim.x * TPB) {
      int ci = (int)(i % CI);
      long t = i / CI;
      int co = (int)(t % CO);
      int tap = (int)(t / CO);
      dst[i] = (half_t)src[((long)tap * wci + ci) * wco + co];
    }
  }
}

__global__ void w1tr_k(const float* __restrict__ W1, half_t* __restrict__ w1t) {
  __shared__ float tile[64][65];
  int k0 = blockIdx.x * 64, j0 = blockIdx.y * 64;
  for (int i = threadIdx.x; i < 4096; i += TPB) {
    int r = i >> 6, c = i & 63;
    tile[r][c] = W1[(long)(k0 + r) * 1024 + j0 + c];
  }
  __syncthreads();
  for (int i = threadIdx.x; i < 4096; i += TPB) {
    int r = i >> 6, c = i & 63;
    w1t[(long)(j0 + r) * 8960 + k0 + c] = (half_t)tile[c][r];
  }
}

// ---------- zero-fill dense GRU outputs + dflat ----------
__global__ void zfill_k(float* __restrict__ h1, float* __restrict__ h2,
                        half_t* __restrict__ df) {
  for (long i = (long)blockIdx.x * TPB + threadIdx.x; i < 286720; i += (long)gridDim.x * TPB) {
    h1[i] = 0.f;
    h2[i] = 0.f;
    df[i] = (half_t)0.f;
  }
}

// ---------- K-packed MFMA conv (CO<=32); 64 sites/block; f16 out ----------
template <int CI, int CO, bool DENSE>
__global__ __launch_bounds__(256) void mconvp_k(const half_t* __restrict__ X,
                                                const half_t* __restrict__ Wt,
                                                half_t* __restrict__ y,
                                                const int* __restrict__ inv,
                                                const int* __restrict__ list,
                                                const int* __restrict__ cnt,
                                                int H, int W) {
  constexpr int KP = ((9 * CI + 31) / 32) * 32;
  constexpr int NCO = CO / 16;
  const int nact = cnt[0];
  const int base = blockIdx.x * 64;
  if (base >= nact) return;
  __shared__ int nbr[64 * 9];
  for (int i = threadIdx.x; i < 64 * 9; i += TPB) {
    int s = i / 9, nb = i - s * 9;
    int j = -1;
    if (base + s < nact) {
      int site = list[base + s];
      int w = site % W; int t = site / W; int h = t % H; int bb = t / H;
      int hh = h + nb / 3 - 1, ww = w + nb % 3 - 1;
      if ((unsigned)hh < (unsigned)H && (unsigned)ww < (unsigned)W) {
        int ss = (bb * H + hh) * W + ww;
        j = DENSE ? ss : inv[ss];
      }
    }
    nbr[i] = j;
  }
  __syncthreads();
  const int lane = threadIdx.x & 63, wv = threadIdx.x >> 6;
  const int srow = lane & 15, kseg = lane >> 4;
  const int sloc = wv * 16 + srow;
  f32x4 acc[NCO];
  #pragma unroll
  for (int c = 0; c < NCO; ++c) acc[c] = (f32x4){0.f, 0.f, 0.f, 0.f};
  #pragma unroll
  for (int k0 = 0; k0 < KP; k0 += 32) {
    const int k = k0 + kseg * 8;
    f16x8 av;
    #pragma unroll
    for (int z = 0; z < 8; ++z) av[z] = (_Float16)0.f;
    if (CI >= 8) {
      int tap = k / CI;
      int ci = k - tap * CI;
      if (tap < 9) {
        int j = nbr[sloc * 9 + tap];
        if (j >= 0) av = *(const f16x8*)(X + (long)j * CI + ci);
      }
    } else {  // CI == 2
      #pragma unroll
      for (int q = 0; q < 4; ++q) {
        int kk = k + 2 * q;
        int tap = kk >> 1;
        if (tap < 9) {
          int j = nbr[sloc * 9 + tap];
          if (j >= 0) {
            const half_t* xp = X + (long)j * 2;
            av[2 * q] = xp[0];
            av[2 * q + 1] = xp[1];
          }
        }
      }
    }
    #pragma unroll
    for (int c = 0; c < NCO; ++c) {
      f16x8 bv = *(const f16x8*)(Wt + (long)(c * 16 + srow) * KP + k);
      acc[c] = __builtin_amdgcn_mfma_f32_16x16x32_f16(av, bv, acc[c], 0, 0, 0);
    }
  }
  #pragma unroll
  for (int c = 0; c < NCO; ++c)
    #pragma unroll
    for (int r = 0; r < 4; ++r) {
      int ss = base + wv * 16 + kseg * 4 + r;
      if (ss < nact) y[(long)ss * CO + c * 16 + srow] = (half_t)acc[c][r];
    }
}

// ---------- LDS-staged-weight conv: 64 sites x 64 co per block, W[tap] in LDS ----------
template <int CI>
__global__ __launch_bounds__(256) void mconv_lds_k(const half_t* __restrict__ X,
                                                   const half_t* __restrict__ Wt,
                                                   half_t* __restrict__ y,
                                                   const int* __restrict__ inv,
                                                   const int* __restrict__ list,
                                                   const int* __restrict__ cnt,
                                                   int H, int W, int COfull) {
  constexpr int NK = CI / 32;
  constexpr int LDW = CI + 8;
  __shared__ half_t wlds[64 * LDW];
  const int nact = cnt[0];
  const int base = blockIdx.x * 64;
  if (base >= nact) return;
  const int lane = threadIdx.x & 63, wv = threadIdx.x >> 6;
  const int srow = lane & 15, kseg = lane >> 4;
  const int co0 = blockIdx.y * 64;
  int jj[9];
  {
    int s = base + wv * 16 + srow;
    bool sv = (s < nact);
    int h = 0, w = 0, bb = 0;
    if (sv) {
      int site = list[s];
      w = site % W;
      int t = site / W;
      h = t % H;
      bb = t / H;
    }
    #pragma unroll
    for (int tap = 0; tap < 9; ++tap) {
      int j = -1;
      if (sv) {
        int hh = h + tap / 3 - 1, ww = w + tap % 3 - 1;
        if ((unsigned)hh < (unsigned)H && (unsigned)ww < (unsigned)W)
          j = inv[(bb * H + hh) * W + ww];
      }
      jj[tap] = j;
    }
  }
  f32x4 acc[4];
  #pragma unroll
  for (int b = 0; b < 4; ++b) acc[b] = (f32x4){0.f, 0.f, 0.f, 0.f};
  for (int tap = 0; tap < 9; ++tap) {
    __syncthreads();
    constexpr int GR = 64 * (CI / 8);
    const half_t* wsrc = Wt + ((long)tap * COfull + co0) * CI;
    for (int idx = threadIdx.x; idx < GR; idx += TPB) {
      int row = idx / (CI / 8), cb = idx % (CI / 8);
      *(f16x8*)(&wlds[row * LDW + cb * 8]) = *(const f16x8*)(wsrc + (long)row * CI + cb * 8);
    }
    __syncthreads();
    const int j = jj[tap];
    f16x8 av[NK];
    #pragma unroll
    for (int s = 0; s < NK; ++s) {
      #pragma unroll
      for (int z = 0; z < 8; ++z) av[s][z] = (_Float16)0.f;
      if (j >= 0) av[s] = *(const f16x8*)(X + (long)j * CI + kseg * 8 + s * 32);
    }
    #pragma unroll
    for (int s = 0; s < NK; ++s) {
      #pragma unroll
      for (int b = 0; b < 4; ++b) {
        f16x8 bv = *(const f16x8*)(&wlds[(b * 16 + srow) * LDW + kseg * 8 + s * 32]);
        acc[b] = __builtin_amdgcn_mfma_f32_16x16x32_f16(av[s], bv, acc[b], 0, 0, 0);
      }
    }
  }
  #pragma unroll
  for (int b = 0; b < 4; ++b)
    #pragma unroll
    for (int r = 0; r < 4; ++r) {
      int ss = base + wv * 16 + kseg * 4 + r;
      if (ss < nact) y[(long)ss * COfull + co0 + b * 16 + srow] = (half_t)acc[b][r];
    }
}

// ---------- fused GRU conv: 16 sites x 16 co per block (grid 70x16) ----------
template <int CI>
__global__ __launch_bounds__(256) void gruconv16_k(const half_t* __restrict__ X,
                                                   const half_t* __restrict__ Wg,
                                                   const half_t* __restrict__ Wc,
                                                   float* __restrict__ hdense,
                                                   half_t* __restrict__ hcomp,
                                                   half_t* __restrict__ dflat,
                                                   const int* __restrict__ inv,
                                                   const int* __restrict__ list,
                                                   const int* __restrict__ cnt,
                                                   int H, int W) {
  constexpr int CO = 256;
  constexpr int NK = CI / 32;
  const int nact = cnt[0];
  const int base = blockIdx.x * 16;
  if (base >= nact) return;
  __shared__ int nbr[16 * 9];
  __shared__ float red[4][16][34];
  for (int i = threadIdx.x; i < 16 * 9; i += TPB) {
    int s = i / 9, nb = i - s * 9;
    int j = -1;
    if (base + s < nact) {
      int site = list[base + s];
      int w = site % W; int t = site / W; int h = t % H; int bb = t / H;
      int hh = h + nb / 3 - 1, ww = w + nb % 3 - 1;
      if ((unsigned)hh < (unsigned)H && (unsigned)ww < (unsigned)W)
        j = inv[(bb * H + hh) * W + ww];
    }
    nbr[i] = j;
  }
  __syncthreads();
  const int lane = threadIdx.x & 63, wv = threadIdx.x >> 6;
  const int srow = lane & 15, kseg = lane >> 4;
  const int co0 = blockIdx.y * 16;
  const int t0 = (wv * 9) / 4, t1 = ((wv + 1) * 9) / 4;
  f32x4 g = {0.f, 0.f, 0.f, 0.f};
  f32x4 c = g;
  for (int tap = t0; tap < t1; ++tap) {
    int j = nbr[srow * 9 + tap];
    const half_t* xp = X + (long)j * CI + kseg * 8;
    const half_t* wgp = Wg + ((long)tap * CO + co0 + srow) * CI + kseg * 8;
    const half_t* wcp = Wc + ((long)tap * CO + co0 + srow) * CI + kseg * 8;
    f16x8 av[NK];
    #pragma unroll
    for (int s = 0; s < NK; ++s) {
      #pragma unroll
      for (int z = 0; z < 8; ++z) av[s][z] = (_Float16)0.f;
      if (j >= 0) av[s] = *(const f16x8*)(xp + s * 32);
    }
    #pragma unroll
    for (int s = 0; s < NK; ++s) {
      f16x8 bg = *(const f16x8*)(wgp + s * 32);
      f16x8 bc = *(const f16x8*)(wcp + s * 32);
      g = __builtin_amdgcn_mfma_f32_16x16x32_f16(av[s], bg, g, 0, 0, 0);
      c = __builtin_amdgcn_mfma_f32_16x16x32_f16(av[s], bc, c, 0, 0, 0);
    }
  }
  #pragma unroll
  for (int r = 0; r < 4; ++r) {
    int s = kseg * 4 + r;
    red[wv][s][srow] = g[r];
    red[wv][s][16 + srow] = c[r];
  }
  __syncthreads();
  {
    int i = threadIdx.x;
    int s = i >> 4, co = i & 15;
    float gs = red[0][s][co] + red[1][s][co] + red[2][s][co] + red[3][s][co];
    float cs = red[0][s][16 + co] + red[1][s][16 + co] + red[2][s][16 + co] + red[3][s][16 + co];
    int ss = base + s;
    if (ss < nact) {
      float u = 1.f / (1.f + expf(-gs));
      float v = u * tanhf(cs);
      if (hcomp) hcomp[(long)ss * CO + co0 + co] = (half_t)v;
      int site = list[ss];
      hdense[(long)site * CO + co0 + co] = v;
      if (dflat) {
        int b = site / 35, s2 = site - b * 35;
        dflat[(long)b * 8960 + (co0 + co) * 35 + s2] = (half_t)v;
      }
    }
  }
}

// ---------- BN (f16 activations) ----------
template <int CO>
__global__ void bn_stats2_k(const half_t* __restrict__ y, const int* __restrict__ cnt,
                            float* __restrict__ stats) {
  __shared__ float ls[512];
  for (int i = threadIdx.x; i < 2 * CO; i += TPB) ls[i] = 0.f;
  __syncthreads();
  long total = (long)cnt[0] * CO;
  long i0 = (long)blockIdx.x * TPB + threadIdx.x;
  int c = (int)(i0 & (CO - 1));
  float s = 0.f, s2 = 0.f;
  for (long i = i0; i < total; i += (long)gridDim.x * TPB) {
    float v = (float)y[i];
    s += v; s2 += v * v;
  }
  atomicAdd(&ls[c], s);
  atomicAdd(&ls[CO + c], s2);
  __syncthreads();
  for (int i = threadIdx.x; i < 2 * CO; i += TPB) atomicAdd(&stats[i], ls[i]);
}

template <int C>
__global__ void bnapply_f16_k(const half_t* __restrict__ y, const int* __restrict__ cnt,
                              const float* __restrict__ stats, const float* __restrict__ gamma,
                              const float* __restrict__ beta, half_t* __restrict__ out) {
  __shared__ float sc[C], sh2[C];
  for (int c = threadIdx.x; c < C; c += TPB) {
    float n = fmaxf((float)cnt[0], 1.f);
    float mean = stats[c] / n;
    float var = fmaxf(stats[C + c] / n - mean * mean, 0.f);
    float s = gamma[c] * rsqrtf(var + 1e-4f);
    sc[c] = s;
    sh2[c] = beta[c] - mean * s;
  }
  __syncthreads();
  long total = (long)cnt[0] * C;
  for (long i = (long)blockIdx.x * TPB + threadIdx.x; i < total; i += (long)gridDim.x * TPB) {
    int c = (int)(i & (C - 1));
    out[i] = (half_t)fmaxf(fmaf((float)y[i], sc[c], sh2[c]), 0.f);
  }
}

// ---------- head: MFMA lin1 ----------
#define KS1 35
__global__ __launch_bounds__(256) void lin1m_k(const half_t* __restrict__ D,
                                               const half_t* __restrict__ W1T,
                                               float* __restrict__ part) {
  __shared__ float red[4][32][65];
  const int lane = threadIdx.x & 63, wv = threadIdx.x >> 6;
  const int srow = lane & 15, kseg = lane >> 4;
  const int kc = blockIdx.x, j0 = blockIdx.y * 64;
  const int kbase = kc * 256 + wv * 64;
  f32x4 acc[2][4];
  #pragma unroll
  for (int m = 0; m < 2; ++m)
    #pragma unroll
    for (int b = 0; b < 4; ++b) acc[m][b] = (f32x4){0.f, 0.f, 0.f, 0.f};
  #pragma unroll
  for (int step = 0; step < 2; ++step) {
    int k = kbase + step * 32 + kseg * 8;
    f16x8 a0 = *(const f16x8*)(D + (long)srow * 8960 + k);
    f16x8 a1 = *(const f16x8*)(D + (long)(16 + srow) * 8960 + k);
    #pragma unroll
    for (int b = 0; b < 4; ++b) {
      f16x8 bv = *(const f16x8*)(W1T + (long)(j0 + b * 16 + srow) * 8960 + k);
      acc[0][b] = __builtin_amdgcn_mfma_f32_16x16x32_f16(a0, bv, acc[0][b], 0, 0, 0);
      acc[1][b] = __builtin_amdgcn_mfma_f32_16x16x32_f16(a1, bv, acc[1][b], 0, 0, 0);
    }
  }
  #pragma unroll
  for (int m = 0; m < 2; ++m)
    #pragma unroll
    for (int b = 0; b < 4; ++b)
      #pragma unroll
      for (int r = 0; r < 4; ++r)
        red[wv][m * 16 + kseg * 4 + r][b * 16 + srow] = acc[m][b][r];
  __syncthreads();
  for (int i = threadIdx.x; i < 32 * 64; i += TPB) {
    int row = i >> 6, col = i & 63;
    float v = red[0][row][col] + red[1][row][col] + red[2][row][col] + red[3][row][col];
    part[(long)kc * 32768 + row * 1024 + j0 + col] = v;
  }
}

__global__ void lin1_reduce_k(const float* __restrict__ part, const float* __restrict__ b1,
                              float* __restrict__ y1) {
  int i = blockIdx.x * TPB + threadIdx.x;
  if (i >= 32 * 1024) return;
  int b = i >> 10, j = i & 1023;
  float a = b1[j];
  #pragma unroll
  for (int kc = 0; kc < KS1; ++kc) a += part[(long)kc * 32768 + b * 1024 + j];
  y1[i] = fmaxf(a, 0.f);
}

#define JS2 8
__global__ void lin2_part_k(const float* __restrict__ y1, const float* __restrict__ W2,
                            float* __restrict__ part2) {
  int i = blockIdx.x * TPB + threadIdx.x;
  if (i >= 32 * 420) return;
  int b = i / 420, o = i - b * 420;
  int j0 = blockIdx.y * 128;
  float a = 0.f;
  const float* yp = y1 + b * 1024 + j0;
  const float* wp = W2 + (long)j0 * 420 + o;
  #pragma unroll 8
  for (int j = 0; j < 128; ++j) a = fmaf(yp[j], wp[(long)j * 420], a);
  part2[(long)blockIdx.y * 13440 + i] = a;
}

__global__ void lin2_fin_k(const float* __restrict__ part2, const float* __restrict__ b2,
                           float* __restrict__ out) {
  int i = blockIdx.x * TPB + threadIdx.x;
  if (i >= 32 * 420) return;
  int o = i % 420;
  float a = b2[o];
  #pragma unroll
  for (int js = 0; js < JS2; ++js) a += part2[(long)js * 13440 + i];
  out[i] = a;
}

extern "C" void kernel_launch(void* const* d_in, const int* in_sizes, int n_in,
                              void* d_out, int out_size, void* d_ws, size_t ws_size,
                              hipStream_t stream) {
  const float* x = (const float*)d_in[0];
  const float* ca[5] = {(const float*)d_in[2], (const float*)d_in[6], (const float*)d_in[10],
                        (const float*)d_in[14], (const float*)d_in[18]};
  const float* bg[5] = {(const float*)d_in[3], (const float*)d_in[7], (const float*)d_in[11],
                        (const float*)d_in[15], (const float*)d_in[19]};
  const float* bb[5] = {(const float*)d_in[4], (const float*)d_in[8], (const float*)d_in[12],
                        (const float*)d_in[16], (const float*)d_in[20]};
  const float* cb[5] = {(const float*)d_in[5], (const float*)d_in[9], (const float*)d_in[13],
                        (const float*)d_in[17], (const float*)d_in[21]};
  const float* g1Wg = (const float*)d_in[22];
  const float* g1Wc = (const float*)d_in[23];
  const float* g2Wg = (const float*)d_in[24];
  const float* g2Wc = (const float*)d_in[25];
  const float* W1 = (const float*)d_in[26];
  const float* b1 = (const float*)d_in[27];
  const float* W2 = (const float*)d_in[28];
  const float* b2 = (const float*)d_in[29];

  const int Hs[6] = {191, 95, 47, 23, 11, 5};
  const int Wd[6] = {255, 127, 63, 31, 15, 7};
  const long NS[6] = {1558560, 386080, 94752, 22816, 5280, 1120};
  const int cap[6] = {200000, 386080, 94752, 22816, 5280, 1120};

  float* ws = (float*)d_ws;
  long off = 0;
  float* part = ws + off;  off += 1200000;
  float* part2 = ws + off; off += 120000;
  float* stats = ws + off; off += 512;
  float* y1 = ws + off;    off += 32L * 1024;

  half_t* hbase = (half_t*)(ws + off);
  long hoff = 0;
  half_t* hbufA = hbase + hoff; hoff += 6500000;
  half_t* hbufB = hbase + hoff; hoff += 6500000;
  half_t* hbufC = hbase + hoff; hoff += 6500000;
  half_t* xh = hbase + hoff;    hoff += 3117120;
  half_t* w1t = hbase + hoff;   hoff += 9175040;
  half_t* df16 = hbase + hoff;  hoff += 286720;
  half_t* wp_ca0 = hbase + hoff; hoff += 16L * 32;
  half_t* wp_cb0 = hbase + hoff; hoff += 16L * 160;
  half_t* wp_ca1 = hbase + hoff; hoff += 32L * 160;
  half_t* wp_cb1 = hbase + hoff; hoff += 32L * 288;
  half_t* wt_ca2 = hbase + hoff; hoff += 9L * 64 * 32;
  half_t* wt_cb2 = hbase + hoff; hoff += 9L * 64 * 64;
  half_t* wt_ca3 = hbase + hoff; hoff += 9L * 128 * 64;
  half_t* wt_cb3 = hbase + hoff; hoff += 9L * 128 * 128;
  half_t* wt_ca4 = hbase + hoff; hoff += 9L * 256 * 128;
  half_t* wt_cb4 = hbase + hoff; hoff += 9L * 256 * 256;
  half_t* wt_g1g = hbase + hoff; hoff += 9L * 256 * 256;
  half_t* wt_g1c = hbase + hoff; hoff += 9L * 256 * 256;
  half_t* wt_g2g = hbase + hoff; hoff += 9L * 256 * 256;
  half_t* wt_g2c = hbase + hoff; hoff += 9L * 256 * 256;

  int* ip = (int*)(hbase + hoff);
  long ioff = 0;
  int* cnt = ip + ioff; ioff += 16;
  int* bcnt = ip + ioff; ioff += 8192;
  int* list[6]; int* inv[6];
  for (int l = 0; l < 6; ++l) { list[l] = ip + ioff; ioff += cap[l]; }
  for (int l = 0; l < 6; ++l) { inv[l] = ip + ioff; ioff += NS[l]; }
  size_t needed = (size_t)off * 4 + (size_t)hoff * 2 + (size_t)ioff * 4;
  if (ws_size < needed) return;

  float* h1d = (float*)d_out + 13440;
  float* h2d = h1d + 286720;

  // ---- one-shot weight packing + W1 transpose ----
  PackArgs pa;
  pa.src[0] = ca[0]; pa.dst[0] = wp_ca0;
  pa.src[1] = cb[0]; pa.dst[1] = wp_cb0;
  pa.src[2] = ca[1]; pa.dst[2] = wp_ca1;
  pa.src[3] = cb[1]; pa.dst[3] = wp_cb1;
  pa.src[4] = ca[2]; pa.dst[4] = wt_ca2;
  pa.src[5] = cb[2]; pa.dst[5] = wt_cb2;
  pa.src[6] = ca[3]; pa.dst[6] = wt_ca3;
  pa.src[7] = cb[3]; pa.dst[7] = wt_cb3;
  pa.src[8] = ca[4]; pa.dst[8] = wt_ca4;
  pa.src[9] = cb[4]; pa.dst[9] = wt_cb4;
  pa.src[10] = g1Wg; pa.dst[10] = wt_g1g;
  pa.src[11] = g1Wc; pa.dst[11] = wt_g1c;
  pa.src[12] = g2Wg; pa.dst[12] = wt_g2g;
  pa.src[13] = g2Wc; pa.dst[13] = wt_g2c;
  packall_k<<<dim3(288, 14), TPB, 0, stream>>>(pa);
  w1tr_k<<<dim3(140, 16), TPB, 0, stream>>>(W1, w1t);
  zfill_k<<<512, TPB, 0, stream>>>(h1d, h2d, df16);

  // ---- level-0 compaction (also x->f16) ----
  {
    int nb = nblk(NS[0]);
    cmpA0_k<<<nb, TPB, 0, stream>>>(x, (int)NS[0], bcnt);
    scan_k<<<1, 1024, 0, stream>>>(bcnt, nb, cnt + 0, stats);
    cmpB0_k<<<nb, TPB, 0, stream>>>(x, (int)NS[0], bcnt, list[0], inv[0], cap[0], xh);
  }

  // ---------- level 1 ----------
  mconvp_k<2, 16, true><<<(cap[0] + 63) / 64, TPB, 0, stream>>>(
      xh, wp_ca0, hbufC, nullptr, list[0], cnt + 0, Hs[0], Wd[0]);
  bn_stats2_k<16><<<288, TPB, 0, stream>>>(hbufC, cnt + 0, stats);
  bnapply_f16_k<16><<<2048, TPB, 0, stream>>>(hbufC, cnt + 0, stats, bg[0], bb[0], hbufA);
  mconvp_k<16, 16, false><<<(cap[0] + 63) / 64, TPB, 0, stream>>>(
      hbufA, wp_cb0, hbufC, inv[0], list[0], cnt + 0, Hs[0], Wd[0]);
  {
    int nb = nblk(NS[1]);
    poolA_k<<<nb, TPB, 0, stream>>>(inv[0], Hs[0], Wd[0], Hs[1], Wd[1], (int)NS[1], bcnt);
    scan_k<<<1, 1024, 0, stream>>>(bcnt, nb, cnt + 1, stats);
    poolB_k<<<nb, TPB, 0, stream>>>(inv[0], Hs[0], Wd[0], Hs[1], Wd[1], (int)NS[1], bcnt,
                                    list[1], inv[1], cap[1]);
  }
  pool_val_f16_k<16><<<1024, TPB, 0, stream>>>(hbufC, inv[0], list[1], cnt + 1, Hs[0], Wd[0], Hs[1], Wd[1], hbufB);

  // ---------- level 2 ----------
  mconvp_k<16, 32, false><<<(cap[1] + 63) / 64, TPB, 0, stream>>>(
      hbufB, wp_ca1, hbufC, inv[1], list[1], cnt + 1, Hs[1], Wd[1]);
  bn_stats2_k<32><<<288, TPB, 0, stream>>>(hbufC, cnt + 1, stats);
  bnapply_f16_k<32><<<2048, TPB, 0, stream>>>(hbufC, cnt + 1, stats, bg[1], bb[1], hbufA);
  mconvp_k<32, 32, false><<<(cap[1] + 63) / 64, TPB, 0, stream>>>(
      hbufA, wp_cb1, hbufC, inv[1], list[1], cnt + 1, Hs[1], Wd[1]);
  {
    int nb = nblk(NS[2]);
    poolA_k<<<nb, TPB, 0, stream>>>(inv[1], Hs[1], Wd[1], Hs[2], Wd[2], (int)NS[2], bcnt);
    scan_k<<<1, 1024, 0, stream>>>(bcnt, nb, cnt + 2, stats);
    poolB_k<<<nb, TPB, 0, stream>>>(inv[1], Hs[1], Wd[1], Hs[2], Wd[2], (int)NS[2], bcnt,
                                    list[2], inv[2], cap[2]);
  }
  pool_val_f16_k<32><<<1024, TPB, 0, stream>>>(hbufC, inv[1], list[2], cnt + 2, Hs[1], Wd[1], Hs[2], Wd[2], hbufB);

  // ---------- level 3 (LDS-staged weights) ----------
  mconv_lds_k<32><<<dim3((cap[2] + 63) / 64, 1), TPB, 0, stream>>>(
      hbufB, wt_ca2, hbufC, inv[2], list[2], cnt + 2, Hs[2], Wd[2], 64);
  bn_stats2_k<64><<<288, TPB, 0, stream>>>(hbufC, cnt + 2, stats);
  bnapply_f16_k<64><<<2048, TPB, 0, stream>>>(hbufC, cnt + 2, stats, bg[2], bb[2], hbufA);
  mconv_lds_k<64><<<dim3((cap[2] + 63) / 64, 1), TPB, 0, stream>>>(
      hbufA, wt_cb2, hbufC, inv[2], list[2], cnt + 2, Hs[2], Wd[2], 64);
  {
    int nb = nblk(NS[3]);
    poolA_k<<<nb, TPB, 0, stream>>>(inv[2], Hs[2], Wd[2], Hs[3], Wd[3], (int)NS[3], bcnt);
    scan_k<<<1, 1024, 0, stream>>>(bcnt, nb, cnt + 3, stats);
    poolB_k<<<nb, TPB, 0, stream>>>(inv[2], Hs[2], Wd[2], Hs[3], Wd[3], (int)NS[3], bcnt,
                                    list[3], inv[3], cap[3]);
  }
  pool_val_f16_k<64><<<1024, TPB, 0, stream>>>(hbufC, inv[2], list[3], cnt + 3, Hs[2], Wd[2], Hs[3], Wd[3], hbufB);

  // ---------- level 4 (LDS-staged weights) ----------
  mconv_lds_k<64><<<dim3((cap[3] + 63) / 64, 2), TPB, 0, stream>>>(
      hbufB, wt_ca3, hbufC, inv[3], list[3], cnt + 3, Hs[3], Wd[3], 128);
  bn_stats2_k<128><<<288, TPB, 0, stream>>>(hbufC, cnt + 3, stats);
  bnapply_f16_k<128><<<2048, TPB, 0, stream>>>(hbufC, cnt + 3, stats, bg[3], bb[3], hbufA);
  mconv_lds_k<128><<<dim3((cap[3] + 63) / 64, 2), TPB, 0, stream>>>(
      hbufA, wt_cb3, hbufC, inv[3], list[3], cnt + 3, Hs[3], Wd[3], 128);
  {
    int nb = nblk(NS[4]);
    poolA_k<<<nb, TPB, 0, stream>>>(inv[3], Hs[3], Wd[3], Hs[4], Wd[4], (int)NS[4], bcnt);
    scan_k<<<1, 1024, 0, stream>>>(bcnt, nb, cnt + 4, stats);
    poolB_k<<<nb, TPB, 0, stream>>>(inv[3], Hs[3], Wd[3], Hs[4], Wd[4], (int)NS[4], bcnt,
                                    list[4], inv[4], cap[4]);
  }
  pool_val_f16_k<128><<<1024, TPB, 0, stream>>>(hbufC, inv[3], list[4], cnt + 4, Hs[3], Wd[3], Hs[4], Wd[4], hbufB);

  // ---------- level 5 (LDS-staged weights) ----------
  mconv_lds_k<128><<<dim3((cap[4] + 63) / 64, 4), TPB, 0, stream>>>(
      hbufB, wt_ca4, hbufC, inv[4], list[4], cnt + 4, Hs[4], Wd[4], 256);
  bn_stats2_k<256><<<288, TPB, 0, stream>>>(hbufC, cnt + 4, stats);
  bnapply_f16_k<256><<<2048, TPB, 0, stream>>>(hbufC, cnt + 4, stats, bg[4], bb[4], hbufA);
  mconv_lds_k<256><<<dim3((cap[4] + 63) / 64, 4), TPB, 0, stream>>>(
      hbufA, wt_cb4, hbufC, inv[4], list[4], cnt + 4, Hs[4], Wd[4], 256);
  {
    int nb = nblk(NS[5]);
    poolA_k<<<nb, TPB, 0, stream>>>(inv[4], Hs[4], Wd[4], Hs[5], Wd[5], (int)NS[5], bcnt);
    scan_k<<<1, 1024, 0, stream>>>(bcnt, nb, cnt + 5, stats);
    poolB_k<<<nb, TPB, 0, stream>>>(inv[4], Hs[4], Wd[4], Hs[5], Wd[5], (int)NS[5], bcnt,
                                    list[5], inv[5], cap[5]);
  }
  pool_val_f16_k<256><<<1024, TPB, 0, stream>>>(hbufC, inv[4], list[5], cnt + 5, Hs[4], Wd[4], Hs[5], Wd[5], hbufB);

  // ---------- GRUs (16-co tiles) ----------
  gruconv16_k<256><<<dim3((cap[5] + 15) / 16, 16), TPB, 0, stream>>>(
      hbufB, wt_g1g, wt_g1c, h1d, hbufA, nullptr, inv[5], list[5], cnt + 5, Hs[5], Wd[5]);
  gruconv16_k<256><<<dim3((cap[5] + 15) / 16, 16), TPB, 0, stream>>>(
      hbufA, wt_g2g, wt_g2c, h2d, nullptr, df16, inv[5], list[5], cnt + 5, Hs[5], Wd[5]);

  // ---------- head ----------
  lin1m_k<<<dim3(KS1, 16), TPB, 0, stream>>>(df16, w1t, part);
  lin1_reduce_k<<<nblk(32L * 1024), TPB, 0, stream>>>(part, b1, y1);
  lin2_part_k<<<dim3(nblk(32L * 420), JS2), TPB, 0, stream>>>(y1, W2, part2);
  lin2_fin_k<<<nblk(32L * 420), TPB, 0, stream>>>(part2, b2, (float*)d_out);
}

// Round 21
// 574.696 us; speedup vs baseline: 1.2217x; 1.0166x over previous
//
#include <hip/hip_runtime.h>
#include <stdint.h>

#define TPB 256

typedef _Float16 half_t;
typedef __attribute__((ext_vector_type(8))) _Float16 f16x8;
typedef __attribute__((ext_vector_type(4))) float f32x4;

static inline int nblk(long n) { return (int)((n + TPB - 1) / TPB); }

// ---------- scan-based compaction ----------
__global__ void cmpA0_k(const float* __restrict__ x, int n, int* __restrict__ bcnt) {
  int i = blockIdx.x * TPB + threadIdx.x;
  bool a = false;
  if (i < n) {
    float2 v = *(const float2*)(x + 2L * i);
    a = (v.x != 0.f) || (v.y != 0.f);
  }
  unsigned long long bal = __ballot(a);
  __shared__ int wc[4];
  if ((threadIdx.x & 63) == 0) wc[threadIdx.x >> 6] = __popcll(bal);
  __syncthreads();
  if (threadIdx.x == 0) bcnt[blockIdx.x] = wc[0] + wc[1] + wc[2] + wc[3];
}

// also converts x -> f16
__global__ void cmpB0_k(const float* __restrict__ x, int n, const int* __restrict__ bbase,
                        int* __restrict__ list, int* __restrict__ inv, int cap,
                        half_t* __restrict__ xh) {
  int i = blockIdx.x * TPB + threadIdx.x;
  float2 v = {0.f, 0.f};
  bool a = false;
  if (i < n) {
    v = *(const float2*)(x + 2L * i);
    a = (v.x != 0.f) || (v.y != 0.f);
  }
  unsigned long long bal = __ballot(a);
  __shared__ int wc[4];
  int wid = threadIdx.x >> 6, lane = threadIdx.x & 63;
  if (lane == 0) wc[wid] = __popcll(bal);
  __syncthreads();
  int base = bbase[blockIdx.x];
  for (int w = 0; w < wid; ++w) base += wc[w];
  if (i < n) {
    xh[2L * i] = (half_t)v.x;
    xh[2L * i + 1] = (half_t)v.y;
    int pos = base + __popcll(bal & ((1ull << lane) - 1));
    if (a && pos < cap) { list[pos] = i; inv[i] = pos; }
    else inv[i] = -1;
  }
}

__device__ __forceinline__ bool actp(const int* invp, int Hp, int Wp, int Ho, int Wo, int i) {
  int wo = i % Wo; int t = i / Wo; int ho = t % Ho; int bb = t / Ho;
  long rb = ((long)bb * Hp + 2 * ho) * Wp + 2 * wo;
  bool a = false;
  #pragma unroll
  for (int kh = 0; kh < 3; ++kh)
    #pragma unroll
    for (int kw = 0; kw < 3; ++kw)
      a |= (invp[rb + kh * Wp + kw] >= 0);
  return a;
}

// poolA: counts + writes activity byte mask
__global__ void poolA_k(const int* __restrict__ invp, int Hp, int Wp, int Ho, int Wo,
                        int n, int* __restrict__ bcnt, uint8_t* __restrict__ actm) {
  int i = blockIdx.x * TPB + threadIdx.x;
  bool a = (i < n) && actp(invp, Hp, Wp, Ho, Wo, i);
  if (i < n) actm[i] = (uint8_t)a;
  unsigned long long bal = __ballot(a);
  __shared__ int wc[4];
  if ((threadIdx.x & 63) == 0) wc[threadIdx.x >> 6] = __popcll(bal);
  __syncthreads();
  if (threadIdx.x == 0) bcnt[blockIdx.x] = wc[0] + wc[1] + wc[2] + wc[3];
}

// poolB: reads byte mask (no re-gather)
__global__ void poolB_k(const uint8_t* __restrict__ actm, int n,
                        const int* __restrict__ bbase, int* __restrict__ list,
                        int* __restrict__ inv, int cap) {
  int i = blockIdx.x * TPB + threadIdx.x;
  bool a = (i < n) && (actm[i] != 0);
  unsigned long long bal = __ballot(a);
  __shared__ int wc[4];
  int wid = threadIdx.x >> 6, lane = threadIdx.x & 63;
  if (lane == 0) wc[wid] = __popcll(bal);
  __syncthreads();
  int base = bbase[blockIdx.x];
  for (int w = 0; w < wid; ++w) base += wc[w];
  if (i < n) {
    int pos = base + __popcll(bal & ((1ull << lane) - 1));
    if (a && pos < cap) { list[pos] = i; inv[i] = pos; }
    else inv[i] = -1;
  }
}

// exclusive scan; total -> *total; zeroes stats
__global__ void scan_k(int* __restrict__ b, int n, int* __restrict__ total,
                       float* __restrict__ stats) {
  __shared__ int sh[1024];
  __shared__ int sc;
  if (threadIdx.x < 512) stats[threadIdx.x] = 0.f;
  if (threadIdx.x == 0) sc = 0;
  __syncthreads();
  for (int base = 0; base < n; base += 1024) {
    int i = base + threadIdx.x;
    int v = (i < n) ? b[i] : 0;
    sh[threadIdx.x] = v;
    __syncthreads();
    for (int o = 1; o < 1024; o <<= 1) {
      int t = (threadIdx.x >= o) ? sh[threadIdx.x - o] : 0;
      __syncthreads();
      sh[threadIdx.x] += t;
      __syncthreads();
    }
    if (i < n) b[i] = sh[threadIdx.x] - v + sc;
    __syncthreads();
    if (threadIdx.x == 0) sc += sh[1023];
    __syncthreads();
  }
  if (threadIdx.x == 0) *total = sc;
}

// ---------- pooled values (f16 in/out, vectorized f16x8) ----------
template <int C>
__global__ void pool_val_f16_k(const half_t* __restrict__ xin, const int* __restrict__ invp,
                               const int* __restrict__ list, const int* __restrict__ cnt,
                               int Hp, int Wp, int Ho, int Wo, half_t* __restrict__ y) {
  constexpr int CV = C / 8;
  long total = (long)cnt[0] * CV;
  for (long i = (long)blockIdx.x * TPB + threadIdx.x; i < total; i += (long)gridDim.x * TPB) {
    int cb = (int)(i & (CV - 1));
    int r = (int)(i / CV);
    int site = list[r];
    int wo = site % Wo; int t = site / Wo; int ho = t % Ho; int bb = t / Ho;
    long rb = ((long)bb * Hp + 2 * ho) * Wp + 2 * wo;
    float best[8];
    #pragma unroll
    for (int z = 0; z < 8; ++z) best[z] = -1e30f;
    #pragma unroll
    for (int kh = 0; kh < 3; ++kh)
      #pragma unroll
      for (int kw = 0; kw < 3; ++kw) {
        int j = invp[rb + kh * Wp + kw];
        if (j >= 0) {
          f16x8 v = *(const f16x8*)(xin + (long)j * C + cb * 8);
          #pragma unroll
          for (int z = 0; z < 8; ++z) best[z] = fmaxf(best[z], (float)v[z]);
        }
      }
    f16x8 o;
    #pragma unroll
    for (int z = 0; z < 8; ++z) o[z] = (half_t)best[z];
    *(f16x8*)(y + (long)r * C + cb * 8) = o;
  }
}

// ---------- mega prep: weight pack (y=0..13) + zfill (y=14) + W1 transpose (y=15) ----------
struct PackArgs {
  const float* src[14];
  half_t* dst[14];
  const float* W1;
  half_t* w1t;
  float* h1;
  float* h2;
  half_t* df;
};

__global__ void megaprep_k(PackArgs pa) {
  __shared__ float tile[64][65];
  const int seg = blockIdx.y;
  if (seg < 14) {
    const int tci[14]  = {2, 16, 16, 32, 32, 64, 64, 128, 128, 256, 256, 256, 256, 256};
    const int tco[14]  = {16, 16, 32, 32, 64, 64, 128, 128, 256, 256, 256, 256, 256, 256};
    const int tkp[14]  = {32, 160, 160, 288, 0, 0, 0, 0, 0, 0, 0, 0, 0, 0};
    const int twci[14] = {2, 16, 16, 32, 32, 64, 64, 128, 128, 256, 512, 512, 512, 512};
    const int twco[14] = {16, 16, 32, 32, 64, 64, 128, 128, 256, 256, 512, 256, 512, 256};
    const int CI = tci[seg], CO = tco[seg], KP = tkp[seg];
    const int wci = twci[seg], wco = twco[seg];
    const float* __restrict__ src = pa.src[seg];
    half_t* __restrict__ dst = pa.dst[seg];
    if (KP > 0) {
      long total = (long)CO * KP;
      for (long i = (long)blockIdx.x * TPB + threadIdx.x; i < total; i += (long)gridDim.x * TPB) {
        int k = (int)(i % KP), co = (int)(i / KP);
        int tap = k / CI, ci = k - tap * CI;
        float v = (tap < 9) ? src[((long)tap * wci + ci) * wco + co] : 0.f;
        dst[i] = (half_t)v;
      }
    } else {
      long total = 9L * CO * CI;
      for (long i = (long)blockIdx.x * TPB + threadIdx.x; i < total; i += (long)gridDim.x * TPB) {
        int ci = (int)(i % CI);
        long t = i / CI;
        int co = (int)(t % CO);
        int tap = (int)(t / CO);
        dst[i] = (half_t)src[((long)tap * wci + ci) * wco + co];
      }
    }
  } else if (seg == 14) {
    for (long i = (long)blockIdx.x * TPB + threadIdx.x; i < 286720; i += (long)gridDim.x * TPB) {
      pa.h1[i] = 0.f;
      pa.h2[i] = 0.f;
      pa.df[i] = (half_t)0.f;
    }
  } else {
    // W1 transpose: bx -> (kc, jc), 140*16 = 2240 tiles
    int bx = blockIdx.x;
    if (bx >= 2240) return;
    int k0 = (bx >> 4) * 64, j0 = (bx & 15) * 64;
    for (int i = threadIdx.x; i < 4096; i += TPB) {
      int r = i >> 6, c = i & 63;
      tile[r][c] = pa.W1[(long)(k0 + r) * 1024 + j0 + c];
    }
    __syncthreads();
    for (int i = threadIdx.x; i < 4096; i += TPB) {
      int r = i >> 6, c = i & 63;
      pa.w1t[(long)(j0 + r) * 8960 + k0 + c] = (half_t)tile[c][r];
    }
  }
}

// ---------- K-packed MFMA conv (CO<=32); 64 sites/block; f16 out ----------
template <int CI, int CO, bool DENSE>
__global__ __launch_bounds__(256) void mconvp_k(const half_t* __restrict__ X,
                                                const half_t* __restrict__ Wt,
                                                half_t* __restrict__ y,
                                                const int* __restrict__ inv,
                                                const int* __restrict__ list,
                                                const int* __restrict__ cnt,
                                                int H, int W) {
  constexpr int KP = ((9 * CI + 31) / 32) * 32;
  constexpr int NCO = CO / 16;
  const int nact = cnt[0];
  const int base = blockIdx.x * 64;
  if (base >= nact) return;
  __shared__ int nbr[64 * 9];
  for (int i = threadIdx.x; i < 64 * 9; i += TPB) {
    int s = i / 9, nb = i - s * 9;
    int j = -1;
    if (base + s < nact) {
      int site = list[base + s];
      int w = site % W; int t = site / W; int h = t % H; int bb = t / H;
      int hh = h + nb / 3 - 1, ww = w + nb % 3 - 1;
      if ((unsigned)hh < (unsigned)H && (unsigned)ww < (unsigned)W) {
        int ss = (bb * H + hh) * W + ww;
        j = DENSE ? ss : inv[ss];
      }
    }
    nbr[i] = j;
  }
  __syncthreads();
  const int lane = threadIdx.x & 63, wv = threadIdx.x >> 6;
  const int srow = lane & 15, kseg = lane >> 4;
  const int sloc = wv * 16 + srow;
  f32x4 acc[NCO];
  #pragma unroll
  for (int c = 0; c < NCO; ++c) acc[c] = (f32x4){0.f, 0.f, 0.f, 0.f};
  #pragma unroll
  for (int k0 = 0; k0 < KP; k0 += 32) {
    const int k = k0 + kseg * 8;
    f16x8 av;
    #pragma unroll
    for (int z = 0; z < 8; ++z) av[z] = (_Float16)0.f;
    if (CI >= 8) {
      int tap = k / CI;
      int ci = k - tap * CI;
      if (tap < 9) {
        int j = nbr[sloc * 9 + tap];
        if (j >= 0) av = *(const f16x8*)(X + (long)j * CI + ci);
      }
    } else {  // CI == 2
      #pragma unroll
      for (int q = 0; q < 4; ++q) {
        int kk = k + 2 * q;
        int tap = kk >> 1;
        if (tap < 9) {
          int j = nbr[sloc * 9 + tap];
          if (j >= 0) {
            const half_t* xp = X + (long)j * 2;
            av[2 * q] = xp[0];
            av[2 * q + 1] = xp[1];
          }
        }
      }
    }
    #pragma unroll
    for (int c = 0; c < NCO; ++c) {
      f16x8 bv = *(const f16x8*)(Wt + (long)(c * 16 + srow) * KP + k);
      acc[c] = __builtin_amdgcn_mfma_f32_16x16x32_f16(av, bv, acc[c], 0, 0, 0);
    }
  }
  #pragma unroll
  for (int c = 0; c < NCO; ++c)
    #pragma unroll
    for (int r = 0; r < 4; ++r) {
      int ss = base + wv * 16 + kseg * 4 + r;
      if (ss < nact) y[(long)ss * CO + c * 16 + srow] = (half_t)acc[c][r];
    }
}

// ---------- LDS-staged-weight conv: 64 sites x 64 co per block, W[tap] in LDS ----------
template <int CI>
__global__ __launch_bounds__(256) void mconv_lds_k(const half_t* __restrict__ X,
                                                   const half_t* __restrict__ Wt,
                                                   half_t* __restrict__ y,
                                                   const int* __restrict__ inv,
                                                   const int* __restrict__ list,
                                                   const int* __restrict__ cnt,
                                                   int H, int W, int COfull) {
  constexpr int NK = CI / 32;
  constexpr int LDW = CI + 8;
  __shared__ half_t wlds[64 * LDW];
  const int nact = cnt[0];
  const int base = blockIdx.x * 64;
  if (base >= nact) return;
  const int lane = threadIdx.x & 63, wv = threadIdx.x >> 6;
  const int srow = lane & 15, kseg = lane >> 4;
  const int co0 = blockIdx.y * 64;
  int jj[9];
  {
    int s = base + wv * 16 + srow;
    bool sv = (s < nact);
    int h = 0, w = 0, bb = 0;
    if (sv) {
      int site = list[s];
      w = site % W;
      int t = site / W;
      h = t % H;
      bb = t / H;
    }
    #pragma unroll
    for (int tap = 0; tap < 9; ++tap) {
      int j = -1;
      if (sv) {
        int hh = h + tap / 3 - 1, ww = w + tap % 3 - 1;
        if ((unsigned)hh < (unsigned)H && (unsigned)ww < (unsigned)W)
          j = inv[(bb * H + hh) * W + ww];
      }
      jj[tap] = j;
    }
  }
  f32x4 acc[4];
  #pragma unroll
  for (int b = 0; b < 4; ++b) acc[b] = (f32x4){0.f, 0.f, 0.f, 0.f};
  for (int tap = 0; tap < 9; ++tap) {
    __syncthreads();
    constexpr int GR = 64 * (CI / 8);
    const half_t* wsrc = Wt + ((long)tap * COfull + co0) * CI;
    for (int idx = threadIdx.x; idx < GR; idx += TPB) {
      int row = idx / (CI / 8), cb = idx % (CI / 8);
      *(f16x8*)(&wlds[row * LDW + cb * 8]) = *(const f16x8*)(wsrc + (long)row * CI + cb * 8);
    }
    __syncthreads();
    const int j = jj[tap];
    f16x8 av[NK];
    #pragma unroll
    for (int s = 0; s < NK; ++s) {
      #pragma unroll
      for (int z = 0; z < 8; ++z) av[s][z] = (_Float16)0.f;
      if (j >= 0) av[s] = *(const f16x8*)(X + (long)j * CI + kseg * 8 + s * 32);
    }
    #pragma unroll
    for (int s = 0; s < NK; ++s) {
      #pragma unroll
      for (int b = 0; b < 4; ++b) {
        f16x8 bv = *(const f16x8*)(&wlds[(b * 16 + srow) * LDW + kseg * 8 + s * 32]);
        acc[b] = __builtin_amdgcn_mfma_f32_16x16x32_f16(av[s], bv, acc[b], 0, 0, 0);
      }
    }
  }
  #pragma unroll
  for (int b = 0; b < 4; ++b)
    #pragma unroll
    for (int r = 0; r < 4; ++r) {
      int ss = base + wv * 16 + kseg * 4 + r;
      if (ss < nact) y[(long)ss * COfull + co0 + b * 16 + srow] = (half_t)acc[b][r];
    }
}

// ---------- fused GRU conv: 16 sites x 16 co per block (grid 70x16) ----------
template <int CI>
__global__ __launch_bounds__(256) void gruconv16_k(const half_t* __restrict__ X,
                                                   const half_t* __restrict__ Wg,
                                                   const half_t* __restrict__ Wc,
                                                   float* __restrict__ hdense,
                                                   half_t* __restrict__ hcomp,
                                                   half_t* __restrict__ dflat,
                                                   const int* __restrict__ inv,
                                                   const int* __restrict__ list,
                                                   const int* __restrict__ cnt,
                                                   int H, int W) {
  constexpr int CO = 256;
  constexpr int NK = CI / 32;
  const int nact = cnt[0];
  const int base = blockIdx.x * 16;
  if (base >= nact) return;
  __shared__ int nbr[16 * 9];
  __shared__ float red[4][16][34];
  for (int i = threadIdx.x; i < 16 * 9; i += TPB) {
    int s = i / 9, nb = i - s * 9;
    int j = -1;
    if (base + s < nact) {
      int site = list[base + s];
      int w = site % W; int t = site / W; int h = t % H; int bb = t / H;
      int hh = h + nb / 3 - 1, ww = w + nb % 3 - 1;
      if ((unsigned)hh < (unsigned)H && (unsigned)ww < (unsigned)W)
        j = inv[(bb * H + hh) * W + ww];
    }
    nbr[i] = j;
  }
  __syncthreads();
  const int lane = threadIdx.x & 63, wv = threadIdx.x >> 6;
  const int srow = lane & 15, kseg = lane >> 4;
  const int co0 = blockIdx.y * 16;
  const int t0 = (wv * 9) / 4, t1 = ((wv + 1) * 9) / 4;
  f32x4 g = {0.f, 0.f, 0.f, 0.f};
  f32x4 c = g;
  for (int tap = t0; tap < t1; ++tap) {
    int j = nbr[srow * 9 + tap];
    const half_t* xp = X + (long)j * CI + kseg * 8;
    const half_t* wgp = Wg + ((long)tap * CO + co0 + srow) * CI + kseg * 8;
    const half_t* wcp = Wc + ((long)tap * CO + co0 + srow) * CI + kseg * 8;
    f16x8 av[NK];
    #pragma unroll
    for (int s = 0; s < NK; ++s) {
      #pragma unroll
      for (int z = 0; z < 8; ++z) av[s][z] = (_Float16)0.f;
      if (j >= 0) av[s] = *(const f16x8*)(xp + s * 32);
    }
    #pragma unroll
    for (int s = 0; s < NK; ++s) {
      f16x8 bg = *(const f16x8*)(wgp + s * 32);
      f16x8 bc = *(const f16x8*)(wcp + s * 32);
      g = __builtin_amdgcn_mfma_f32_16x16x32_f16(av[s], bg, g, 0, 0, 0);
      c = __builtin_amdgcn_mfma_f32_16x16x32_f16(av[s], bc, c, 0, 0, 0);
    }
  }
  #pragma unroll
  for (int r = 0; r < 4; ++r) {
    int s = kseg * 4 + r;
    red[wv][s][srow] = g[r];
    red[wv][s][16 + srow] = c[r];
  }
  __syncthreads();
  {
    int i = threadIdx.x;
    int s = i >> 4, co = i & 15;
    float gs = red[0][s][co] + red[1][s][co] + red[2][s][co] + red[3][s][co];
    float cs = red[0][s][16 + co] + red[1][s][16 + co] + red[2][s][16 + co] + red[3][s][16 + co];
    int ss = base + s;
    if (ss < nact) {
      float u = 1.f / (1.f + expf(-gs));
      float v = u * tanhf(cs);
      if (hcomp) hcomp[(long)ss * CO + co0 + co] = (half_t)v;
      int site = list[ss];
      hdense[(long)site * CO + co0 + co] = v;
      if (dflat) {
        int b = site / 35, s2 = site - b * 35;
        dflat[(long)b * 8960 + (co0 + co) * 35 + s2] = (half_t)v;
      }
    }
  }
}

// ---------- BN (f16 activations) ----------
template <int CO>
__global__ void bn_stats2_k(const half_t* __restrict__ y, const int* __restrict__ cnt,
                            float* __restrict__ stats) {
  __shared__ float ls[512];
  for (int i = threadIdx.x; i < 2 * CO; i += TPB) ls[i] = 0.f;
  __syncthreads();
  long total = (long)cnt[0] * CO;
  long i0 = (long)blockIdx.x * TPB + threadIdx.x;
  int c = (int)(i0 & (CO - 1));
  float s = 0.f, s2 = 0.f;
  for (long i = i0; i < total; i += (long)gridDim.x * TPB) {
    float v = (float)y[i];
    s += v; s2 += v * v;
  }
  atomicAdd(&ls[c], s);
  atomicAdd(&ls[CO + c], s2);
  __syncthreads();
  for (int i = threadIdx.x; i < 2 * CO; i += TPB) atomicAdd(&stats[i], ls[i]);
}

template <int C>
__global__ void bnapply_f16_k(const half_t* __restrict__ y, const int* __restrict__ cnt,
                              const float* __restrict__ stats, const float* __restrict__ gamma,
                              const float* __restrict__ beta, half_t* __restrict__ out) {
  __shared__ float sc[C], sh2[C];
  for (int c = threadIdx.x; c < C; c += TPB) {
    float n = fmaxf((float)cnt[0], 1.f);
    float mean = stats[c] / n;
    float var = fmaxf(stats[C + c] / n - mean * mean, 0.f);
    float s = gamma[c] * rsqrtf(var + 1e-4f);
    sc[c] = s;
    sh2[c] = beta[c] - mean * s;
  }
  __syncthreads();
  long total = (long)cnt[0] * C;
  for (long i = (long)blockIdx.x * TPB + threadIdx.x; i < total; i += (long)gridDim.x * TPB) {
    int c = (int)(i & (C - 1));
    out[i] = (half_t)fmaxf(fmaf((float)y[i], sc[c], sh2[c]), 0.f);
  }
}

// ---------- head: MFMA lin1 ----------
#define KS1 35
__global__ __launch_bounds__(256) void lin1m_k(const half_t* __restrict__ D,
                                               const half_t* __restrict__ W1T,
                                               float* __restrict__ part) {
  __shared__ float red[4][32][65];
  const int lane = threadIdx.x & 63, wv = threadIdx.x >> 6;
  const int srow = lane & 15, kseg = lane >> 4;
  const int kc = blockIdx.x, j0 = blockIdx.y * 64;
  const int kbase = kc * 256 + wv * 64;
  f32x4 acc[2][4];
  #pragma unroll
  for (int m = 0; m < 2; ++m)
    #pragma unroll
    for (int b = 0; b < 4; ++b) acc[m][b] = (f32x4){0.f, 0.f, 0.f, 0.f};
  #pragma unroll
  for (int step = 0; step < 2; ++step) {
    int k = kbase + step * 32 + kseg * 8;
    f16x8 a0 = *(const f16x8*)(D + (long)srow * 8960 + k);
    f16x8 a1 = *(const f16x8*)(D + (long)(16 + srow) * 8960 + k);
    #pragma unroll
    for (int b = 0; b < 4; ++b) {
      f16x8 bv = *(const f16x8*)(W1T + (long)(j0 + b * 16 + srow) * 8960 + k);
      acc[0][b] = __builtin_amdgcn_mfma_f32_16x16x32_f16(a0, bv, acc[0][b], 0, 0, 0);
      acc[1][b] = __builtin_amdgcn_mfma_f32_16x16x32_f16(a1, bv, acc[1][b], 0, 0, 0);
    }
  }
  #pragma unroll
  for (int m = 0; m < 2; ++m)
    #pragma unroll
    for (int b = 0; b < 4; ++b)
      #pragma unroll
      for (int r = 0; r < 4; ++r)
        red[wv][m * 16 + kseg * 4 + r][b * 16 + srow] = acc[m][b][r];
  __syncthreads();
  for (int i = threadIdx.x; i < 32 * 64; i += TPB) {
    int row = i >> 6, col = i & 63;
    float v = red[0][row][col] + red[1][row][col] + red[2][row][col] + red[3][row][col];
    part[(long)kc * 32768 + row * 1024 + j0 + col] = v;
  }
}

__global__ void lin1_reduce_k(const float* __restrict__ part, const float* __restrict__ b1,
                              float* __restrict__ y1) {
  int i = blockIdx.x * TPB + threadIdx.x;
  if (i >= 32 * 1024) return;
  int b = i >> 10, j = i & 1023;
  float a = b1[j];
  #pragma unroll
  for (int kc = 0; kc < KS1; ++kc) a += part[(long)kc * 32768 + b * 1024 + j];
  y1[i] = fmaxf(a, 0.f);
}

#define JS2 8
__global__ void lin2_part_k(const float* __restrict__ y1, const float* __restrict__ W2,
                            float* __restrict__ part2) {
  int i = blockIdx.x * TPB + threadIdx.x;
  if (i >= 32 * 420) return;
  int b = i / 420, o = i - b * 420;
  int j0 = blockIdx.y * 128;
  float a = 0.f;
  const float* yp = y1 + b * 1024 + j0;
  const float* wp = W2 + (long)j0 * 420 + o;
  #pragma unroll 8
  for (int j = 0; j < 128; ++j) a = fmaf(yp[j], wp[(long)j * 420], a);
  part2[(long)blockIdx.y * 13440 + i] = a;
}

__global__ void lin2_fin_k(const float* __restrict__ part2, const float* __restrict__ b2,
                           float* __restrict__ out) {
  int i = blockIdx.x * TPB + threadIdx.x;
  if (i >= 32 * 420) return;
  int o = i % 420;
  float a = b2[o];
  #pragma unroll
  for (int js = 0; js < JS2; ++js) a += part2[(long)js * 13440 + i];
  out[i] = a;
}

extern "C" void kernel_launch(void* const* d_in, const int* in_sizes, int n_in,
                              void* d_out, int out_size, void* d_ws, size_t ws_size,
                              hipStream_t stream) {
  const float* x = (const float*)d_in[0];
  const float* ca[5] = {(const float*)d_in[2], (const float*)d_in[6], (const float*)d_in[10],
                        (const float*)d_in[14], (const float*)d_in[18]};
  const float* bg[5] = {(const float*)d_in[3], (const float*)d_in[7], (const float*)d_in[11],
                        (const float*)d_in[15], (const float*)d_in[19]};
  const float* bb[5] = {(const float*)d_in[4], (const float*)d_in[8], (const float*)d_in[12],
                        (const float*)d_in[16], (const float*)d_in[20]};
  const float* cb[5] = {(const float*)d_in[5], (const float*)d_in[9], (const float*)d_in[13],
                        (const float*)d_in[17], (const float*)d_in[21]};
  const float* g1Wg = (const float*)d_in[22];
  const float* g1Wc = (const float*)d_in[23];
  const float* g2Wg = (const float*)d_in[24];
  const float* g2Wc = (const float*)d_in[25];
  const float* W1 = (const float*)d_in[26];
  const float* b1 = (const float*)d_in[27];
  const float* W2 = (const float*)d_in[28];
  const float* b2 = (const float*)d_in[29];

  const int Hs[6] = {191, 95, 47, 23, 11, 5};
  const int Wd[6] = {255, 127, 63, 31, 15, 7};
  const long NS[6] = {1558560, 386080, 94752, 22816, 5280, 1120};
  const int cap[6] = {160000, 386080, 94752, 22816, 5280, 1120};

  float* ws = (float*)d_ws;
  long off = 0;
  float* part = ws + off;  off += 1200000;
  float* part2 = ws + off; off += 120000;
  float* stats = ws + off; off += 512;
  float* y1 = ws + off;    off += 32L * 1024;

  half_t* hbase = (half_t*)(ws + off);
  long hoff = 0;
  half_t* hbufA = hbase + hoff; hoff += 6500000;
  half_t* hbufB = hbase + hoff; hoff += 6500000;
  half_t* hbufC = hbase + hoff; hoff += 6500000;
  half_t* xh = hbase + hoff;    hoff += 3117120;
  half_t* w1t = hbase + hoff;   hoff += 9175040;
  half_t* df16 = hbase + hoff;  hoff += 286720;
  half_t* wp_ca0 = hbase + hoff; hoff += 16L * 32;
  half_t* wp_cb0 = hbase + hoff; hoff += 16L * 160;
  half_t* wp_ca1 = hbase + hoff; hoff += 32L * 160;
  half_t* wp_cb1 = hbase + hoff; hoff += 32L * 288;
  half_t* wt_ca2 = hbase + hoff; hoff += 9L * 64 * 32;
  half_t* wt_cb2 = hbase + hoff; hoff += 9L * 64 * 64;
  half_t* wt_ca3 = hbase + hoff; hoff += 9L * 128 * 64;
  half_t* wt_cb3 = hbase + hoff; hoff += 9L * 128 * 128;
  half_t* wt_ca4 = hbase + hoff; hoff += 9L * 256 * 128;
  half_t* wt_cb4 = hbase + hoff; hoff += 9L * 256 * 256;
  half_t* wt_g1g = hbase + hoff; hoff += 9L * 256 * 256;
  half_t* wt_g1c = hbase + hoff; hoff += 9L * 256 * 256;
  half_t* wt_g2g = hbase + hoff; hoff += 9L * 256 * 256;
  half_t* wt_g2c = hbase + hoff; hoff += 9L * 256 * 256;

  int* ip = (int*)(hbase + hoff);
  long ioff = 0;
  int* cnt = ip + ioff; ioff += 16;
  int* bcnt = ip + ioff; ioff += 8192;
  int* list[6]; int* inv[6];
  for (int l = 0; l < 6; ++l) { list[l] = ip + ioff; ioff += cap[l]; }
  for (int l = 0; l < 6; ++l) { inv[l] = ip + ioff; ioff += NS[l]; }
  uint8_t* actm = (uint8_t*)(ip + ioff);
  long aoff = NS[1];  // largest pooled-level site count
  size_t needed = (size_t)off * 4 + (size_t)hoff * 2 + (size_t)ioff * 4 + (size_t)aoff;
  if (ws_size < needed) return;

  float* h1d = (float*)d_out + 13440;
  float* h2d = h1d + 286720;

  // ---- one-shot prep: weight pack + W1 transpose + zero fills ----
  PackArgs pa;
  pa.src[0] = ca[0]; pa.dst[0] = wp_ca0;
  pa.src[1] = cb[0]; pa.dst[1] = wp_cb0;
  pa.src[2] = ca[1]; pa.dst[2] = wp_ca1;
  pa.src[3] = cb[1]; pa.dst[3] = wp_cb1;
  pa.src[4] = ca[2]; pa.dst[4] = wt_ca2;
  pa.src[5] = cb[2]; pa.dst[5] = wt_cb2;
  pa.src[6] = ca[3]; pa.dst[6] = wt_ca3;
  pa.src[7] = cb[3]; pa.dst[7] = wt_cb3;
  pa.src[8] = ca[4]; pa.dst[8] = wt_ca4;
  pa.src[9] = cb[4]; pa.dst[9] = wt_cb4;
  pa.src[10] = g1Wg; pa.dst[10] = wt_g1g;
  pa.src[11] = g1Wc; pa.dst[11] = wt_g1c;
  pa.src[12] = g2Wg; pa.dst[12] = wt_g2g;
  pa.src[13] = g2Wc; pa.dst[13] = wt_g2c;
  pa.W1 = W1; pa.w1t = w1t;
  pa.h1 = h1d; pa.h2 = h2d; pa.df = df16;
  megaprep_k<<<dim3(2240, 16), TPB, 0, stream>>>(pa);

  // ---- level-0 compaction (also x->f16) ----
  {
    int nb = nblk(NS[0]);
    cmpA0_k<<<nb, TPB, 0, stream>>>(x, (int)NS[0], bcnt);
    scan_k<<<1, 1024, 0, stream>>>(bcnt, nb, cnt + 0, stats);
    cmpB0_k<<<nb, TPB, 0, stream>>>(x, (int)NS[0], bcnt, list[0], inv[0], cap[0], xh);
  }

  // ---------- level 1 ----------
  mconvp_k<2, 16, true><<<(cap[0] + 63) / 64, TPB, 0, stream>>>(
      xh, wp_ca0, hbufC, nullptr, list[0], cnt + 0, Hs[0], Wd[0]);
  bn_stats2_k<16><<<288, TPB, 0, stream>>>(hbufC, cnt + 0, stats);
  bnapply_f16_k<16><<<2048, TPB, 0, stream>>>(hbufC, cnt + 0, stats, bg[0], bb[0], hbufA);
  mconvp_k<16, 16, false><<<(cap[0] + 63) / 64, TPB, 0, stream>>>(
      hbufA, wp_cb0, hbufC, inv[0], list[0], cnt + 0, Hs[0], Wd[0]);
  {
    int nb = nblk(NS[1]);
    poolA_k<<<nb, TPB, 0, stream>>>(inv[0], Hs[0], Wd[0], Hs[1], Wd[1], (int)NS[1], bcnt, actm);
    scan_k<<<1, 1024, 0, stream>>>(bcnt, nb, cnt + 1, stats);
    poolB_k<<<nb, TPB, 0, stream>>>(actm, (int)NS[1], bcnt, list[1], inv[1], cap[1]);
  }
  pool_val_f16_k<16><<<1024, TPB, 0, stream>>>(hbufC, inv[0], list[1], cnt + 1, Hs[0], Wd[0], Hs[1], Wd[1], hbufB);

  // ---------- level 2 ----------
  mconvp_k<16, 32, false><<<(cap[1] + 63) / 64, TPB, 0, stream>>>(
      hbufB, wp_ca1, hbufC, inv[1], list[1], cnt + 1, Hs[1], Wd[1]);
  bn_stats2_k<32><<<288, TPB, 0, stream>>>(hbufC, cnt + 1, stats);
  bnapply_f16_k<32><<<2048, TPB, 0, stream>>>(hbufC, cnt + 1, stats, bg[1], bb[1], hbufA);
  mconvp_k<32, 32, false><<<(cap[1] + 63) / 64, TPB, 0, stream>>>(
      hbufA, wp_cb1, hbufC, inv[1], list[1], cnt + 1, Hs[1], Wd[1]);
  {
    int nb = nblk(NS[2]);
    poolA_k<<<nb, TPB, 0, stream>>>(inv[1], Hs[1], Wd[1], Hs[2], Wd[2], (int)NS[2], bcnt, actm);
    scan_k<<<1, 1024, 0, stream>>>(bcnt, nb, cnt + 2, stats);
    poolB_k<<<nb, TPB, 0, stream>>>(actm, (int)NS[2], bcnt, list[2], inv[2], cap[2]);
  }
  pool_val_f16_k<32><<<1024, TPB, 0, stream>>>(hbufC, inv[1], list[2], cnt + 2, Hs[1], Wd[1], Hs[2], Wd[2], hbufB);

  // ---------- level 3 (LDS-staged weights) ----------
  mconv_lds_k<32><<<dim3((cap[2] + 63) / 64, 1), TPB, 0, stream>>>(
      hbufB, wt_ca2, hbufC, inv[2], list[2], cnt + 2, Hs[2], Wd[2], 64);
  bn_stats2_k<64><<<288, TPB, 0, stream>>>(hbufC, cnt + 2, stats);
  bnapply_f16_k<64><<<2048, TPB, 0, stream>>>(hbufC, cnt + 2, stats, bg[2], bb[2], hbufA);
  mconv_lds_k<64><<<dim3((cap[2] + 63) / 64, 1), TPB, 0, stream>>>(
      hbufA, wt_cb2, hbufC, inv[2], list[2], cnt + 2, Hs[2], Wd[2], 64);
  {
    int nb = nblk(NS[3]);
    poolA_k<<<nb, TPB, 0, stream>>>(inv[2], Hs[2], Wd[2], Hs[3], Wd[3], (int)NS[3], bcnt, actm);
    scan_k<<<1, 1024, 0, stream>>>(bcnt, nb, cnt + 3, stats);
    poolB_k<<<nb, TPB, 0, stream>>>(actm, (int)NS[3], bcnt, list[3], inv[3], cap[3]);
  }
  pool_val_f16_k<64><<<1024, TPB, 0, stream>>>(hbufC, inv[2], list[3], cnt + 3, Hs[2], Wd[2], Hs[3], Wd[3], hbufB);

  // ---------- level 4 (LDS-staged weights) ----------
  mconv_lds_k<64><<<dim3((cap[3] + 63) / 64, 2), TPB, 0, stream>>>(
      hbufB, wt_ca3, hbufC, inv[3], list[3], cnt + 3, Hs[3], Wd[3], 128);
  bn_stats2_k<128><<<288, TPB, 0, stream>>>(hbufC, cnt + 3, stats);
  bnapply_f16_k<128><<<2048, TPB, 0, stream>>>(hbufC, cnt + 3, stats, bg[3], bb[3], hbufA);
  mconv_lds_k<128><<<dim3((cap[3] + 63) / 64, 2), TPB, 0, stream>>>(
      hbufA, wt_cb3, hbufC, inv[3], list[3], cnt + 3, Hs[3], Wd[3], 128);
  {
    int nb = nblk(NS[4]);
    poolA_k<<<nb, TPB, 0, stream>>>(inv[3], Hs[3], Wd[3], Hs[4], Wd[4], (int)NS[4], bcnt, actm);
    scan_k<<<1, 1024, 0, stream>>>(bcnt, nb, cnt + 4, stats);
    poolB_k<<<nb, TPB, 0, stream>>>(actm, (int)NS[4], bcnt, list[4], inv[4], cap[4]);
  }
  pool_val_f16_k<128><<<1024, TPB, 0, stream>>>(hbufC, inv[3], list[4], cnt + 4, Hs[3], Wd[3], Hs[4], Wd[4], hbufB);

  // ---------- level 5 (LDS-staged weights) ----------
  mconv_lds_k<128><<<dim3((cap[4] + 63) / 64, 4), TPB, 0, stream>>>(
      hbufB, wt_ca4, hbufC, inv[4], list[4], cnt + 4, Hs[4], Wd[4], 256);
  bn_stats2_k<256><<<288, TPB, 0, stream>>>(hbufC, cnt + 4, stats);
  bnapply_f16_k<256><<<2048, TPB, 0, stream>>>(hbufC, cnt + 4, stats, bg[4], bb[4], hbufA);
  mconv_lds_k<256><<<dim3((cap[4] + 63) / 64, 4), TPB, 0, stream>>>(
      hbufA, wt_cb4, hbufC, inv[4], list[4], cnt + 4, Hs[4], Wd[4], 256);
  {
    int nb = nblk(NS[5]);
    poolA_k<<<nb, TPB, 0, stream>>>(inv[4], Hs[4], Wd[4], Hs[5], Wd[5], (int)NS[5], bcnt, actm);
    scan_k<<<1, 1024, 0, stream>>>(bcnt, nb, cnt + 5, stats);
    poolB_k<<<nb, TPB, 0, stream>>>(actm, (int)NS[5], bcnt, list[5], inv[5], cap[5]);
  }
  pool_val_f16_k<256><<<1024, TPB, 0, stream>>>(hbufC, inv[4], list[5], cnt + 5, Hs[4], Wd[4], Hs[5], Wd[5], hbufB);

  // ---------- GRUs (16-co tiles) ----------
  gruconv16_k<256><<<dim3((cap[5] + 15) / 16, 16), TPB, 0, stream>>>(
      hbufB, wt_g1g, wt_g1c, h1d, hbufA, nullptr, inv[5], list[5], cnt + 5, Hs[5], Wd[5]);
  gruconv16_k<256><<<dim3((cap[5] + 15) / 16, 16), TPB, 0, stream>>>(
      hbufA, wt_g2g, wt_g2c, h2d, nullptr, df16, inv[5], list[5], cnt + 5, Hs[5], Wd[5]);

  // ---------- head ----------
  lin1m_k<<<dim3(KS1, 16), TPB, 0, stream>>>(df16, w1t, part);
  lin1_reduce_k<<<nblk(32L * 1024), TPB, 0, stream>>>(part, b1, y1);
  lin2_part_k<<<dim3(nblk(32L * 420), JS2), TPB, 0, stream>>>(y1, W2, part2);
  lin2_fin_k<<<nblk(32L * 420), TPB, 0, stream>>>(part2, b2, (float*)d_out);
}

// Round 22
// 566.399 us; speedup vs baseline: 1.2396x; 1.0146x over previous
//
#include <hip/hip_runtime.h>
#include <stdint.h>

#define TPB 256

typedef _Float16 half_t;
typedef __attribute__((ext_vector_type(8))) _Float16 f16x8;
typedef __attribute__((ext_vector_type(4))) float f32x4;

static inline int nblk(long n) { return (int)((n + TPB - 1) / TPB); }

// ---------- scan-based compaction ----------
__global__ void cmpA0_k(const float* __restrict__ x, int n, int* __restrict__ bcnt) {
  int i = blockIdx.x * TPB + threadIdx.x;
  bool a = false;
  if (i < n) {
    float2 v = *(const float2*)(x + 2L * i);
    a = (v.x != 0.f) || (v.y != 0.f);
  }
  unsigned long long bal = __ballot(a);
  __shared__ int wc[4];
  if ((threadIdx.x & 63) == 0) wc[threadIdx.x >> 6] = __popcll(bal);
  __syncthreads();
  if (threadIdx.x == 0) bcnt[blockIdx.x] = wc[0] + wc[1] + wc[2] + wc[3];
}

// also converts x -> f16
__global__ void cmpB0_k(const float* __restrict__ x, int n, const int* __restrict__ bbase,
                        int* __restrict__ list, int* __restrict__ inv, int cap,
                        half_t* __restrict__ xh) {
  int i = blockIdx.x * TPB + threadIdx.x;
  float2 v = {0.f, 0.f};
  bool a = false;
  if (i < n) {
    v = *(const float2*)(x + 2L * i);
    a = (v.x != 0.f) || (v.y != 0.f);
  }
  unsigned long long bal = __ballot(a);
  __shared__ int wc[4];
  int wid = threadIdx.x >> 6, lane = threadIdx.x & 63;
  if (lane == 0) wc[wid] = __popcll(bal);
  __syncthreads();
  int base = bbase[blockIdx.x];
  for (int w = 0; w < wid; ++w) base += wc[w];
  if (i < n) {
    xh[2L * i] = (half_t)v.x;
    xh[2L * i + 1] = (half_t)v.y;
    int pos = base + __popcll(bal & ((1ull << lane) - 1));
    if (a && pos < cap) { list[pos] = i; inv[i] = pos; }
    else inv[i] = -1;
  }
}

__device__ __forceinline__ bool actp(const int* invp, int Hp, int Wp, int Ho, int Wo, int i) {
  int wo = i % Wo; int t = i / Wo; int ho = t % Ho; int bb = t / Ho;
  long rb = ((long)bb * Hp + 2 * ho) * Wp + 2 * wo;
  bool a = false;
  #pragma unroll
  for (int kh = 0; kh < 3; ++kh)
    #pragma unroll
    for (int kw = 0; kw < 3; ++kw)
      a |= (invp[rb + kh * Wp + kw] >= 0);
  return a;
}

// poolA: counts + writes activity byte mask
__global__ void poolA_k(const int* __restrict__ invp, int Hp, int Wp, int Ho, int Wo,
                        int n, int* __restrict__ bcnt, uint8_t* __restrict__ actm) {
  int i = blockIdx.x * TPB + threadIdx.x;
  bool a = (i < n) && actp(invp, Hp, Wp, Ho, Wo, i);
  if (i < n) actm[i] = (uint8_t)a;
  unsigned long long bal = __ballot(a);
  __shared__ int wc[4];
  if ((threadIdx.x & 63) == 0) wc[threadIdx.x >> 6] = __popcll(bal);
  __syncthreads();
  if (threadIdx.x == 0) bcnt[blockIdx.x] = wc[0] + wc[1] + wc[2] + wc[3];
}

// poolB: reads byte mask (no re-gather)
__global__ void poolB_k(const uint8_t* __restrict__ actm, int n,
                        const int* __restrict__ bbase, int* __restrict__ list,
                        int* __restrict__ inv, int cap) {
  int i = blockIdx.x * TPB + threadIdx.x;
  bool a = (i < n) && (actm[i] != 0);
  unsigned long long bal = __ballot(a);
  __shared__ int wc[4];
  int wid = threadIdx.x >> 6, lane = threadIdx.x & 63;
  if (lane == 0) wc[wid] = __popcll(bal);
  __syncthreads();
  int base = bbase[blockIdx.x];
  for (int w = 0; w < wid; ++w) base += wc[w];
  if (i < n) {
    int pos = base + __popcll(bal & ((1ull << lane) - 1));
    if (a && pos < cap) { list[pos] = i; inv[i] = pos; }
    else inv[i] = -1;
  }
}

// exclusive scan; total -> *total; zeroes stats
__global__ void scan_k(int* __restrict__ b, int n, int* __restrict__ total,
                       float* __restrict__ stats) {
  __shared__ int sh[1024];
  __shared__ int sc;
  if (threadIdx.x < 512) stats[threadIdx.x] = 0.f;
  if (threadIdx.x == 0) sc = 0;
  __syncthreads();
  for (int base = 0; base < n; base += 1024) {
    int i = base + threadIdx.x;
    int v = (i < n) ? b[i] : 0;
    sh[threadIdx.x] = v;
    __syncthreads();
    for (int o = 1; o < 1024; o <<= 1) {
      int t = (threadIdx.x >= o) ? sh[threadIdx.x - o] : 0;
      __syncthreads();
      sh[threadIdx.x] += t;
      __syncthreads();
    }
    if (i < n) b[i] = sh[threadIdx.x] - v + sc;
    __syncthreads();
    if (threadIdx.x == 0) sc += sh[1023];
    __syncthreads();
  }
  if (threadIdx.x == 0) *total = sc;
}

// ---------- pooled values (f16 in/out, vectorized f16x8) ----------
template <int C>
__global__ void pool_val_f16_k(const half_t* __restrict__ xin, const int* __restrict__ invp,
                               const int* __restrict__ list, const int* __restrict__ cnt,
                               int Hp, int Wp, int Ho, int Wo, half_t* __restrict__ y) {
  constexpr int CV = C / 8;
  long total = (long)cnt[0] * CV;
  for (long i = (long)blockIdx.x * TPB + threadIdx.x; i < total; i += (long)gridDim.x * TPB) {
    int cb = (int)(i & (CV - 1));
    int r = (int)(i / CV);
    int site = list[r];
    int wo = site % Wo; int t = site / Wo; int ho = t % Ho; int bb = t / Ho;
    long rb = ((long)bb * Hp + 2 * ho) * Wp + 2 * wo;
    float best[8];
    #pragma unroll
    for (int z = 0; z < 8; ++z) best[z] = -1e30f;
    #pragma unroll
    for (int kh = 0; kh < 3; ++kh)
      #pragma unroll
      for (int kw = 0; kw < 3; ++kw) {
        int j = invp[rb + kh * Wp + kw];
        if (j >= 0) {
          f16x8 v = *(const f16x8*)(xin + (long)j * C + cb * 8);
          #pragma unroll
          for (int z = 0; z < 8; ++z) best[z] = fmaxf(best[z], (float)v[z]);
        }
      }
    f16x8 o;
    #pragma unroll
    for (int z = 0; z < 8; ++z) o[z] = (half_t)best[z];
    *(f16x8*)(y + (long)r * C + cb * 8) = o;
  }
}

// ---------- mega prep: weight pack (y=0..13) + zfill (y=14) + W1 transpose (y=15) ----------
// Segs 5..13 (CI,CO multiples of 64) use 64x64 LDS tile transpose for coalesced reads.
struct PackArgs {
  const float* src[14];
  half_t* dst[14];
  const float* W1;
  half_t* w1t;
  float* h1;
  float* h2;
  half_t* df;
};

__global__ void megaprep_k(PackArgs pa) {
  __shared__ float tile[64][65];
  const int seg = blockIdx.y;
  const int tci[14]  = {2, 16, 16, 32, 32, 64, 64, 128, 128, 256, 256, 256, 256, 256};
  const int tco[14]  = {16, 16, 32, 32, 64, 64, 128, 128, 256, 256, 256, 256, 256, 256};
  const int tkp[14]  = {32, 160, 160, 288, 0, 0, 0, 0, 0, 0, 0, 0, 0, 0};
  const int twci[14] = {2, 16, 16, 32, 32, 64, 64, 128, 128, 256, 512, 512, 512, 512};
  const int twco[14] = {16, 16, 32, 32, 64, 64, 128, 128, 256, 256, 512, 256, 512, 256};
  if (seg < 5) {
    // scalar pack: K-packed (segs 0-3) or small per-tap (seg 4)
    const int CI = tci[seg], CO = tco[seg], KP = tkp[seg];
    const int wci = twci[seg], wco = twco[seg];
    const float* __restrict__ src = pa.src[seg];
    half_t* __restrict__ dst = pa.dst[seg];
    if (KP > 0) {
      long total = (long)CO * KP;
      for (long i = (long)blockIdx.x * TPB + threadIdx.x; i < total; i += (long)gridDim.x * TPB) {
        int k = (int)(i % KP), co = (int)(i / KP);
        int tap = k / CI, ci = k - tap * CI;
        float v = (tap < 9) ? src[((long)tap * wci + ci) * wco + co] : 0.f;
        dst[i] = (half_t)v;
      }
    } else {
      long total = 9L * CO * CI;
      for (long i = (long)blockIdx.x * TPB + threadIdx.x; i < total; i += (long)gridDim.x * TPB) {
        int ci = (int)(i % CI);
        long t = i / CI;
        int co = (int)(t % CO);
        int tap = (int)(t / CO);
        dst[i] = (half_t)src[((long)tap * wci + ci) * wco + co];
      }
    }
  } else if (seg < 14) {
    // tiled transpose pack: dst[(tap*CO+co)*CI+ci] = f16(src[(tap*wci+ci)*wco+co])
    const int CI = tci[seg], CO = tco[seg];
    const int wci = twci[seg], wco = twco[seg];
    const int cit_n = CI >> 6, cot_n = CO >> 6;
    const int ntiles = 9 * cit_n * cot_n;
    int bx = blockIdx.x;
    if (bx >= ntiles) return;
    int tap = bx / (cit_n * cot_n);
    int rem = bx - tap * (cit_n * cot_n);
    int cit = rem / cot_n, cot = rem - cit * cot_n;
    const float* __restrict__ src = pa.src[seg];
    half_t* __restrict__ dst = pa.dst[seg];
    const long sbase = ((long)tap * wci + cit * 64) * wco + cot * 64;
    for (int i = threadIdx.x; i < 4096; i += TPB) {
      int r = i >> 6, c = i & 63;
      tile[r][c] = src[sbase + (long)r * wco + c];
    }
    __syncthreads();
    const long dbase = ((long)tap * CO + cot * 64) * CI + cit * 64;
    for (int i = threadIdx.x; i < 4096; i += TPB) {
      int r = i >> 6, c = i & 63;
      dst[dbase + (long)r * CI + c] = (half_t)tile[c][r];
    }
  } else if (seg == 14) {
    for (long i = (long)blockIdx.x * TPB + threadIdx.x; i < 286720; i += (long)gridDim.x * TPB) {
      pa.h1[i] = 0.f;
      pa.h2[i] = 0.f;
      pa.df[i] = (half_t)0.f;
    }
  } else {
    // W1 transpose: bx -> (kc, jc), 140*16 = 2240 tiles
    int bx = blockIdx.x;
    if (bx >= 2240) return;
    int k0 = (bx >> 4) * 64, j0 = (bx & 15) * 64;
    for (int i = threadIdx.x; i < 4096; i += TPB) {
      int r = i >> 6, c = i & 63;
      tile[r][c] = pa.W1[(long)(k0 + r) * 1024 + j0 + c];
    }
    __syncthreads();
    for (int i = threadIdx.x; i < 4096; i += TPB) {
      int r = i >> 6, c = i & 63;
      pa.w1t[(long)(j0 + r) * 8960 + k0 + c] = (half_t)tile[c][r];
    }
  }
}

// ---------- K-packed MFMA conv (CO<=32); 64 sites/block; f16 out ----------
template <int CI, int CO, bool DENSE>
__global__ __launch_bounds__(256) void mconvp_k(const half_t* __restrict__ X,
                                                const half_t* __restrict__ Wt,
                                                half_t* __restrict__ y,
                                                const int* __restrict__ inv,
                                                const int* __restrict__ list,
                                                const int* __restrict__ cnt,
                                                int H, int W) {
  constexpr int KP = ((9 * CI + 31) / 32) * 32;
  constexpr int NCO = CO / 16;
  const int nact = cnt[0];
  const int base = blockIdx.x * 64;
  if (base >= nact) return;
  __shared__ int nbr[64 * 9];
  for (int i = threadIdx.x; i < 64 * 9; i += TPB) {
    int s = i / 9, nb = i - s * 9;
    int j = -1;
    if (base + s < nact) {
      int site = list[base + s];
      int w = site % W; int t = site / W; int h = t % H; int bb = t / H;
      int hh = h + nb / 3 - 1, ww = w + nb % 3 - 1;
      if ((unsigned)hh < (unsigned)H && (unsigned)ww < (unsigned)W) {
        int ss = (bb * H + hh) * W + ww;
        j = DENSE ? ss : inv[ss];
      }
    }
    nbr[i] = j;
  }
  __syncthreads();
  const int lane = threadIdx.x & 63, wv = threadIdx.x >> 6;
  const int srow = lane & 15, kseg = lane >> 4;
  const int sloc = wv * 16 + srow;
  f32x4 acc[NCO];
  #pragma unroll
  for (int c = 0; c < NCO; ++c) acc[c] = (f32x4){0.f, 0.f, 0.f, 0.f};
  #pragma unroll
  for (int k0 = 0; k0 < KP; k0 += 32) {
    const int k = k0 + kseg * 8;
    f16x8 av;
    #pragma unroll
    for (int z = 0; z < 8; ++z) av[z] = (_Float16)0.f;
    if (CI >= 8) {
      int tap = k / CI;
      int ci = k - tap * CI;
      if (tap < 9) {
        int j = nbr[sloc * 9 + tap];
        if (j >= 0) av = *(const f16x8*)(X + (long)j * CI + ci);
      }
    } else {  // CI == 2
      #pragma unroll
      for (int q = 0; q < 4; ++q) {
        int kk = k + 2 * q;
        int tap = kk >> 1;
        if (tap < 9) {
          int j = nbr[sloc * 9 + tap];
          if (j >= 0) {
            const half_t* xp = X + (long)j * 2;
            av[2 * q] = xp[0];
            av[2 * q + 1] = xp[1];
          }
        }
      }
    }
    #pragma unroll
    for (int c = 0; c < NCO; ++c) {
      f16x8 bv = *(const f16x8*)(Wt + (long)(c * 16 + srow) * KP + k);
      acc[c] = __builtin_amdgcn_mfma_f32_16x16x32_f16(av, bv, acc[c], 0, 0, 0);
    }
  }
  #pragma unroll
  for (int c = 0; c < NCO; ++c)
    #pragma unroll
    for (int r = 0; r < 4; ++r) {
      int ss = base + wv * 16 + kseg * 4 + r;
      if (ss < nact) y[(long)ss * CO + c * 16 + srow] = (half_t)acc[c][r];
    }
}

// ---------- LDS-staged-weight conv: 64 sites x 64 co per block, W[tap] in LDS ----------
template <int CI>
__global__ __launch_bounds__(256) void mconv_lds_k(const half_t* __restrict__ X,
                                                   const half_t* __restrict__ Wt,
                                                   half_t* __restrict__ y,
                                                   const int* __restrict__ inv,
                                                   const int* __restrict__ list,
                                                   const int* __restrict__ cnt,
                                                   int H, int W, int COfull) {
  constexpr int NK = CI / 32;
  constexpr int LDW = CI + 8;
  __shared__ half_t wlds[64 * LDW];
  const int nact = cnt[0];
  const int base = blockIdx.x * 64;
  if (base >= nact) return;
  const int lane = threadIdx.x & 63, wv = threadIdx.x >> 6;
  const int srow = lane & 15, kseg = lane >> 4;
  const int co0 = blockIdx.y * 64;
  int jj[9];
  {
    int s = base + wv * 16 + srow;
    bool sv = (s < nact);
    int h = 0, w = 0, bb = 0;
    if (sv) {
      int site = list[s];
      w = site % W;
      int t = site / W;
      h = t % H;
      bb = t / H;
    }
    #pragma unroll
    for (int tap = 0; tap < 9; ++tap) {
      int j = -1;
      if (sv) {
        int hh = h + tap / 3 - 1, ww = w + tap % 3 - 1;
        if ((unsigned)hh < (unsigned)H && (unsigned)ww < (unsigned)W)
          j = inv[(bb * H + hh) * W + ww];
      }
      jj[tap] = j;
    }
  }
  f32x4 acc[4];
  #pragma unroll
  for (int b = 0; b < 4; ++b) acc[b] = (f32x4){0.f, 0.f, 0.f, 0.f};
  for (int tap = 0; tap < 9; ++tap) {
    __syncthreads();
    constexpr int GR = 64 * (CI / 8);
    const half_t* wsrc = Wt + ((long)tap * COfull + co0) * CI;
    for (int idx = threadIdx.x; idx < GR; idx += TPB) {
      int row = idx / (CI / 8), cb = idx % (CI / 8);
      *(f16x8*)(&wlds[row * LDW + cb * 8]) = *(const f16x8*)(wsrc + (long)row * CI + cb * 8);
    }
    __syncthreads();
    const int j = jj[tap];
    f16x8 av[NK];
    #pragma unroll
    for (int s = 0; s < NK; ++s) {
      #pragma unroll
      for (int z = 0; z < 8; ++z) av[s][z] = (_Float16)0.f;
      if (j >= 0) av[s] = *(const f16x8*)(X + (long)j * CI + kseg * 8 + s * 32);
    }
    #pragma unroll
    for (int s = 0; s < NK; ++s) {
      #pragma unroll
      for (int b = 0; b < 4; ++b) {
        f16x8 bv = *(const f16x8*)(&wlds[(b * 16 + srow) * LDW + kseg * 8 + s * 32]);
        acc[b] = __builtin_amdgcn_mfma_f32_16x16x32_f16(av[s], bv, acc[b], 0, 0, 0);
      }
    }
  }
  #pragma unroll
  for (int b = 0; b < 4; ++b)
    #pragma unroll
    for (int r = 0; r < 4; ++r) {
      int ss = base + wv * 16 + kseg * 4 + r;
      if (ss < nact) y[(long)ss * COfull + co0 + b * 16 + srow] = (half_t)acc[b][r];
    }
}

// ---------- fused GRU conv: 16 sites x 16 co per block (grid 70x16) ----------
template <int CI>
__global__ __launch_bounds__(256) void gruconv16_k(const half_t* __restrict__ X,
                                                   const half_t* __restrict__ Wg,
                                                   const half_t* __restrict__ Wc,
                                                   float* __restrict__ hdense,
                                                   half_t* __restrict__ hcomp,
                                                   half_t* __restrict__ dflat,
                                                   const int* __restrict__ inv,
                                                   const int* __restrict__ list,
                                                   const int* __restrict__ cnt,
                                                   int H, int W) {
  constexpr int CO = 256;
  constexpr int NK = CI / 32;
  const int nact = cnt[0];
  const int base = blockIdx.x * 16;
  if (base >= nact) return;
  __shared__ int nbr[16 * 9];
  __shared__ float red[4][16][34];
  for (int i = threadIdx.x; i < 16 * 9; i += TPB) {
    int s = i / 9, nb = i - s * 9;
    int j = -1;
    if (base + s < nact) {
      int site = list[base + s];
      int w = site % W; int t = site / W; int h = t % H; int bb = t / H;
      int hh = h + nb / 3 - 1, ww = w + nb % 3 - 1;
      if ((unsigned)hh < (unsigned)H && (unsigned)ww < (unsigned)W)
        j = inv[(bb * H + hh) * W + ww];
    }
    nbr[i] = j;
  }
  __syncthreads();
  const int lane = threadIdx.x & 63, wv = threadIdx.x >> 6;
  const int srow = lane & 15, kseg = lane >> 4;
  const int co0 = blockIdx.y * 16;
  const int t0 = (wv * 9) / 4, t1 = ((wv + 1) * 9) / 4;
  f32x4 g = {0.f, 0.f, 0.f, 0.f};
  f32x4 c = g;
  for (int tap = t0; tap < t1; ++tap) {
    int j = nbr[srow * 9 + tap];
    const half_t* xp = X + (long)j * CI + kseg * 8;
    const half_t* wgp = Wg + ((long)tap * CO + co0 + srow) * CI + kseg * 8;
    const half_t* wcp = Wc + ((long)tap * CO + co0 + srow) * CI + kseg * 8;
    f16x8 av[NK];
    #pragma unroll
    for (int s = 0; s < NK; ++s) {
      #pragma unroll
      for (int z = 0; z < 8; ++z) av[s][z] = (_Float16)0.f;
      if (j >= 0) av[s] = *(const f16x8*)(xp + s * 32);
    }
    #pragma unroll
    for (int s = 0; s < NK; ++s) {
      f16x8 bg = *(const f16x8*)(wgp + s * 32);
      f16x8 bc = *(const f16x8*)(wcp + s * 32);
      g = __builtin_amdgcn_mfma_f32_16x16x32_f16(av[s], bg, g, 0, 0, 0);
      c = __builtin_amdgcn_mfma_f32_16x16x32_f16(av[s], bc, c, 0, 0, 0);
    }
  }
  #pragma unroll
  for (int r = 0; r < 4; ++r) {
    int s = kseg * 4 + r;
    red[wv][s][srow] = g[r];
    red[wv][s][16 + srow] = c[r];
  }
  __syncthreads();
  {
    int i = threadIdx.x;
    int s = i >> 4, co = i & 15;
    float gs = red[0][s][co] + red[1][s][co] + red[2][s][co] + red[3][s][co];
    float cs = red[0][s][16 + co] + red[1][s][16 + co] + red[2][s][16 + co] + red[3][s][16 + co];
    int ss = base + s;
    if (ss < nact) {
      float u = 1.f / (1.f + expf(-gs));
      float v = u * tanhf(cs);
      if (hcomp) hcomp[(long)ss * CO + co0 + co] = (half_t)v;
      int site = list[ss];
      hdense[(long)site * CO + co0 + co] = v;
      if (dflat) {
        int b = site / 35, s2 = site - b * 35;
        dflat[(long)b * 8960 + (co0 + co) * 35 + s2] = (half_t)v;
      }
    }
  }
}

// ---------- BN (f16 activations) ----------
template <int CO>
__global__ void bn_stats2_k(const half_t* __restrict__ y, const int* __restrict__ cnt,
                            float* __restrict__ stats) {
  __shared__ float ls[512];
  for (int i = threadIdx.x; i < 2 * CO; i += TPB) ls[i] = 0.f;
  __syncthreads();
  long total = (long)cnt[0] * CO;
  long i0 = (long)blockIdx.x * TPB + threadIdx.x;
  int c = (int)(i0 & (CO - 1));
  float s = 0.f, s2 = 0.f;
  for (long i = i0; i < total; i += (long)gridDim.x * TPB) {
    float v = (float)y[i];
    s += v; s2 += v * v;
  }
  atomicAdd(&ls[c], s);
  atomicAdd(&ls[CO + c], s2);
  __syncthreads();
  for (int i = threadIdx.x; i < 2 * CO; i += TPB) atomicAdd(&stats[i], ls[i]);
}

template <int C>
__global__ void bnapply_f16_k(const half_t* __restrict__ y, const int* __restrict__ cnt,
                              const float* __restrict__ stats, const float* __restrict__ gamma,
                              const float* __restrict__ beta, half_t* __restrict__ out) {
  __shared__ float sc[C], sh2[C];
  for (int c = threadIdx.x; c < C; c += TPB) {
    float n = fmaxf((float)cnt[0], 1.f);
    float mean = stats[c] / n;
    float var = fmaxf(stats[C + c] / n - mean * mean, 0.f);
    float s = gamma[c] * rsqrtf(var + 1e-4f);
    sc[c] = s;
    sh2[c] = beta[c] - mean * s;
  }
  __syncthreads();
  long total = (long)cnt[0] * C;
  for (long i = (long)blockIdx.x * TPB + threadIdx.x; i < total; i += (long)gridDim.x * TPB) {
    int c = (int)(i & (C - 1));
    out[i] = (half_t)fmaxf(fmaf((float)y[i], sc[c], sh2[c]), 0.f);
  }
}

// ---------- head: MFMA lin1 ----------
#define KS1 35
__global__ __launch_bounds__(256) void lin1m_k(const half_t* __restrict__ D,
                                               const half_t* __restrict__ W1T,
                                               float* __restrict__ part) {
  __shared__ float red[4][32][65];
  const int lane = threadIdx.x & 63, wv = threadIdx.x >> 6;
  const int srow = lane & 15, kseg = lane >> 4;
  const int kc = blockIdx.x, j0 = blockIdx.y * 64;
  const int kbase = kc * 256 + wv * 64;
  f32x4 acc[2][4];
  #pragma unroll
  for (int m = 0; m < 2; ++m)
    #pragma unroll
    for (int b = 0; b < 4; ++b) acc[m][b] = (f32x4){0.f, 0.f, 0.f, 0.f};
  #pragma unroll
  for (int step = 0; step < 2; ++step) {
    int k = kbase + step * 32 + kseg * 8;
    f16x8 a0 = *(const f16x8*)(D + (long)srow * 8960 + k);
    f16x8 a1 = *(const f16x8*)(D + (long)(16 + srow) * 8960 + k);
    #pragma unroll
    for (int b = 0; b < 4; ++b) {
      f16x8 bv = *(const f16x8*)(W1T + (long)(j0 + b * 16 + srow) * 8960 + k);
      acc[0][b] = __builtin_amdgcn_mfma_f32_16x16x32_f16(a0, bv, acc[0][b], 0, 0, 0);
      acc[1][b] = __builtin_amdgcn_mfma_f32_16x16x32_f16(a1, bv, acc[1][b], 0, 0, 0);
    }
  }
  #pragma unroll
  for (int m = 0; m < 2; ++m)
    #pragma unroll
    for (int b = 0; b < 4; ++b)
      #pragma unroll
      for (int r = 0; r < 4; ++r)
        red[wv][m * 16 + kseg * 4 + r][b * 16 + srow] = acc[m][b][r];
  __syncthreads();
  for (int i = threadIdx.x; i < 32 * 64; i += TPB) {
    int row = i >> 6, col = i & 63;
    float v = red[0][row][col] + red[1][row][col] + red[2][row][col] + red[3][row][col];
    part[(long)kc * 32768 + row * 1024 + j0 + col] = v;
  }
}

__global__ void lin1_reduce_k(const float* __restrict__ part, const float* __restrict__ b1,
                              float* __restrict__ y1) {
  int i = blockIdx.x * TPB + threadIdx.x;
  if (i >= 32 * 1024) return;
  int b = i >> 10, j = i & 1023;
  float a = b1[j];
  #pragma unroll
  for (int kc = 0; kc < KS1; ++kc) a += part[(long)kc * 32768 + b * 1024 + j];
  y1[i] = fmaxf(a, 0.f);
}

#define JS2 8
__global__ void lin2_part_k(const float* __restrict__ y1, const float* __restrict__ W2,
                            float* __restrict__ part2) {
  int i = blockIdx.x * TPB + threadIdx.x;
  if (i >= 32 * 420) return;
  int b = i / 420, o = i - b * 420;
  int j0 = blockIdx.y * 128;
  float a = 0.f;
  const float* yp = y1 + b * 1024 + j0;
  const float* wp = W2 + (long)j0 * 420 + o;
  #pragma unroll 8
  for (int j = 0; j < 128; ++j) a = fmaf(yp[j], wp[(long)j * 420], a);
  part2[(long)blockIdx.y * 13440 + i] = a;
}

__global__ void lin2_fin_k(const float* __restrict__ part2, const float* __restrict__ b2,
                           float* __restrict__ out) {
  int i = blockIdx.x * TPB + threadIdx.x;
  if (i >= 32 * 420) return;
  int o = i % 420;
  float a = b2[o];
  #pragma unroll
  for (int js = 0; js < JS2; ++js) a += part2[(long)js * 13440 + i];
  out[i] = a;
}

extern "C" void kernel_launch(void* const* d_in, const int* in_sizes, int n_in,
                              void* d_out, int out_size, void* d_ws, size_t ws_size,
                              hipStream_t stream) {
  const float* x = (const float*)d_in[0];
  const float* ca[5] = {(const float*)d_in[2], (const float*)d_in[6], (const float*)d_in[10],
                        (const float*)d_in[14], (const float*)d_in[18]};
  const float* bg[5] = {(const float*)d_in[3], (const float*)d_in[7], (const float*)d_in[11],
                        (const float*)d_in[15], (const float*)d_in[19]};
  const float* bb[5] = {(const float*)d_in[4], (const float*)d_in[8], (const float*)d_in[12],
                        (const float*)d_in[16], (const float*)d_in[20]};
  const float* cb[5] = {(const float*)d_in[5], (const float*)d_in[9], (const float*)d_in[13],
                        (const float*)d_in[17], (const float*)d_in[21]};
  const float* g1Wg = (const float*)d_in[22];
  const float* g1Wc = (const float*)d_in[23];
  const float* g2Wg = (const float*)d_in[24];
  const float* g2Wc = (const float*)d_in[25];
  const float* W1 = (const float*)d_in[26];
  const float* b1 = (const float*)d_in[27];
  const float* W2 = (const float*)d_in[28];
  const float* b2 = (const float*)d_in[29];

  const int Hs[6] = {191, 95, 47, 23, 11, 5};
  const int Wd[6] = {255, 127, 63, 31, 15, 7};
  const long NS[6] = {1558560, 386080, 94752, 22816, 5280, 1120};
  const int cap[6] = {160000, 386080, 94752, 22816, 5280, 1120};

  float* ws = (float*)d_ws;
  long off = 0;
  float* part = ws + off;  off += 1200000;
  float* part2 = ws + off; off += 120000;
  float* stats = ws + off; off += 512;
  float* y1 = ws + off;    off += 32L * 1024;

  half_t* hbase = (half_t*)(ws + off);
  long hoff = 0;
  half_t* hbufA = hbase + hoff; hoff += 6500000;
  half_t* hbufB = hbase + hoff; hoff += 6500000;
  half_t* hbufC = hbase + hoff; hoff += 6500000;
  half_t* xh = hbase + hoff;    hoff += 3117120;
  half_t* w1t = hbase + hoff;   hoff += 9175040;
  half_t* df16 = hbase + hoff;  hoff += 286720;
  half_t* wp_ca0 = hbase + hoff; hoff += 16L * 32;
  half_t* wp_cb0 = hbase + hoff; hoff += 16L * 160;
  half_t* wp_ca1 = hbase + hoff; hoff += 32L * 160;
  half_t* wp_cb1 = hbase + hoff; hoff += 32L * 288;
  half_t* wt_ca2 = hbase + hoff; hoff += 9L * 64 * 32;
  half_t* wt_cb2 = hbase + hoff; hoff += 9L * 64 * 64;
  half_t* wt_ca3 = hbase + hoff; hoff += 9L * 128 * 64;
  half_t* wt_cb3 = hbase + hoff; hoff += 9L * 128 * 128;
  half_t* wt_ca4 = hbase + hoff; hoff += 9L * 256 * 128;
  half_t* wt_cb4 = hbase + hoff; hoff += 9L * 256 * 256;
  half_t* wt_g1g = hbase + hoff; hoff += 9L * 256 * 256;
  half_t* wt_g1c = hbase + hoff; hoff += 9L * 256 * 256;
  half_t* wt_g2g = hbase + hoff; hoff += 9L * 256 * 256;
  half_t* wt_g2c = hbase + hoff; hoff += 9L * 256 * 256;

  int* ip = (int*)(hbase + hoff);
  long ioff = 0;
  int* cnt = ip + ioff; ioff += 16;
  int* bcnt = ip + ioff; ioff += 8192;
  int* list[6]; int* inv[6];
  for (int l = 0; l < 6; ++l) { list[l] = ip + ioff; ioff += cap[l]; }
  for (int l = 0; l < 6; ++l) { inv[l] = ip + ioff; ioff += NS[l]; }
  uint8_t* actm = (uint8_t*)(ip + ioff);
  long aoff = NS[1];
  size_t needed = (size_t)off * 4 + (size_t)hoff * 2 + (size_t)ioff * 4 + (size_t)aoff;
  if (ws_size < needed) return;

  float* h1d = (float*)d_out + 13440;
  float* h2d = h1d + 286720;

  // ---- one-shot prep: weight pack (tiled transpose for big segs) + W1 transpose + zero fills ----
  PackArgs pa;
  pa.src[0] = ca[0]; pa.dst[0] = wp_ca0;
  pa.src[1] = cb[0]; pa.dst[1] = wp_cb0;
  pa.src[2] = ca[1]; pa.dst[2] = wp_ca1;
  pa.src[3] = cb[1]; pa.dst[3] = wp_cb1;
  pa.src[4] = ca[2]; pa.dst[4] = wt_ca2;
  pa.src[5] = cb[2]; pa.dst[5] = wt_cb2;
  pa.src[6] = ca[3]; pa.dst[6] = wt_ca3;
  pa.src[7] = cb[3]; pa.dst[7] = wt_cb3;
  pa.src[8] = ca[4]; pa.dst[8] = wt_ca4;
  pa.src[9] = cb[4]; pa.dst[9] = wt_cb4;
  pa.src[10] = g1Wg; pa.dst[10] = wt_g1g;
  pa.src[11] = g1Wc; pa.dst[11] = wt_g1c;
  pa.src[12] = g2Wg; pa.dst[12] = wt_g2g;
  pa.src[13] = g2Wc; pa.dst[13] = wt_g2c;
  pa.W1 = W1; pa.w1t = w1t;
  pa.h1 = h1d; pa.h2 = h2d; pa.df = df16;
  megaprep_k<<<dim3(2240, 16), TPB, 0, stream>>>(pa);

  // ---- level-0 compaction (also x->f16) ----
  {
    int nb = nblk(NS[0]);
    cmpA0_k<<<nb, TPB, 0, stream>>>(x, (int)NS[0], bcnt);
    scan_k<<<1, 1024, 0, stream>>>(bcnt, nb, cnt + 0, stats);
    cmpB0_k<<<nb, TPB, 0, stream>>>(x, (int)NS[0], bcnt, list[0], inv[0], cap[0], xh);
  }

  // ---------- level 1 ----------
  mconvp_k<2, 16, true><<<(cap[0] + 63) / 64, TPB, 0, stream>>>(
      xh, wp_ca0, hbufC, nullptr, list[0], cnt + 0, Hs[0], Wd[0]);
  bn_stats2_k<16><<<288, TPB, 0, stream>>>(hbufC, cnt + 0, stats);
  bnapply_f16_k<16><<<2048, TPB, 0, stream>>>(hbufC, cnt + 0, stats, bg[0], bb[0], hbufA);
  mconvp_k<16, 16, false><<<(cap[0] + 63) / 64, TPB, 0, stream>>>(
      hbufA, wp_cb0, hbufC, inv[0], list[0], cnt + 0, Hs[0], Wd[0]);
  {
    int nb = nblk(NS[1]);
    poolA_k<<<nb, TPB, 0, stream>>>(inv[0], Hs[0], Wd[0], Hs[1], Wd[1], (int)NS[1], bcnt, actm);
    scan_k<<<1, 1024, 0, stream>>>(bcnt, nb, cnt + 1, stats);
    poolB_k<<<nb, TPB, 0, stream>>>(actm, (int)NS[1], bcnt, list[1], inv[1], cap[1]);
  }
  pool_val_f16_k<16><<<1024, TPB, 0, stream>>>(hbufC, inv[0], list[1], cnt + 1, Hs[0], Wd[0], Hs[1], Wd[1], hbufB);

  // ---------- level 2 ----------
  mconvp_k<16, 32, false><<<(cap[1] + 63) / 64, TPB, 0, stream>>>(
      hbufB, wp_ca1, hbufC, inv[1], list[1], cnt + 1, Hs[1], Wd[1]);
  bn_stats2_k<32><<<288, TPB, 0, stream>>>(hbufC, cnt + 1, stats);
  bnapply_f16_k<32><<<2048, TPB, 0, stream>>>(hbufC, cnt + 1, stats, bg[1], bb[1], hbufA);
  mconvp_k<32, 32, false><<<(cap[1] + 63) / 64, TPB, 0, stream>>>(
      hbufA, wp_cb1, hbufC, inv[1], list[1], cnt + 1, Hs[1], Wd[1]);
  {
    int nb = nblk(NS[2]);
    poolA_k<<<nb, TPB, 0, stream>>>(inv[1], Hs[1], Wd[1], Hs[2], Wd[2], (int)NS[2], bcnt, actm);
    scan_k<<<1, 1024, 0, stream>>>(bcnt, nb, cnt + 2, stats);
    poolB_k<<<nb, TPB, 0, stream>>>(actm, (int)NS[2], bcnt, list[2], inv[2], cap[2]);
  }
  pool_val_f16_k<32><<<1024, TPB, 0, stream>>>(hbufC, inv[1], list[2], cnt + 2, Hs[1], Wd[1], Hs[2], Wd[2], hbufB);

  // ---------- level 3 (LDS-staged weights) ----------
  mconv_lds_k<32><<<dim3((cap[2] + 63) / 64, 1), TPB, 0, stream>>>(
      hbufB, wt_ca2, hbufC, inv[2], list[2], cnt + 2, Hs[2], Wd[2], 64);
  bn_stats2_k<64><<<288, TPB, 0, stream>>>(hbufC, cnt + 2, stats);
  bnapply_f16_k<64><<<2048, TPB, 0, stream>>>(hbufC, cnt + 2, stats, bg[2], bb[2], hbufA);
  mconv_lds_k<64><<<dim3((cap[2] + 63) / 64, 1), TPB, 0, stream>>>(
      hbufA, wt_cb2, hbufC, inv[2], list[2], cnt + 2, Hs[2], Wd[2], 64);
  {
    int nb = nblk(NS[3]);
    poolA_k<<<nb, TPB, 0, stream>>>(inv[2], Hs[2], Wd[2], Hs[3], Wd[3], (int)NS[3], bcnt, actm);
    scan_k<<<1, 1024, 0, stream>>>(bcnt, nb, cnt + 3, stats);
    poolB_k<<<nb, TPB, 0, stream>>>(actm, (int)NS[3], bcnt, list[3], inv[3], cap[3]);
  }
  pool_val_f16_k<64><<<1024, TPB, 0, stream>>>(hbufC, inv[2], list[3], cnt + 3, Hs[2], Wd[2], Hs[3], Wd[3], hbufB);

  // ---------- level 4 (LDS-staged weights) ----------
  mconv_lds_k<64><<<dim3((cap[3] + 63) / 64, 2), TPB, 0, stream>>>(
      hbufB, wt_ca3, hbufC, inv[3], list[3], cnt + 3, Hs[3], Wd[3], 128);
  bn_stats2_k<128><<<288, TPB, 0, stream>>>(hbufC, cnt + 3, stats);
  bnapply_f16_k<128><<<2048, TPB, 0, stream>>>(hbufC, cnt + 3, stats, bg[3], bb[3], hbufA);
  mconv_lds_k<128><<<dim3((cap[3] + 63) / 64, 2), TPB, 0, stream>>>(
      hbufA, wt_cb3, hbufC, inv[3], list[3], cnt + 3, Hs[3], Wd[3], 128);
  {
    int nb = nblk(NS[4]);
    poolA_k<<<nb, TPB, 0, stream>>>(inv[3], Hs[3], Wd[3], Hs[4], Wd[4], (int)NS[4], bcnt, actm);
    scan_k<<<1, 1024, 0, stream>>>(bcnt, nb, cnt + 4, stats);
    poolB_k<<<nb, TPB, 0, stream>>>(actm, (int)NS[4], bcnt, list[4], inv[4], cap[4]);
  }
  pool_val_f16_k<128><<<1024, TPB, 0, stream>>>(hbufC, inv[3], list[4], cnt + 4, Hs[3], Wd[3], Hs[4], Wd[4], hbufB);

  // ---------- level 5 (LDS-staged weights) ----------
  mconv_lds_k<128><<<dim3((cap[4] + 63) / 64, 4), TPB, 0, stream>>>(
      hbufB, wt_ca4, hbufC, inv[4], list[4], cnt + 4, Hs[4], Wd[4], 256);
  bn_stats2_k<256><<<288, TPB, 0, stream>>>(hbufC, cnt + 4, stats);
  bnapply_f16_k<256><<<2048, TPB, 0, stream>>>(hbufC, cnt + 4, stats, bg[4], bb[4], hbufA);
  mconv_lds_k<256><<<dim3((cap[4] + 63) / 64, 4), TPB, 0, stream>>>(
      hbufA, wt_cb4, hbufC, inv[4], list[4], cnt + 4, Hs[4], Wd[4], 256);
  {
    int nb = nblk(NS[5]);
    poolA_k<<<nb, TPB, 0, stream>>>(inv[4], Hs[4], Wd[4], Hs[5], Wd[5], (int)NS[5], bcnt, actm);
    scan_k<<<1, 1024, 0, stream>>>(bcnt, nb, cnt + 5, stats);
    poolB_k<<<nb, TPB, 0, stream>>>(actm, (int)NS[5], bcnt, list[5], inv[5], cap[5]);
  }
  pool_val_f16_k<256><<<1024, TPB, 0, stream>>>(hbufC, inv[4], list[5], cnt + 5, Hs[4], Wd[4], Hs[5], Wd[5], hbufB);

  // ---------- GRUs (16-co tiles) ----------
  gruconv16_k<256><<<dim3((cap[5] + 15) / 16, 16), TPB, 0, stream>>>(
      hbufB, wt_g1g, wt_g1c, h1d, hbufA, nullptr, inv[5], list[5], cnt + 5, Hs[5], Wd[5]);
  gruconv16_k<256><<<dim3((cap[5] + 15) / 16, 16), TPB, 0, stream>>>(
      hbufA, wt_g2g, wt_g2c, h2d, nullptr, df16, inv[5], list[5], cnt + 5, Hs[5], Wd[5]);

  // ---------- head ----------
  lin1m_k<<<dim3(KS1, 16), TPB, 0, stream>>>(df16, w1t, part);
  lin1_reduce_k<<<nblk(32L * 1024), TPB, 0, stream>>>(part, b1, y1);
  lin2_part_k<<<dim3(nblk(32L * 420), JS2), TPB, 0, stream>>>(y1, W2, part2);
  lin2_fin_k<<<nblk(32L * 420), TPB, 0, stream>>>(part2, b2, (float*)d_out);
}

// Round 23
// 560.542 us; speedup vs baseline: 1.2525x; 1.0104x over previous
//
#include <hip/hip_runtime.h>
#include <stdint.h>

#define TPB 256

typedef _Float16 half_t;
typedef __attribute__((ext_vector_type(8))) _Float16 f16x8;
typedef __attribute__((ext_vector_type(4))) float f32x4;

static inline int nblk(long n) { return (int)((n + TPB - 1) / TPB); }

// ---------- scan-based compaction ----------
__global__ void cmpA0_k(const float* __restrict__ x, int n, int* __restrict__ bcnt) {
  int i = blockIdx.x * TPB + threadIdx.x;
  bool a = false;
  if (i < n) {
    float2 v = *(const float2*)(x + 2L * i);
    a = (v.x != 0.f) || (v.y != 0.f);
  }
  unsigned long long bal = __ballot(a);
  __shared__ int wc[4];
  if ((threadIdx.x & 63) == 0) wc[threadIdx.x >> 6] = __popcll(bal);
  __syncthreads();
  if (threadIdx.x == 0) bcnt[blockIdx.x] = wc[0] + wc[1] + wc[2] + wc[3];
}

// also converts x -> f16
__global__ void cmpB0_k(const float* __restrict__ x, int n, const int* __restrict__ bbase,
                        int* __restrict__ list, int* __restrict__ inv, int cap,
                        half_t* __restrict__ xh) {
  int i = blockIdx.x * TPB + threadIdx.x;
  float2 v = {0.f, 0.f};
  bool a = false;
  if (i < n) {
    v = *(const float2*)(x + 2L * i);
    a = (v.x != 0.f) || (v.y != 0.f);
  }
  unsigned long long bal = __ballot(a);
  __shared__ int wc[4];
  int wid = threadIdx.x >> 6, lane = threadIdx.x & 63;
  if (lane == 0) wc[wid] = __popcll(bal);
  __syncthreads();
  int base = bbase[blockIdx.x];
  for (int w = 0; w < wid; ++w) base += wc[w];
  if (i < n) {
    xh[2L * i] = (half_t)v.x;
    xh[2L * i + 1] = (half_t)v.y;
    int pos = base + __popcll(bal & ((1ull << lane) - 1));
    if (a && pos < cap) { list[pos] = i; inv[i] = pos; }
    else inv[i] = -1;
  }
}

__device__ __forceinline__ bool actp(const int* invp, int Hp, int Wp, int Ho, int Wo, int i) {
  int wo = i % Wo; int t = i / Wo; int ho = t % Ho; int bb = t / Ho;
  long rb = ((long)bb * Hp + 2 * ho) * Wp + 2 * wo;
  bool a = false;
  #pragma unroll
  for (int kh = 0; kh < 3; ++kh)
    #pragma unroll
    for (int kw = 0; kw < 3; ++kw)
      a |= (invp[rb + kh * Wp + kw] >= 0);
  return a;
}

// poolA: counts + writes activity byte mask
__global__ void poolA_k(const int* __restrict__ invp, int Hp, int Wp, int Ho, int Wo,
                        int n, int* __restrict__ bcnt, uint8_t* __restrict__ actm) {
  int i = blockIdx.x * TPB + threadIdx.x;
  bool a = (i < n) && actp(invp, Hp, Wp, Ho, Wo, i);
  if (i < n) actm[i] = (uint8_t)a;
  unsigned long long bal = __ballot(a);
  __shared__ int wc[4];
  if ((threadIdx.x & 63) == 0) wc[threadIdx.x >> 6] = __popcll(bal);
  __syncthreads();
  if (threadIdx.x == 0) bcnt[blockIdx.x] = wc[0] + wc[1] + wc[2] + wc[3];
}

// poolB: reads byte mask (no re-gather)
__global__ void poolB_k(const uint8_t* __restrict__ actm, int n,
                        const int* __restrict__ bbase, int* __restrict__ list,
                        int* __restrict__ inv, int cap) {
  int i = blockIdx.x * TPB + threadIdx.x;
  bool a = (i < n) && (actm[i] != 0);
  unsigned long long bal = __ballot(a);
  __shared__ int wc[4];
  int wid = threadIdx.x >> 6, lane = threadIdx.x & 63;
  if (lane == 0) wc[wid] = __popcll(bal);
  __syncthreads();
  int base = bbase[blockIdx.x];
  for (int w = 0; w < wid; ++w) base += wc[w];
  if (i < n) {
    int pos = base + __popcll(bal & ((1ull << lane) - 1));
    if (a && pos < cap) { list[pos] = i; inv[i] = pos; }
    else inv[i] = -1;
  }
}

// exclusive scan; total -> *total; zeroes stats
__global__ void scan_k(int* __restrict__ b, int n, int* __restrict__ total,
                       float* __restrict__ stats) {
  __shared__ int sh[1024];
  __shared__ int sc;
  if (threadIdx.x < 512) stats[threadIdx.x] = 0.f;
  if (threadIdx.x == 0) sc = 0;
  __syncthreads();
  for (int base = 0; base < n; base += 1024) {
    int i = base + threadIdx.x;
    int v = (i < n) ? b[i] : 0;
    sh[threadIdx.x] = v;
    __syncthreads();
    for (int o = 1; o < 1024; o <<= 1) {
      int t = (threadIdx.x >= o) ? sh[threadIdx.x - o] : 0;
      __syncthreads();
      sh[threadIdx.x] += t;
      __syncthreads();
    }
    if (i < n) b[i] = sh[threadIdx.x] - v + sc;
    __syncthreads();
    if (threadIdx.x == 0) sc += sh[1023];
    __syncthreads();
  }
  if (threadIdx.x == 0) *total = sc;
}

// ---------- pooled values (f16 in/out, vectorized f16x8) ----------
template <int C>
__global__ void pool_val_f16_k(const half_t* __restrict__ xin, const int* __restrict__ invp,
                               const int* __restrict__ list, const int* __restrict__ cnt,
                               int Hp, int Wp, int Ho, int Wo, half_t* __restrict__ y) {
  constexpr int CV = C / 8;
  long total = (long)cnt[0] * CV;
  for (long i = (long)blockIdx.x * TPB + threadIdx.x; i < total; i += (long)gridDim.x * TPB) {
    int cb = (int)(i & (CV - 1));
    int r = (int)(i / CV);
    int site = list[r];
    int wo = site % Wo; int t = site / Wo; int ho = t % Ho; int bb = t / Ho;
    long rb = ((long)bb * Hp + 2 * ho) * Wp + 2 * wo;
    float best[8];
    #pragma unroll
    for (int z = 0; z < 8; ++z) best[z] = -1e30f;
    #pragma unroll
    for (int kh = 0; kh < 3; ++kh)
      #pragma unroll
      for (int kw = 0; kw < 3; ++kw) {
        int j = invp[rb + kh * Wp + kw];
        if (j >= 0) {
          f16x8 v = *(const f16x8*)(xin + (long)j * C + cb * 8);
          #pragma unroll
          for (int z = 0; z < 8; ++z) best[z] = fmaxf(best[z], (float)v[z]);
        }
      }
    f16x8 o;
    #pragma unroll
    for (int z = 0; z < 8; ++z) o[z] = (half_t)best[z];
    *(f16x8*)(y + (long)r * C + cb * 8) = o;
  }
}

// ---------- mega prep: weight pack (y=0..13) + zfill (y=14) + W1 transpose (y=15) ----------
// Segs 5..13 and W1 use 64x64 LDS tile transpose with float4 loads + f16x8 stores.
struct PackArgs {
  const float* src[14];
  half_t* dst[14];
  const float* W1;
  half_t* w1t;
  float* h1;
  float* h2;
  half_t* df;
};

__global__ void megaprep_k(PackArgs pa) {
  __shared__ float tile[64][65];
  const int seg = blockIdx.y;
  const int tci[14]  = {2, 16, 16, 32, 32, 64, 64, 128, 128, 256, 256, 256, 256, 256};
  const int tco[14]  = {16, 16, 32, 32, 64, 64, 128, 128, 256, 256, 256, 256, 256, 256};
  const int tkp[14]  = {32, 160, 160, 288, 0, 0, 0, 0, 0, 0, 0, 0, 0, 0};
  const int twci[14] = {2, 16, 16, 32, 32, 64, 64, 128, 128, 256, 512, 512, 512, 512};
  const int twco[14] = {16, 16, 32, 32, 64, 64, 128, 128, 256, 256, 512, 256, 512, 256};
  if (seg < 5) {
    // scalar pack: K-packed (segs 0-3) or small per-tap (seg 4)
    const int CI = tci[seg], CO = tco[seg], KP = tkp[seg];
    const int wci = twci[seg], wco = twco[seg];
    const float* __restrict__ src = pa.src[seg];
    half_t* __restrict__ dst = pa.dst[seg];
    if (KP > 0) {
      long total = (long)CO * KP;
      for (long i = (long)blockIdx.x * TPB + threadIdx.x; i < total; i += (long)gridDim.x * TPB) {
        int k = (int)(i % KP), co = (int)(i / KP);
        int tap = k / CI, ci = k - tap * CI;
        float v = (tap < 9) ? src[((long)tap * wci + ci) * wco + co] : 0.f;
        dst[i] = (half_t)v;
      }
    } else {
      long total = 9L * CO * CI;
      for (long i = (long)blockIdx.x * TPB + threadIdx.x; i < total; i += (long)gridDim.x * TPB) {
        int ci = (int)(i % CI);
        long t = i / CI;
        int co = (int)(t % CO);
        int tap = (int)(t / CO);
        dst[i] = (half_t)src[((long)tap * wci + ci) * wco + co];
      }
    }
  } else if (seg < 14) {
    // tiled transpose pack: dst[(tap*CO+co)*CI+ci] = f16(src[(tap*wci+ci)*wco+co])
    const int CI = tci[seg], CO = tco[seg];
    const int wci = twci[seg], wco = twco[seg];
    const int cit_n = CI >> 6, cot_n = CO >> 6;
    const int ntiles = 9 * cit_n * cot_n;
    int bx = blockIdx.x;
    if (bx >= ntiles) return;
    int tap = bx / (cit_n * cot_n);
    int rem = bx - tap * (cit_n * cot_n);
    int cit = rem / cot_n, cot = rem - cit * cot_n;
    const float* __restrict__ src = pa.src[seg];
    half_t* __restrict__ dst = pa.dst[seg];
    const long sbase = ((long)tap * wci + cit * 64) * wco + cot * 64;
    for (int i = threadIdx.x; i < 1024; i += TPB) {
      int r = i >> 4, c4 = i & 15;
      float4 v = *(const float4*)(src + sbase + (long)r * wco + c4 * 4);
      tile[r][c4 * 4 + 0] = v.x;
      tile[r][c4 * 4 + 1] = v.y;
      tile[r][c4 * 4 + 2] = v.z;
      tile[r][c4 * 4 + 3] = v.w;
    }
    __syncthreads();
    const long dbase = ((long)tap * CO + cot * 64) * CI + cit * 64;
    for (int i = threadIdx.x; i < 512; i += TPB) {
      int r = i >> 3, c8 = i & 7;
      f16x8 o;
      #pragma unroll
      for (int z = 0; z < 8; ++z) o[z] = (half_t)tile[c8 * 8 + z][r];
      *(f16x8*)(dst + dbase + (long)r * CI + c8 * 8) = o;
    }
  } else if (seg == 14) {
    for (long i = (long)blockIdx.x * TPB + threadIdx.x; i < 286720; i += (long)gridDim.x * TPB) {
      pa.h1[i] = 0.f;
      pa.h2[i] = 0.f;
      pa.df[i] = (half_t)0.f;
    }
  } else {
    // W1 transpose: bx -> (kc, jc), 140*16 = 2240 tiles
    int bx = blockIdx.x;
    if (bx >= 2240) return;
    int k0 = (bx >> 4) * 64, j0 = (bx & 15) * 64;
    for (int i = threadIdx.x; i < 1024; i += TPB) {
      int r = i >> 4, c4 = i & 15;
      float4 v = *(const float4*)(pa.W1 + (long)(k0 + r) * 1024 + j0 + c4 * 4);
      tile[r][c4 * 4 + 0] = v.x;
      tile[r][c4 * 4 + 1] = v.y;
      tile[r][c4 * 4 + 2] = v.z;
      tile[r][c4 * 4 + 3] = v.w;
    }
    __syncthreads();
    for (int i = threadIdx.x; i < 512; i += TPB) {
      int r = i >> 3, c8 = i & 7;
      f16x8 o;
      #pragma unroll
      for (int z = 0; z < 8; ++z) o[z] = (half_t)tile[c8 * 8 + z][r];
      *(f16x8*)(pa.w1t + (long)(j0 + r) * 8960 + k0 + c8 * 8) = o;
    }
  }
}

// ---------- K-packed MFMA conv (CO<=32); 64 sites/block; f16 out ----------
template <int CI, int CO, bool DENSE>
__global__ __launch_bounds__(256) void mconvp_k(const half_t* __restrict__ X,
                                                const half_t* __restrict__ Wt,
                                                half_t* __restrict__ y,
                                                const int* __restrict__ inv,
                                                const int* __restrict__ list,
                                                const int* __restrict__ cnt,
                                                int H, int W) {
  constexpr int KP = ((9 * CI + 31) / 32) * 32;
  constexpr int NCO = CO / 16;
  const int nact = cnt[0];
  const int base = blockIdx.x * 64;
  if (base >= nact) return;
  __shared__ int nbr[64 * 9];
  for (int i = threadIdx.x; i < 64 * 9; i += TPB) {
    int s = i / 9, nb = i - s * 9;
    int j = -1;
    if (base + s < nact) {
      int site = list[base + s];
      int w = site % W; int t = site / W; int h = t % H; int bb = t / H;
      int hh = h + nb / 3 - 1, ww = w + nb % 3 - 1;
      if ((unsigned)hh < (unsigned)H && (unsigned)ww < (unsigned)W) {
        int ss = (bb * H + hh) * W + ww;
        j = DENSE ? ss : inv[ss];
      }
    }
    nbr[i] = j;
  }
  __syncthreads();
  const int lane = threadIdx.x & 63, wv = threadIdx.x >> 6;
  const int srow = lane & 15, kseg = lane >> 4;
  const int sloc = wv * 16 + srow;
  f32x4 acc[NCO];
  #pragma unroll
  for (int c = 0; c < NCO; ++c) acc[c] = (f32x4){0.f, 0.f, 0.f, 0.f};
  #pragma unroll
  for (int k0 = 0; k0 < KP; k0 += 32) {
    const int k = k0 + kseg * 8;
    f16x8 av;
    #pragma unroll
    for (int z = 0; z < 8; ++z) av[z] = (_Float16)0.f;
    if (CI >= 8) {
      int tap = k / CI;
      int ci = k - tap * CI;
      if (tap < 9) {
        int j = nbr[sloc * 9 + tap];
        if (j >= 0) av = *(const f16x8*)(X + (long)j * CI + ci);
      }
    } else {  // CI == 2
      #pragma unroll
      for (int q = 0; q < 4; ++q) {
        int kk = k + 2 * q;
        int tap = kk >> 1;
        if (tap < 9) {
          int j = nbr[sloc * 9 + tap];
          if (j >= 0) {
            const half_t* xp = X + (long)j * 2;
            av[2 * q] = xp[0];
            av[2 * q + 1] = xp[1];
          }
        }
      }
    }
    #pragma unroll
    for (int c = 0; c < NCO; ++c) {
      f16x8 bv = *(const f16x8*)(Wt + (long)(c * 16 + srow) * KP + k);
      acc[c] = __builtin_amdgcn_mfma_f32_16x16x32_f16(av, bv, acc[c], 0, 0, 0);
    }
  }
  #pragma unroll
  for (int c = 0; c < NCO; ++c)
    #pragma unroll
    for (int r = 0; r < 4; ++r) {
      int ss = base + wv * 16 + kseg * 4 + r;
      if (ss < nact) y[(long)ss * CO + c * 16 + srow] = (half_t)acc[c][r];
    }
}

// ---------- LDS-staged-weight conv: 64 sites x 64 co per block, W[tap] in LDS ----------
template <int CI>
__global__ __launch_bounds__(256) void mconv_lds_k(const half_t* __restrict__ X,
                                                   const half_t* __restrict__ Wt,
                                                   half_t* __restrict__ y,
                                                   const int* __restrict__ inv,
                                                   const int* __restrict__ list,
                                                   const int* __restrict__ cnt,
                                                   int H, int W, int COfull) {
  constexpr int NK = CI / 32;
  constexpr int LDW = CI + 8;
  __shared__ half_t wlds[64 * LDW];
  const int nact = cnt[0];
  const int base = blockIdx.x * 64;
  if (base >= nact) return;
  const int lane = threadIdx.x & 63, wv = threadIdx.x >> 6;
  const int srow = lane & 15, kseg = lane >> 4;
  const int co0 = blockIdx.y * 64;
  int jj[9];
  {
    int s = base + wv * 16 + srow;
    bool sv = (s < nact);
    int h = 0, w = 0, bb = 0;
    if (sv) {
      int site = list[s];
      w = site % W;
      int t = site / W;
      h = t % H;
      bb = t / H;
    }
    #pragma unroll
    for (int tap = 0; tap < 9; ++tap) {
      int j = -1;
      if (sv) {
        int hh = h + tap / 3 - 1, ww = w + tap % 3 - 1;
        if ((unsigned)hh < (unsigned)H && (unsigned)ww < (unsigned)W)
          j = inv[(bb * H + hh) * W + ww];
      }
      jj[tap] = j;
    }
  }
  f32x4 acc[4];
  #pragma unroll
  for (int b = 0; b < 4; ++b) acc[b] = (f32x4){0.f, 0.f, 0.f, 0.f};
  for (int tap = 0; tap < 9; ++tap) {
    __syncthreads();
    constexpr int GR = 64 * (CI / 8);
    const half_t* wsrc = Wt + ((long)tap * COfull + co0) * CI;
    for (int idx = threadIdx.x; idx < GR; idx += TPB) {
      int row = idx / (CI / 8), cb = idx % (CI / 8);
      *(f16x8*)(&wlds[row * LDW + cb * 8]) = *(const f16x8*)(wsrc + (long)row * CI + cb * 8);
    }
    __syncthreads();
    const int j = jj[tap];
    f16x8 av[NK];
    #pragma unroll
    for (int s = 0; s < NK; ++s) {
      #pragma unroll
      for (int z = 0; z < 8; ++z) av[s][z] = (_Float16)0.f;
      if (j >= 0) av[s] = *(const f16x8*)(X + (long)j * CI + kseg * 8 + s * 32);
    }
    #pragma unroll
    for (int s = 0; s < NK; ++s) {
      #pragma unroll
      for (int b = 0; b < 4; ++b) {
        f16x8 bv = *(const f16x8*)(&wlds[(b * 16 + srow) * LDW + kseg * 8 + s * 32]);
        acc[b] = __builtin_amdgcn_mfma_f32_16x16x32_f16(av[s], bv, acc[b], 0, 0, 0);
      }
    }
  }
  #pragma unroll
  for (int b = 0; b < 4; ++b)
    #pragma unroll
    for (int r = 0; r < 4; ++r) {
      int ss = base + wv * 16 + kseg * 4 + r;
      if (ss < nact) y[(long)ss * COfull + co0 + b * 16 + srow] = (half_t)acc[b][r];
    }
}

// ---------- fused GRU conv: 16 sites x 16 co per block (grid 70x16) ----------
template <int CI>
__global__ __launch_bounds__(256) void gruconv16_k(const half_t* __restrict__ X,
                                                   const half_t* __restrict__ Wg,
                                                   const half_t* __restrict__ Wc,
                                                   float* __restrict__ hdense,
                                                   half_t* __restrict__ hcomp,
                                                   half_t* __restrict__ dflat,
                                                   const int* __restrict__ inv,
                                                   const int* __restrict__ list,
                                                   const int* __restrict__ cnt,
                                                   int H, int W) {
  constexpr int CO = 256;
  constexpr int NK = CI / 32;
  const int nact = cnt[0];
  const int base = blockIdx.x * 16;
  if (base >= nact) return;
  __shared__ int nbr[16 * 9];
  __shared__ float red[4][16][34];
  for (int i = threadIdx.x; i < 16 * 9; i += TPB) {
    int s = i / 9, nb = i - s * 9;
    int j = -1;
    if (base + s < nact) {
      int site = list[base + s];
      int w = site % W; int t = site / W; int h = t % H; int bb = t / H;
      int hh = h + nb / 3 - 1, ww = w + nb % 3 - 1;
      if ((unsigned)hh < (unsigned)H && (unsigned)ww < (unsigned)W)
        j = inv[(bb * H + hh) * W + ww];
    }
    nbr[i] = j;
  }
  __syncthreads();
  const int lane = threadIdx.x & 63, wv = threadIdx.x >> 6;
  const int srow = lane & 15, kseg = lane >> 4;
  const int co0 = blockIdx.y * 16;
  const int t0 = (wv * 9) / 4, t1 = ((wv + 1) * 9) / 4;
  f32x4 g = {0.f, 0.f, 0.f, 0.f};
  f32x4 c = g;
  for (int tap = t0; tap < t1; ++tap) {
    int j = nbr[srow * 9 + tap];
    const half_t* xp = X + (long)j * CI + kseg * 8;
    const half_t* wgp = Wg + ((long)tap * CO + co0 + srow) * CI + kseg * 8;
    const half_t* wcp = Wc + ((long)tap * CO + co0 + srow) * CI + kseg * 8;
    f16x8 av[NK];
    #pragma unroll
    for (int s = 0; s < NK; ++s) {
      #pragma unroll
      for (int z = 0; z < 8; ++z) av[s][z] = (_Float16)0.f;
      if (j >= 0) av[s] = *(const f16x8*)(xp + s * 32);
    }
    #pragma unroll
    for (int s = 0; s < NK; ++s) {
      f16x8 bg = *(const f16x8*)(wgp + s * 32);
      f16x8 bc = *(const f16x8*)(wcp + s * 32);
      g = __builtin_amdgcn_mfma_f32_16x16x32_f16(av[s], bg, g, 0, 0, 0);
      c = __builtin_amdgcn_mfma_f32_16x16x32_f16(av[s], bc, c, 0, 0, 0);
    }
  }
  #pragma unroll
  for (int r = 0; r < 4; ++r) {
    int s = kseg * 4 + r;
    red[wv][s][srow] = g[r];
    red[wv][s][16 + srow] = c[r];
  }
  __syncthreads();
  {
    int i = threadIdx.x;
    int s = i >> 4, co = i & 15;
    float gs = red[0][s][co] + red[1][s][co] + red[2][s][co] + red[3][s][co];
    float cs = red[0][s][16 + co] + red[1][s][16 + co] + red[2][s][16 + co] + red[3][s][16 + co];
    int ss = base + s;
    if (ss < nact) {
      float u = 1.f / (1.f + expf(-gs));
      float v = u * tanhf(cs);
      if (hcomp) hcomp[(long)ss * CO + co0 + co] = (half_t)v;
      int site = list[ss];
      hdense[(long)site * CO + co0 + co] = v;
      if (dflat) {
        int b = site / 35, s2 = site - b * 35;
        dflat[(long)b * 8960 + (co0 + co) * 35 + s2] = (half_t)v;
      }
    }
  }
}

// ---------- BN (f16 activations) ----------
template <int CO>
__global__ void bn_stats2_k(const half_t* __restrict__ y, const int* __restrict__ cnt,
                            float* __restrict__ stats) {
  __shared__ float ls[512];
  for (int i = threadIdx.x; i < 2 * CO; i += TPB) ls[i] = 0.f;
  __syncthreads();
  long total = (long)cnt[0] * CO;
  long i0 = (long)blockIdx.x * TPB + threadIdx.x;
  int c = (int)(i0 & (CO - 1));
  float s = 0.f, s2 = 0.f;
  for (long i = i0; i < total; i += (long)gridDim.x * TPB) {
    float v = (float)y[i];
    s += v; s2 += v * v;
  }
  atomicAdd(&ls[c], s);
  atomicAdd(&ls[CO + c], s2);
  __syncthreads();
  for (int i = threadIdx.x; i < 2 * CO; i += TPB) atomicAdd(&stats[i], ls[i]);
}

template <int C>
__global__ void bnapply_f16_k(const half_t* __restrict__ y, const int* __restrict__ cnt,
                              const float* __restrict__ stats, const float* __restrict__ gamma,
                              const float* __restrict__ beta, half_t* __restrict__ out) {
  __shared__ float sc[C], sh2[C];
  for (int c = threadIdx.x; c < C; c += TPB) {
    float n = fmaxf((float)cnt[0], 1.f);
    float mean = stats[c] / n;
    float var = fmaxf(stats[C + c] / n - mean * mean, 0.f);
    float s = gamma[c] * rsqrtf(var + 1e-4f);
    sc[c] = s;
    sh2[c] = beta[c] - mean * s;
  }
  __syncthreads();
  long total = (long)cnt[0] * C;
  for (long i = (long)blockIdx.x * TPB + threadIdx.x; i < total; i += (long)gridDim.x * TPB) {
    int c = (int)(i & (C - 1));
    out[i] = (half_t)fmaxf(fmaf((float)y[i], sc[c], sh2[c]), 0.f);
  }
}

// ---------- head: MFMA lin1 ----------
#define KS1 35
__global__ __launch_bounds__(256) void lin1m_k(const half_t* __restrict__ D,
                                               const half_t* __restrict__ W1T,
                                               float* __restrict__ part) {
  __shared__ float red[4][32][65];
  const int lane = threadIdx.x & 63, wv = threadIdx.x >> 6;
  const int srow = lane & 15, kseg = lane >> 4;
  const int kc = blockIdx.x, j0 = blockIdx.y * 64;
  const int kbase = kc * 256 + wv * 64;
  f32x4 acc[2][4];
  #pragma unroll
  for (int m = 0; m < 2; ++m)
    #pragma unroll
    for (int b = 0; b < 4; ++b) acc[m][b] = (f32x4){0.f, 0.f, 0.f, 0.f};
  #pragma unroll
  for (int step = 0; step < 2; ++step) {
    int k = kbase + step * 32 + kseg * 8;
    f16x8 a0 = *(const f16x8*)(D + (long)srow * 8960 + k);
    f16x8 a1 = *(const f16x8*)(D + (long)(16 + srow) * 8960 + k);
    #pragma unroll
    for (int b = 0; b < 4; ++b) {
      f16x8 bv = *(const f16x8*)(W1T + (long)(j0 + b * 16 + srow) * 8960 + k);
      acc[0][b] = __builtin_amdgcn_mfma_f32_16x16x32_f16(a0, bv, acc[0][b], 0, 0, 0);
      acc[1][b] = __builtin_amdgcn_mfma_f32_16x16x32_f16(a1, bv, acc[1][b], 0, 0, 0);
    }
  }
  #pragma unroll
  for (int m = 0; m < 2; ++m)
    #pragma unroll
    for (int b = 0; b < 4; ++b)
      #pragma unroll
      for (int r = 0; r < 4; ++r)
        red[wv][m * 16 + kseg * 4 + r][b * 16 + srow] = acc[m][b][r];
  __syncthreads();
  for (int i = threadIdx.x; i < 32 * 64; i += TPB) {
    int row = i >> 6, col = i & 63;
    float v = red[0][row][col] + red[1][row][col] + red[2][row][col] + red[3][row][col];
    part[(long)kc * 32768 + row * 1024 + j0 + col] = v;
  }
}

__global__ void lin1_reduce_k(const float* __restrict__ part, const float* __restrict__ b1,
                              float* __restrict__ y1) {
  int i = blockIdx.x * TPB + threadIdx.x;
  if (i >= 32 * 1024) return;
  int b = i >> 10, j = i & 1023;
  float a = b1[j];
  #pragma unroll
  for (int kc = 0; kc < KS1; ++kc) a += part[(long)kc * 32768 + b * 1024 + j];
  y1[i] = fmaxf(a, 0.f);
}

#define JS2 8
__global__ void lin2_part_k(const float* __restrict__ y1, const float* __restrict__ W2,
                            float* __restrict__ part2) {
  int i = blockIdx.x * TPB + threadIdx.x;
  if (i >= 32 * 420) return;
  int b = i / 420, o = i - b * 420;
  int j0 = blockIdx.y * 128;
  float a = 0.f;
  const float* yp = y1 + b * 1024 + j0;
  const float* wp = W2 + (long)j0 * 420 + o;
  #pragma unroll 8
  for (int j = 0; j < 128; ++j) a = fmaf(yp[j], wp[(long)j * 420], a);
  part2[(long)blockIdx.y * 13440 + i] = a;
}

__global__ void lin2_fin_k(const float* __restrict__ part2, const float* __restrict__ b2,
                           float* __restrict__ out) {
  int i = blockIdx.x * TPB + threadIdx.x;
  if (i >= 32 * 420) return;
  int o = i % 420;
  float a = b2[o];
  #pragma unroll
  for (int js = 0; js < JS2; ++js) a += part2[(long)js * 13440 + i];
  out[i] = a;
}

extern "C" void kernel_launch(void* const* d_in, const int* in_sizes, int n_in,
                              void* d_out, int out_size, void* d_ws, size_t ws_size,
                              hipStream_t stream) {
  const float* x = (const float*)d_in[0];
  const float* ca[5] = {(const float*)d_in[2], (const float*)d_in[6], (const float*)d_in[10],
                        (const float*)d_in[14], (const float*)d_in[18]};
  const float* bg[5] = {(const float*)d_in[3], (const float*)d_in[7], (const float*)d_in[11],
                        (const float*)d_in[15], (const float*)d_in[19]};
  const float* bb[5] = {(const float*)d_in[4], (const float*)d_in[8], (const float*)d_in[12],
                        (const float*)d_in[16], (const float*)d_in[20]};
  const float* cb[5] = {(const float*)d_in[5], (const float*)d_in[9], (const float*)d_in[13],
                        (const float*)d_in[17], (const float*)d_in[21]};
  const float* g1Wg = (const float*)d_in[22];
  const float* g1Wc = (const float*)d_in[23];
  const float* g2Wg = (const float*)d_in[24];
  const float* g2Wc = (const float*)d_in[25];
  const float* W1 = (const float*)d_in[26];
  const float* b1 = (const float*)d_in[27];
  const float* W2 = (const float*)d_in[28];
  const float* b2 = (const float*)d_in[29];

  const int Hs[6] = {191, 95, 47, 23, 11, 5};
  const int Wd[6] = {255, 127, 63, 31, 15, 7};
  const long NS[6] = {1558560, 386080, 94752, 22816, 5280, 1120};
  const int cap[6] = {160000, 386080, 94752, 22816, 5280, 1120};

  float* ws = (float*)d_ws;
  long off = 0;
  float* part = ws + off;  off += 1200000;
  float* part2 = ws + off; off += 120000;
  float* stats = ws + off; off += 512;
  float* y1 = ws + off;    off += 32L * 1024;

  half_t* hbase = (half_t*)(ws + off);
  long hoff = 0;
  half_t* hbufA = hbase + hoff; hoff += 6500000;
  half_t* hbufB = hbase + hoff; hoff += 6500000;
  half_t* hbufC = hbase + hoff; hoff += 6500000;
  half_t* xh = hbase + hoff;    hoff += 3117120;
  half_t* w1t = hbase + hoff;   hoff += 9175040;
  half_t* df16 = hbase + hoff;  hoff += 286720;
  half_t* wp_ca0 = hbase + hoff; hoff += 16L * 32;
  half_t* wp_cb0 = hbase + hoff; hoff += 16L * 160;
  half_t* wp_ca1 = hbase + hoff; hoff += 32L * 160;
  half_t* wp_cb1 = hbase + hoff; hoff += 32L * 288;
  half_t* wt_ca2 = hbase + hoff; hoff += 9L * 64 * 32;
  half_t* wt_cb2 = hbase + hoff; hoff += 9L * 64 * 64;
  half_t* wt_ca3 = hbase + hoff; hoff += 9L * 128 * 64;
  half_t* wt_cb3 = hbase + hoff; hoff += 9L * 128 * 128;
  half_t* wt_ca4 = hbase + hoff; hoff += 9L * 256 * 128;
  half_t* wt_cb4 = hbase + hoff; hoff += 9L * 256 * 256;
  half_t* wt_g1g = hbase + hoff; hoff += 9L * 256 * 256;
  half_t* wt_g1c = hbase + hoff; hoff += 9L * 256 * 256;
  half_t* wt_g2g = hbase + hoff; hoff += 9L * 256 * 256;
  half_t* wt_g2c = hbase + hoff; hoff += 9L * 256 * 256;

  int* ip = (int*)(hbase + hoff);
  long ioff = 0;
  int* cnt = ip + ioff; ioff += 16;
  int* bcnt = ip + ioff; ioff += 8192;
  int* list[6]; int* inv[6];
  for (int l = 0; l < 6; ++l) { list[l] = ip + ioff; ioff += cap[l]; }
  for (int l = 0; l < 6; ++l) { inv[l] = ip + ioff; ioff += NS[l]; }
  uint8_t* actm = (uint8_t*)(ip + ioff);
  long aoff = NS[1];
  size_t needed = (size_t)off * 4 + (size_t)hoff * 2 + (size_t)ioff * 4 + (size_t)aoff;
  if (ws_size < needed) return;

  float* h1d = (float*)d_out + 13440;
  float* h2d = h1d + 286720;

  // ---- one-shot prep ----
  PackArgs pa;
  pa.src[0] = ca[0]; pa.dst[0] = wp_ca0;
  pa.src[1] = cb[0]; pa.dst[1] = wp_cb0;
  pa.src[2] = ca[1]; pa.dst[2] = wp_ca1;
  pa.src[3] = cb[1]; pa.dst[3] = wp_cb1;
  pa.src[4] = ca[2]; pa.dst[4] = wt_ca2;
  pa.src[5] = cb[2]; pa.dst[5] = wt_cb2;
  pa.src[6] = ca[3]; pa.dst[6] = wt_ca3;
  pa.src[7] = cb[3]; pa.dst[7] = wt_cb3;
  pa.src[8] = ca[4]; pa.dst[8] = wt_ca4;
  pa.src[9] = cb[4]; pa.dst[9] = wt_cb4;
  pa.src[10] = g1Wg; pa.dst[10] = wt_g1g;
  pa.src[11] = g1Wc; pa.dst[11] = wt_g1c;
  pa.src[12] = g2Wg; pa.dst[12] = wt_g2g;
  pa.src[13] = g2Wc; pa.dst[13] = wt_g2c;
  pa.W1 = W1; pa.w1t = w1t;
  pa.h1 = h1d; pa.h2 = h2d; pa.df = df16;
  megaprep_k<<<dim3(2240, 16), TPB, 0, stream>>>(pa);

  // ---- level-0 compaction (also x->f16) ----
  {
    int nb = nblk(NS[0]);
    cmpA0_k<<<nb, TPB, 0, stream>>>(x, (int)NS[0], bcnt);
    scan_k<<<1, 1024, 0, stream>>>(bcnt, nb, cnt + 0, stats);
    cmpB0_k<<<nb, TPB, 0, stream>>>(x, (int)NS[0], bcnt, list[0], inv[0], cap[0], xh);
  }

  // ---------- level 1 ----------
  mconvp_k<2, 16, true><<<(cap[0] + 63) / 64, TPB, 0, stream>>>(
      xh, wp_ca0, hbufC, nullptr, list[0], cnt + 0, Hs[0], Wd[0]);
  bn_stats2_k<16><<<288, TPB, 0, stream>>>(hbufC, cnt + 0, stats);
  bnapply_f16_k<16><<<2048, TPB, 0, stream>>>(hbufC, cnt + 0, stats, bg[0], bb[0], hbufA);
  mconvp_k<16, 16, false><<<(cap[0] + 63) / 64, TPB, 0, stream>>>(
      hbufA, wp_cb0, hbufC, inv[0], list[0], cnt + 0, Hs[0], Wd[0]);
  {
    int nb = nblk(NS[1]);
    poolA_k<<<nb, TPB, 0, stream>>>(inv[0], Hs[0], Wd[0], Hs[1], Wd[1], (int)NS[1], bcnt, actm);
    scan_k<<<1, 1024, 0, stream>>>(bcnt, nb, cnt + 1, stats);
    poolB_k<<<nb, TPB, 0, stream>>>(actm, (int)NS[1], bcnt, list[1], inv[1], cap[1]);
  }
  pool_val_f16_k<16><<<1024, TPB, 0, stream>>>(hbufC, inv[0], list[1], cnt + 1, Hs[0], Wd[0], Hs[1], Wd[1], hbufB);

  // ---------- level 2 ----------
  mconvp_k<16, 32, false><<<(cap[1] + 63) / 64, TPB, 0, stream>>>(
      hbufB, wp_ca1, hbufC, inv[1], list[1], cnt + 1, Hs[1], Wd[1]);
  bn_stats2_k<32><<<288, TPB, 0, stream>>>(hbufC, cnt + 1, stats);
  bnapply_f16_k<32><<<2048, TPB, 0, stream>>>(hbufC, cnt + 1, stats, bg[1], bb[1], hbufA);
  mconvp_k<32, 32, false><<<(cap[1] + 63) / 64, TPB, 0, stream>>>(
      hbufA, wp_cb1, hbufC, inv[1], list[1], cnt + 1, Hs[1], Wd[1]);
  {
    int nb = nblk(NS[2]);
    poolA_k<<<nb, TPB, 0, stream>>>(inv[1], Hs[1], Wd[1], Hs[2], Wd[2], (int)NS[2], bcnt, actm);
    scan_k<<<1, 1024, 0, stream>>>(bcnt, nb, cnt + 2, stats);
    poolB_k<<<nb, TPB, 0, stream>>>(actm, (int)NS[2], bcnt, list[2], inv[2], cap[2]);
  }
  pool_val_f16_k<32><<<1024, TPB, 0, stream>>>(hbufC, inv[1], list[2], cnt + 2, Hs[1], Wd[1], Hs[2], Wd[2], hbufB);

  // ---------- level 3 (LDS-staged weights) ----------
  mconv_lds_k<32><<<dim3((cap[2] + 63) / 64, 1), TPB, 0, stream>>>(
      hbufB, wt_ca2, hbufC, inv[2], list[2], cnt + 2, Hs[2], Wd[2], 64);
  bn_stats2_k<64><<<288, TPB, 0, stream>>>(hbufC, cnt + 2, stats);
  bnapply_f16_k<64><<<2048, TPB, 0, stream>>>(hbufC, cnt + 2, stats, bg[2], bb[2], hbufA);
  mconv_lds_k<64><<<dim3((cap[2] + 63) / 64, 1), TPB, 0, stream>>>(
      hbufA, wt_cb2, hbufC, inv[2], list[2], cnt + 2, Hs[2], Wd[2], 64);
  {
    int nb = nblk(NS[3]);
    poolA_k<<<nb, TPB, 0, stream>>>(inv[2], Hs[2], Wd[2], Hs[3], Wd[3], (int)NS[3], bcnt, actm);
    scan_k<<<1, 1024, 0, stream>>>(bcnt, nb, cnt + 3, stats);
    poolB_k<<<nb, TPB, 0, stream>>>(actm, (int)NS[3], bcnt, list[3], inv[3], cap[3]);
  }
  pool_val_f16_k<64><<<1024, TPB, 0, stream>>>(hbufC, inv[2], list[3], cnt + 3, Hs[2], Wd[2], Hs[3], Wd[3], hbufB);

  // ---------- level 4 (LDS-staged weights) ----------
  mconv_lds_k<64><<<dim3((cap[3] + 63) / 64, 2), TPB, 0, stream>>>(
      hbufB, wt_ca3, hbufC, inv[3], list[3], cnt + 3, Hs[3], Wd[3], 128);
  bn_stats2_k<128><<<288, TPB, 0, stream>>>(hbufC, cnt + 3, stats);
  bnapply_f16_k<128><<<2048, TPB, 0, stream>>>(hbufC, cnt + 3, stats, bg[3], bb[3], hbufA);
  mconv_lds_k<128><<<dim3((cap[3] + 63) / 64, 2), TPB, 0, stream>>>(
      hbufA, wt_cb3, hbufC, inv[3], list[3], cnt + 3, Hs[3], Wd[3], 128);
  {
    int nb = nblk(NS[4]);
    poolA_k<<<nb, TPB, 0, stream>>>(inv[3], Hs[3], Wd[3], Hs[4], Wd[4], (int)NS[4], bcnt, actm);
    scan_k<<<1, 1024, 0, stream>>>(bcnt, nb, cnt + 4, stats);
    poolB_k<<<nb, TPB, 0, stream>>>(actm, (int)NS[4], bcnt, list[4], inv[4], cap[4]);
  }
  pool_val_f16_k<128><<<1024, TPB, 0, stream>>>(hbufC, inv[3], list[4], cnt + 4, Hs[3], Wd[3], Hs[4], Wd[4], hbufB);

  // ---------- level 5 (LDS-staged weights) ----------
  mconv_lds_k<128><<<dim3((cap[4] + 63) / 64, 4), TPB, 0, stream>>>(
      hbufB, wt_ca4, hbufC, inv[4], list[4], cnt + 4, Hs[4], Wd[4], 256);
  bn_stats2_k<256><<<288, TPB, 0, stream>>>(hbufC, cnt + 4, stats);
  bnapply_f16_k<256><<<2048, TPB, 0, stream>>>(hbufC, cnt + 4, stats, bg[4], bb[4], hbufA);
  mconv_lds_k<256><<<dim3((cap[4] + 63) / 64, 4), TPB, 0, stream>>>(
      hbufA, wt_cb4, hbufC, inv[4], list[4], cnt + 4, Hs[4], Wd[4], 256);
  {
    int nb = nblk(NS[5]);
    poolA_k<<<nb, TPB, 0, stream>>>(inv[4], Hs[4], Wd[4], Hs[5], Wd[5], (int)NS[5], bcnt, actm);
    scan_k<<<1, 1024, 0, stream>>>(bcnt, nb, cnt + 5, stats);
    poolB_k<<<nb, TPB, 0, stream>>>(actm, (int)NS[5], bcnt, list[5], inv[5], cap[5]);
  }
  pool_val_f16_k<256><<<1024, TPB, 0, stream>>>(hbufC, inv[4], list[5], cnt + 5, Hs[4], Wd[4], Hs[5], Wd[5], hbufB);

  // ---------- GRUs (16-co tiles) ----------
  gruconv16_k<256><<<dim3((cap[5] + 15) / 16, 16), TPB, 0, stream>>>(
      hbufB, wt_g1g, wt_g1c, h1d, hbufA, nullptr, inv[5], list[5], cnt + 5, Hs[5], Wd[5]);
  gruconv16_k<256><<<dim3((cap[5] + 15) / 16, 16), TPB, 0, stream>>>(
      hbufA, wt_g2g, wt_g2c, h2d, nullptr, df16, inv[5], list[5], cnt + 5, Hs[5], Wd[5]);

  // ---------- head ----------
  lin1m_k<<<dim3(KS1, 16), TPB, 0, stream>>>(df16, w1t, part);
  lin1_reduce_k<<<nblk(32L * 1024), TPB, 0, stream>>>(part, b1, y1);
  lin2_part_k<<<dim3(nblk(32L * 420), JS2), TPB, 0, stream>>>(y1, W2, part2);
  lin2_fin_k<<<nblk(32L * 420), TPB, 0, stream>>>(part2, b2, (float*)d_out);
}